// Round 1
// baseline (1453.621 us; speedup 1.0000x reference)
//
#include <hip/hip_runtime.h>
#include <cstdint>
#include <cstddef>

typedef unsigned short ushort_t;
typedef unsigned int uint_t;

#define NB 128
#define NC 128
#define NL 256
#define NH 8
#define HD 16
#define HDV 64
#define NEV 512

__device__ __forceinline__ ushort_t f2bf(float f) {
    uint_t u = __float_as_uint(f);
    u += 0x7fffu + ((u >> 16) & 1u);
    return (ushort_t)(u >> 16);
}
__device__ __forceinline__ float bf2f(ushort_t s) {
    return __uint_as_float(((uint_t)s) << 16);
}

// ---------------- K0: weight transpose  wt[(ci*9+tap)*128 + co] = w[(co*CIN+ci)*9+tap]
template<int CIN>
__global__ __launch_bounds__(256) void k_wtrans(const float* __restrict__ w,
                                               float* __restrict__ wt) {
    int idx = blockIdx.x * 256 + threadIdx.x;
    const int total = NC * CIN * 9;
    if (idx >= total) return;
    int co = idx & (NC - 1);
    int rest = idx >> 7;          // NC == 128
    int tap = rest % 9;
    int ci = rest / 9;
    wt[idx] = w[((size_t)co * CIN + ci) * 9 + tap];
}

// ---------------- K1: fused position projections + attention, one block per (head, batch)
__global__ __launch_bounds__(256) void k_pos_attn(
    const float* __restrict__ x,
    const float* __restrict__ wq, const float* __restrict__ bq,
    const float* __restrict__ wk, const float* __restrict__ bk,
    const float* __restrict__ wv, const float* __restrict__ bv,
    ushort_t* __restrict__ att)
{
    const int h = blockIdx.x;
    const int b = blockIdx.y;
    const int l = threadIdx.x;          // query row / spatial index

    __shared__ float    pk_s[NL][HD];   // 16 KB
    __shared__ ushort_t pv_s[NL][HDV];  // 32 KB (bf16)

    const float* xb = x + (size_t)b * NC * NL + l;

    // ---- projections q, k (accumulate in registers; weight loads are wave-uniform -> s_load)
    float aq[HD], ak[HD];
    #pragma unroll
    for (int i = 0; i < HD; ++i) { aq[i] = bq[h*HD + i]; ak[i] = bk[h*HD + i]; }
    {
        const float* wqh = wq + (size_t)h * HD * NC;
        const float* wkh = wk + (size_t)h * HD * NC;
        for (int c4 = 0; c4 < NC/4; ++c4) {
            float x0 = xb[(4*c4+0)*NL];
            float x1 = xb[(4*c4+1)*NL];
            float x2 = xb[(4*c4+2)*NL];
            float x3 = xb[(4*c4+3)*NL];
            #pragma unroll
            for (int i = 0; i < HD; ++i) {
                float4 a = *(const float4*)(wqh + i*NC + 4*c4);
                aq[i] = fmaf(x0,a.x,fmaf(x1,a.y,fmaf(x2,a.z,fmaf(x3,a.w,aq[i]))));
                float4 k2 = *(const float4*)(wkh + i*NC + 4*c4);
                ak[i] = fmaf(x0,k2.x,fmaf(x1,k2.y,fmaf(x2,k2.z,fmaf(x3,k2.w,ak[i]))));
            }
        }
        #pragma unroll
        for (int i = 0; i < HD; ++i) pk_s[l][i] = ak[i];
    }
    // ---- projection v (second pass over x, 64 accumulators)
    {
        float av[HDV];
        #pragma unroll
        for (int j = 0; j < HDV; ++j) av[j] = bv[h*HDV + j];
        const float* wvh = wv + (size_t)h * HDV * NC;
        for (int c4 = 0; c4 < NC/4; ++c4) {
            float x0 = xb[(4*c4+0)*NL];
            float x1 = xb[(4*c4+1)*NL];
            float x2 = xb[(4*c4+2)*NL];
            float x3 = xb[(4*c4+3)*NL];
            #pragma unroll
            for (int j = 0; j < HDV; ++j) {
                float4 a = *(const float4*)(wvh + j*NC + 4*c4);
                av[j] = fmaf(x0,a.x,fmaf(x1,a.y,fmaf(x2,a.z,fmaf(x3,a.w,av[j]))));
            }
        }
        #pragma unroll
        for (int j = 0; j < HDV; ++j) pv_s[l][j] = f2bf(av[j]);
    }
    __syncthreads();

    // ---- softmax(QK^T * 0.25) @ V, two-pass (recompute scores), thread = row l
    float mx = -3.0e38f;
    for (int m = 0; m < NL; ++m) {
        const float4* pk4 = (const float4*)pk_s[m];
        float s = 0.f;
        #pragma unroll
        for (int i4 = 0; i4 < HD/4; ++i4) {
            float4 kk = pk4[i4];
            s = fmaf(aq[4*i4+0],kk.x,fmaf(aq[4*i4+1],kk.y,
                 fmaf(aq[4*i4+2],kk.z,fmaf(aq[4*i4+3],kk.w,s))));
        }
        mx = fmaxf(mx, s);
    }
    float outv[HDV];
    #pragma unroll
    for (int j = 0; j < HDV; ++j) outv[j] = 0.f;
    float den = 0.f;
    for (int m = 0; m < NL; ++m) {
        const float4* pk4 = (const float4*)pk_s[m];
        float s = 0.f;
        #pragma unroll
        for (int i4 = 0; i4 < HD/4; ++i4) {
            float4 kk = pk4[i4];
            s = fmaf(aq[4*i4+0],kk.x,fmaf(aq[4*i4+1],kk.y,
                 fmaf(aq[4*i4+2],kk.z,fmaf(aq[4*i4+3],kk.w,s))));
        }
        float wgt = __expf((s - mx) * 0.25f);
        den += wgt;
        const uint4* pv4 = (const uint4*)pv_s[m];
        #pragma unroll
        for (int k8 = 0; k8 < HDV/8; ++k8) {
            uint4 u = pv4[k8];
            outv[k8*8+0] = fmaf(wgt, __uint_as_float(u.x << 16),        outv[k8*8+0]);
            outv[k8*8+1] = fmaf(wgt, __uint_as_float(u.x & 0xffff0000u), outv[k8*8+1]);
            outv[k8*8+2] = fmaf(wgt, __uint_as_float(u.y << 16),        outv[k8*8+2]);
            outv[k8*8+3] = fmaf(wgt, __uint_as_float(u.y & 0xffff0000u), outv[k8*8+3]);
            outv[k8*8+4] = fmaf(wgt, __uint_as_float(u.z << 16),        outv[k8*8+4]);
            outv[k8*8+5] = fmaf(wgt, __uint_as_float(u.z & 0xffff0000u), outv[k8*8+5]);
            outv[k8*8+6] = fmaf(wgt, __uint_as_float(u.w << 16),        outv[k8*8+6]);
            outv[k8*8+7] = fmaf(wgt, __uint_as_float(u.w & 0xffff0000u), outv[k8*8+7]);
        }
    }
    const float inv = 1.f / den;
    // (B,h,L,dv) -> transpose -> channel = h*64+dv, spatial l
    ushort_t* ap = att + ((size_t)b*NEV + h*HDV)*NL + l;
    #pragma unroll
    for (int j = 0; j < HDV; ++j) ap[(size_t)j*NL] = f2bf(outv[j]*inv);
}

// ---------------- K2 / K4: 3x3 conv (implicit GEMM), padded-halo LDS image, uniform s_load weights
// block: 256 threads = 2 co-groups(16 co) x 128 l-groups (each thread: 16 co x 2 l)
template<int CIN, bool RES>
__global__ __launch_bounds__(256) void k_conv3x3(
    const void* __restrict__ in_, const float* __restrict__ resid,
    const float* __restrict__ wt, const float* __restrict__ bias,
    const float* __restrict__ gamma, float* __restrict__ out)
{
    constexpr int CHUNKS = CIN / 16;
    __shared__ float att_p[16 * 324];         // 16 ci x (18x18 zero-padded image)
    const int b = blockIdx.y;
    const int co_base = blockIdx.x * 32;
    const int t = threadIdx.x;
    const int lgrp = t & 127;
    const int cgu  = __builtin_amdgcn_readfirstlane(t >> 7);   // wave-uniform co-group
    const int ty = t >> 4, tx = t & 15;       // staging coords (256 = 16x16)
    const int yb = lgrp >> 4, xx = lgrp & 15;
    const int vb = yb * 18 + xx;

    float acc[16][2];
    #pragma unroll
    for (int j = 0; j < 16; ++j) { acc[j][0] = 0.f; acc[j][1] = 0.f; }

    for (int i = t; i < 16*324; i += 256) att_p[i] = 0.f;   // zero halo once

    for (int ch = 0; ch < CHUNKS; ++ch) {
        const int ci0 = ch * 16;
        __syncthreads();
        #pragma unroll
        for (int r = 0; r < 16; ++r) {
            float v;
            if constexpr (CIN == NEV) {
                ushort_t u = ((const ushort_t*)in_)[((size_t)b*CIN + ci0 + r)*NL + t];
                v = bf2f(u);
            } else {
                v = ((const float*)in_)[((size_t)b*CIN + ci0 + r)*NL + t];
            }
            att_p[r*324 + (ty+1)*18 + (tx+1)] = v;
        }
        __syncthreads();
        for (int r = 0; r < 16; ++r) {
            const int rb = r*324 + vb;
            const float* wbase = wt + ((size_t)(ci0 + r) * 9) * NC + co_base + cgu*16;
            #pragma unroll
            for (int dy = 0; dy < 3; ++dy) {
                #pragma unroll
                for (int dx = 0; dx < 3; ++dx) {
                    float v0 = att_p[rb + dy*18 + dx];
                    float v1 = att_p[rb + 144 + dy*18 + dx];   // +8 rows (l+128)
                    const float* wr = wbase + (dy*3 + dx) * NC;
                    #pragma unroll
                    for (int j = 0; j < 16; ++j) {
                        float wj = wr[j];                      // wave-uniform -> s_load
                        acc[j][0] = fmaf(v0, wj, acc[j][0]);
                        acc[j][1] = fmaf(v1, wj, acc[j][1]);
                    }
                }
            }
        }
    }
    float g = 0.f;
    if constexpr (RES) g = gamma[0];
    #pragma unroll
    for (int j = 0; j < 16; ++j) {
        const int co = co_base + cgu*16 + j;
        const float bco = bias[co];
        #pragma unroll
        for (int q = 0; q < 2; ++q) {
            const size_t o = ((size_t)b*NC + co)*NL + lgrp + 128*q;
            if constexpr (RES) out[o] = resid[o] + g * (bco + acc[j][q]);
            else               out[o] = bco + acc[j][q];
        }
    }
}

// ---------------- K3: channel attention (block-diagonal, gram-collapsed) + fusion
#define NLP 260
__global__ __launch_bounds__(256) void k_cha(
    const float* __restrict__ xc,
    const float* __restrict__ cwq, const float* __restrict__ cbq,
    const float* __restrict__ cwk, const float* __restrict__ cbk,
    const float* __restrict__ cwv, const float* __restrict__ cbv,
    const float* __restrict__ cwo, const float* __restrict__ cbo,
    const float* __restrict__ gamma,
    float* __restrict__ comb)
{
    const int h = blockIdx.x, b = blockIdx.y, t = threadIdx.x;
    __shared__ float qh[16][NLP];
    __shared__ float G_s[16][17];
    __shared__ float S_s[16];
    __shared__ float wq_s[128], bq_s[128], wk_s[128], bk_s[128], wv_s[128], bv_s[128];
    __shared__ float A_s[128][17];
    __shared__ float B_s[128];
    __shared__ float M_s[16][17];
    __shared__ float c_s[16];

    #pragma unroll
    for (int j = 0; j < 16; ++j)
        qh[j][t] = xc[((size_t)b*NC + h*16 + j)*NL + t];
    if (t < 128) {
        const int k = h*128 + t;
        wq_s[t] = cwq[k]; bq_s[t] = cbq[k];
        wk_s[t] = cwk[k]; bk_s[t] = cbk[k];
        wv_s[t] = cwv[k]; bv_s[t] = cbv[k];
    }
    __syncthreads();
    {   // gram matrix G = qh qh^T and row sums S
        const int i = t >> 4, j = t & 15;
        const float4* qi = (const float4*)qh[i];
        const float4* qj = (const float4*)qh[j];
        float gg = 0.f;
        for (int l4 = 0; l4 < NL/4; ++l4) {
            float4 a = qi[l4], c = qj[l4];
            gg = fmaf(a.x,c.x,fmaf(a.y,c.y,fmaf(a.z,c.z,fmaf(a.w,c.w,gg))));
        }
        G_s[i][j] = gg;
    }
    if (t < 16) {
        const float4* qi = (const float4*)qh[t];
        float s = 0.f;
        for (int l4 = 0; l4 < NL/4; ++l4) { float4 a = qi[l4]; s += a.x + a.y + a.z + a.w; }
        S_s[t] = s;
    }
    __syncthreads();
    if (t < 128) {  // thread = attention row c2; softmax over d; fold V into rank-16 A,B
        const int c2 = t, cg = c2 >> 3;
        const float wqc = wq_s[c2], bqc = bq_s[c2];
        float P[16];
        #pragma unroll
        for (int j = 0; j < 16; ++j) P[j] = wqc*G_s[cg][j] + bqc*S_s[j];
        const float Qc = wqc*S_s[cg] + bqc*256.0f;
        float mx = -3.0e38f;
        #pragma unroll
        for (int dg = 0; dg < 16; ++dg) {
            #pragma unroll
            for (int dj = 0; dj < 8; ++dj) {
                const int d = dg*8 + dj;
                float s = wk_s[d]*P[dg] + bk_s[d]*Qc;
                mx = fmaxf(mx, s);
            }
        }
        float A[16];
        #pragma unroll
        for (int j = 0; j < 16; ++j) A[j] = 0.f;
        float Bv = 0.f, den = 0.f;
        #pragma unroll
        for (int dg = 0; dg < 16; ++dg) {
            #pragma unroll
            for (int dj = 0; dj < 8; ++dj) {
                const int d = dg*8 + dj;
                float s = wk_s[d]*P[dg] + bk_s[d]*Qc;
                float e = __expf((s - mx) * 0.0625f);
                den += e;
                A[dg] = fmaf(e, wv_s[d], A[dg]);
                Bv = fmaf(e, bv_s[d], Bv);
            }
        }
        const float inv = 1.f / den;
        #pragma unroll
        for (int j = 0; j < 16; ++j) A_s[c2][j] = A[j]*inv;
        B_s[c2] = Bv*inv;
    }
    __syncthreads();
    {   // grouped proj_out folded: M (16x16) and const vector
        const int cl = t >> 4, j = t & 15;
        const int cp = h*16 + cl;
        float m = 0.f;
        #pragma unroll
        for (int hp = 0; hp < 8; ++hp)
            m = fmaf(cwo[cp*8+hp], A_s[cl*8+hp][j], m);
        M_s[cl][j] = m;
        if (j == 0) {
            float cc = cbo[cp];
            #pragma unroll
            for (int hp = 0; hp < 8; ++hp)
                cc = fmaf(cwo[cp*8+hp], B_s[cl*8+hp], cc);
            c_s[cl] = cc;
        }
    }
    __syncthreads();
    {   // out_cha = xc + gamma*(const + M @ qh);  comb = 0.5*(out_pos + out_cha)
        const float g = gamma[0];
        const int l = t;
        #pragma unroll 2
        for (int cl = 0; cl < 16; ++cl) {
            float a = c_s[cl];
            #pragma unroll
            for (int j = 0; j < 16; ++j)
                a = fmaf(M_s[cl][j], qh[j][l], a);
            const size_t o = ((size_t)b*NC + h*16 + cl)*NL + l;
            comb[o] = 0.5f*(comb[o] + xc[o] + g*a);
        }
    }
}

extern "C" void kernel_launch(void* const* d_in, const int* in_sizes, int n_in,
                              void* d_out, int out_size, void* d_ws, size_t ws_size,
                              hipStream_t stream)
{
    const float* qpos = (const float*)d_in[0];
    const float* qcha = (const float*)d_in[1];
    const float* pwq  = (const float*)d_in[2];
    const float* pbq  = (const float*)d_in[3];
    const float* pwk  = (const float*)d_in[4];
    const float* pbk  = (const float*)d_in[5];
    const float* pwv  = (const float*)d_in[6];
    const float* pbv  = (const float*)d_in[7];
    const float* pwo  = (const float*)d_in[8];
    const float* pbo  = (const float*)d_in[9];
    const float* gpos = (const float*)d_in[10];
    const float* cwq  = (const float*)d_in[11];
    const float* cbq  = (const float*)d_in[12];
    const float* cwk  = (const float*)d_in[13];
    const float* cbk  = (const float*)d_in[14];
    const float* cwv  = (const float*)d_in[15];
    const float* cbv  = (const float*)d_in[16];
    const float* cwo  = (const float*)d_in[17];
    const float* cbo  = (const float*)d_in[18];
    const float* gcha = (const float*)d_in[19];
    const float* fw   = (const float*)d_in[20];
    const float* fb   = (const float*)d_in[21];
    float* outp = (float*)d_out;

    char* ws = (char*)d_ws;
    ushort_t* att  = (ushort_t*)ws;                                  // 33,554,432 B (bf16)
    float*    comb = (float*)(ws + 33554432);                        // 16,777,216 B
    float*    wtp  = (float*)(ws + 33554432 + 16777216);             //  2,359,296 B
    float*    wtf  = (float*)(ws + 33554432 + 16777216 + 2359296);   //    589,824 B

    k_wtrans<NEV><<<dim3((NC*NEV*9 + 255)/256), 256, 0, stream>>>(pwo, wtp);
    k_wtrans<NC><<<dim3((NC*NC*9 + 255)/256), 256, 0, stream>>>(fw, wtf);

    k_pos_attn<<<dim3(NH, NB), 256, 0, stream>>>(qpos, pwq, pbq, pwk, pbk, pwv, pbv, att);
    k_conv3x3<NEV, true><<<dim3(4, NB), 256, 0, stream>>>(att, qpos, wtp, pbo, gpos, comb);
    k_cha<<<dim3(NH, NB), 256, 0, stream>>>(qcha, cwq, cbq, cwk, cbk, cwv, cbv,
                                            cwo, cbo, gcha, comb);
    k_conv3x3<NC, false><<<dim3(4, NB), 256, 0, stream>>>(comb, nullptr, wtf, fb, nullptr, outp);
}

// Round 2
// 758.860 us; speedup vs baseline: 1.9155x; 1.9155x over previous
//
#include <hip/hip_runtime.h>
#include <cstdint>
#include <cstddef>

typedef unsigned short ushort_t;
typedef unsigned int uint_t;
typedef __attribute__((ext_vector_type(8))) short bf16x8;
typedef __attribute__((ext_vector_type(4))) float f32x4;

#define NB 128
#define NC 128
#define NL 256
#define NH 8
#define HD 16
#define HDV 64
#define NEV 512

__device__ __forceinline__ ushort_t f2bf(float f) {
    uint_t u = __float_as_uint(f);
    u += 0x7fffu + ((u >> 16) & 1u);
    return (ushort_t)(u >> 16);
}
__device__ __forceinline__ float bf2f(ushort_t s) {
    return __uint_as_float(((uint_t)s) << 16);
}

// ---------------- K0: pack conv weights into MFMA A-fragment order (bf16)
// wp[frag][lane][8], frag = (chunk*9 + tap)*8 + rt
// lane: row co = rt*16 + (lane&15); g = lane>>4; ci = chunk*32 + g*8 + j
template<int CIN>
__global__ __launch_bounds__(256) void k_wpack(const float* __restrict__ w,
                                               short* __restrict__ wp) {
    int idx = blockIdx.x * 256 + threadIdx.x;
    if (idx >= CIN * 1152) return;      // CIN*9*128 elements
    int j    = idx & 7;
    int lane = (idx >> 3) & 63;
    int frag = idx >> 9;
    int rt   = frag & 7;
    int tap  = (frag >> 3) % 9;
    int ch   = frag / 72;
    int co   = rt * 16 + (lane & 15);
    int g    = lane >> 4;
    int ci   = ch * 32 + g * 8 + j;
    wp[idx] = (short)f2bf(w[((size_t)co * CIN + ci) * 9 + tap]);
}

// ---------------- K1: fused position projections + attention, one block per (head, batch)
// writes att NHWC bf16: att[b][l][h*64+j]
__global__ __launch_bounds__(256) void k_pos_attn(
    const float* __restrict__ x,
    const float* __restrict__ wq, const float* __restrict__ bq,
    const float* __restrict__ wk, const float* __restrict__ bk,
    const float* __restrict__ wv, const float* __restrict__ bv,
    ushort_t* __restrict__ att)
{
    const int h = blockIdx.x;
    const int b = blockIdx.y;
    const int l = threadIdx.x;          // query row / spatial index

    __shared__ float    pk_s[NL][HD];   // 16 KB
    __shared__ ushort_t pv_s[NL][HDV];  // 32 KB (bf16)

    const float* xb = x + (size_t)b * NC * NL + l;

    float aq[HD], ak[HD];
    #pragma unroll
    for (int i = 0; i < HD; ++i) { aq[i] = bq[h*HD + i]; ak[i] = bk[h*HD + i]; }
    {
        const float* wqh = wq + (size_t)h * HD * NC;
        const float* wkh = wk + (size_t)h * HD * NC;
        for (int c4 = 0; c4 < NC/4; ++c4) {
            float x0 = xb[(4*c4+0)*NL];
            float x1 = xb[(4*c4+1)*NL];
            float x2 = xb[(4*c4+2)*NL];
            float x3 = xb[(4*c4+3)*NL];
            #pragma unroll
            for (int i = 0; i < HD; ++i) {
                float4 a = *(const float4*)(wqh + i*NC + 4*c4);
                aq[i] = fmaf(x0,a.x,fmaf(x1,a.y,fmaf(x2,a.z,fmaf(x3,a.w,aq[i]))));
                float4 k2 = *(const float4*)(wkh + i*NC + 4*c4);
                ak[i] = fmaf(x0,k2.x,fmaf(x1,k2.y,fmaf(x2,k2.z,fmaf(x3,k2.w,ak[i]))));
            }
        }
        #pragma unroll
        for (int i = 0; i < HD; ++i) pk_s[l][i] = ak[i];
    }
    {
        float av[HDV];
        #pragma unroll
        for (int j = 0; j < HDV; ++j) av[j] = bv[h*HDV + j];
        const float* wvh = wv + (size_t)h * HDV * NC;
        for (int c4 = 0; c4 < NC/4; ++c4) {
            float x0 = xb[(4*c4+0)*NL];
            float x1 = xb[(4*c4+1)*NL];
            float x2 = xb[(4*c4+2)*NL];
            float x3 = xb[(4*c4+3)*NL];
            #pragma unroll
            for (int j = 0; j < HDV; ++j) {
                float4 a = *(const float4*)(wvh + j*NC + 4*c4);
                av[j] = fmaf(x0,a.x,fmaf(x1,a.y,fmaf(x2,a.z,fmaf(x3,a.w,av[j]))));
            }
        }
        #pragma unroll
        for (int j = 0; j < HDV; ++j) pv_s[l][j] = f2bf(av[j]);
    }
    __syncthreads();

    float mx = -3.0e38f;
    for (int m = 0; m < NL; ++m) {
        const float4* pk4 = (const float4*)pk_s[m];
        float s = 0.f;
        #pragma unroll
        for (int i4 = 0; i4 < HD/4; ++i4) {
            float4 kk = pk4[i4];
            s = fmaf(aq[4*i4+0],kk.x,fmaf(aq[4*i4+1],kk.y,
                 fmaf(aq[4*i4+2],kk.z,fmaf(aq[4*i4+3],kk.w,s))));
        }
        mx = fmaxf(mx, s);
    }
    float outv[HDV];
    #pragma unroll
    for (int j = 0; j < HDV; ++j) outv[j] = 0.f;
    float den = 0.f;
    for (int m = 0; m < NL; ++m) {
        const float4* pk4 = (const float4*)pk_s[m];
        float s = 0.f;
        #pragma unroll
        for (int i4 = 0; i4 < HD/4; ++i4) {
            float4 kk = pk4[i4];
            s = fmaf(aq[4*i4+0],kk.x,fmaf(aq[4*i4+1],kk.y,
                 fmaf(aq[4*i4+2],kk.z,fmaf(aq[4*i4+3],kk.w,s))));
        }
        float wgt = __expf((s - mx) * 0.25f);
        den += wgt;
        const uint4* pv4 = (const uint4*)pv_s[m];
        #pragma unroll
        for (int k8 = 0; k8 < HDV/8; ++k8) {
            uint4 u = pv4[k8];
            outv[k8*8+0] = fmaf(wgt, __uint_as_float(u.x << 16),        outv[k8*8+0]);
            outv[k8*8+1] = fmaf(wgt, __uint_as_float(u.x & 0xffff0000u), outv[k8*8+1]);
            outv[k8*8+2] = fmaf(wgt, __uint_as_float(u.y << 16),        outv[k8*8+2]);
            outv[k8*8+3] = fmaf(wgt, __uint_as_float(u.y & 0xffff0000u), outv[k8*8+3]);
            outv[k8*8+4] = fmaf(wgt, __uint_as_float(u.z << 16),        outv[k8*8+4]);
            outv[k8*8+5] = fmaf(wgt, __uint_as_float(u.z & 0xffff0000u), outv[k8*8+5]);
            outv[k8*8+6] = fmaf(wgt, __uint_as_float(u.w << 16),        outv[k8*8+6]);
            outv[k8*8+7] = fmaf(wgt, __uint_as_float(u.w & 0xffff0000u), outv[k8*8+7]);
        }
    }
    const float inv = 1.f / den;
    // NHWC store: 32 packed dwords, contiguous
    uint_t* ap = (uint_t*)(att + (((size_t)b*NL + l)*NEV + h*HDV));
    #pragma unroll
    for (int j2 = 0; j2 < HDV/2; ++j2)
        ap[j2] = ((uint_t)f2bf(outv[2*j2+1]*inv) << 16) | (uint_t)f2bf(outv[2*j2]*inv);
}

// ---------------- K2/K4: 3x3 conv via MFMA implicit GEMM
// Block: 4 waves (2x2), tile 128co x 128l (l-half), grid (2, NB).
// LDS image: ims[y_p(10)][g(4)][x_p(18)][8ci] bf16, one 32-ci chunk at a time.
template<int CIN, bool INBF16, bool RES>
__global__ __launch_bounds__(256) void k_conv_mfma(
    const void* __restrict__ in_, const float* __restrict__ resid,
    const short* __restrict__ wp, const float* __restrict__ bias,
    const float* __restrict__ gamma,
    float* __restrict__ outF)
{
    constexpr int CHUNKS = CIN / 32;
    __shared__ __align__(16) short ims[10*4*18*8];   // 11.52 KB

    const int lhalf = blockIdx.x;
    const int b     = blockIdx.y;
    const int t     = threadIdx.x;
    const int lane  = t & 63;
    const int w     = t >> 6;
    const int wr    = w >> 1;          // co half (0/1)
    const int wc    = w & 1;           // l quarter within half (0/1)
    const int n     = lane & 15;
    const int g     = lane >> 4;
    const int y0    = lhalf * 8;

    // zero the x halo (x_p = 0 and 17) once; never rewritten
    {
        bf16x8 z = {0,0,0,0,0,0,0,0};
        for (int i = t; i < 80; i += 256) {
            int side = i & 1, gg = (i >> 1) & 3, yp = i >> 3;
            *(bf16x8*)&ims[((yp*4 + gg)*18 + side*17) * 8] = z;
        }
    }

    f32x4 acc[4][4];
    #pragma unroll
    for (int i = 0; i < 4; ++i)
        #pragma unroll
        for (int j = 0; j < 4; ++j) acc[i][j] = (f32x4){0.f,0.f,0.f,0.f};

    const short* wpl = wp + (size_t)lane * 8;
    const int laneoff = g * 18 + n;    // slot offset from (y-row base)

    for (int ch = 0; ch < CHUNKS; ++ch) {
        const int ci0 = ch * 32;
        __syncthreads();
        // ---- stage 32 ci x 10 padded rows x 16 x (interior); 640 tasks
        for (int task = t; task < 640; task += 256) {
            int gg = task & 3;
            int xx = (task >> 2) & 15;
            int yp = task >> 6;                 // 0..9
            int y  = y0 - 1 + yp;
            bf16x8 v = {0,0,0,0,0,0,0,0};
            if (y >= 0 && y < 16) {
                int l = y * 16 + xx;
                if constexpr (INBF16) {
                    v = *(const bf16x8*)((const ushort_t*)in_ +
                        ((size_t)(b*NL + l))*CIN + ci0 + gg*8);
                } else {
                    const float4* sp = (const float4*)((const float*)in_ +
                        ((size_t)(b*NL + l))*CIN + ci0 + gg*8);
                    float4 a = sp[0], c2 = sp[1];
                    v[0] = (short)f2bf(a.x);  v[1] = (short)f2bf(a.y);
                    v[2] = (short)f2bf(a.z);  v[3] = (short)f2bf(a.w);
                    v[4] = (short)f2bf(c2.x); v[5] = (short)f2bf(c2.y);
                    v[6] = (short)f2bf(c2.z); v[7] = (short)f2bf(c2.w);
                }
            }
            *(bf16x8*)&ims[((yp*4 + gg)*18 + xx + 1) * 8] = v;
        }
        __syncthreads();
        // ---- compute: 9 taps x (4 A-frags global, 4 B-frags LDS, 16 MFMA)
        #pragma unroll
        for (int tap = 0; tap < 9; ++tap) {
            const int dy = tap / 3, dx = tap % 3;
            bf16x8 Bf[4];
            #pragma unroll
            for (int ct = 0; ct < 4; ++ct) {
                int yrow = wc*4 + ct + dy;          // 0..9
                Bf[ct] = *(const bf16x8*)&ims[(yrow*72 + laneoff + dx) * 8];
            }
            bf16x8 Af[4];
            #pragma unroll
            for (int rt = 0; rt < 4; ++rt) {
                int frag = (ch*9 + tap)*8 + wr*4 + rt;
                Af[rt] = *(const bf16x8*)(wpl + (size_t)frag * 512);
            }
            #pragma unroll
            for (int rt = 0; rt < 4; ++rt)
                #pragma unroll
                for (int ct = 0; ct < 4; ++ct)
                    acc[rt][ct] = __builtin_amdgcn_mfma_f32_16x16x32_bf16(
                        Af[rt], Bf[ct], acc[rt][ct], 0, 0, 0);
        }
    }

    // ---- epilogue
    if constexpr (RES) {
        const float g0 = gamma[0];
        #pragma unroll
        for (int rt = 0; rt < 4; ++rt) {
            const int co0 = wr*64 + rt*16 + g*4;
            const float b0 = bias[co0+0], b1 = bias[co0+1],
                        b2 = bias[co0+2], b3 = bias[co0+3];
            #pragma unroll
            for (int ct = 0; ct < 4; ++ct) {
                const int l = lhalf*128 + wc*64 + ct*16 + n;
                f32x4 a = acc[rt][ct];
                float4 r;
                r.x = 0.5f*(resid[((size_t)b*NC + co0+0)*NL + l] + g0*(b0 + a[0]));
                r.y = 0.5f*(resid[((size_t)b*NC + co0+1)*NL + l] + g0*(b1 + a[1]));
                r.z = 0.5f*(resid[((size_t)b*NC + co0+2)*NL + l] + g0*(b2 + a[2]));
                r.w = 0.5f*(resid[((size_t)b*NC + co0+3)*NL + l] + g0*(b3 + a[3]));
                *(float4*)(outF + ((size_t)b*NL + l)*NC + co0) = r;   // NHWC comb
            }
        }
    } else {
        #pragma unroll
        for (int rt = 0; rt < 4; ++rt) {
            const int co0 = wr*64 + rt*16 + g*4;
            const float b0 = bias[co0+0], b1 = bias[co0+1],
                        b2 = bias[co0+2], b3 = bias[co0+3];
            #pragma unroll
            for (int ct = 0; ct < 4; ++ct) {
                const int l = lhalf*128 + wc*64 + ct*16 + n;
                f32x4 a = acc[rt][ct];
                outF[((size_t)b*NC + co0+0)*NL + l] = b0 + a[0];      // NCHW out
                outF[((size_t)b*NC + co0+1)*NL + l] = b1 + a[1];
                outF[((size_t)b*NC + co0+2)*NL + l] = b2 + a[2];
                outF[((size_t)b*NC + co0+3)*NL + l] = b3 + a[3];
            }
        }
    }
}

// ---------------- K3: channel attention (block-diagonal, gram-collapsed) + fusion
#define NLP 260
__global__ __launch_bounds__(256) void k_cha(
    const float* __restrict__ xc,
    const float* __restrict__ cwq, const float* __restrict__ cbq,
    const float* __restrict__ cwk, const float* __restrict__ cbk,
    const float* __restrict__ cwv, const float* __restrict__ cbv,
    const float* __restrict__ cwo, const float* __restrict__ cbo,
    const float* __restrict__ gamma,
    float* __restrict__ comb)
{
    const int h = blockIdx.x, b = blockIdx.y, t = threadIdx.x;
    __shared__ float qh[16][NLP];
    __shared__ float G_s[16][17];
    __shared__ float S_s[16];
    __shared__ float wq_s[128], bq_s[128], wk_s[128], bk_s[128], wv_s[128], bv_s[128];
    __shared__ float A_s[128][17];
    __shared__ float B_s[128];
    __shared__ float M_s[16][17];
    __shared__ float c_s[16];

    #pragma unroll
    for (int j = 0; j < 16; ++j)
        qh[j][t] = xc[((size_t)b*NC + h*16 + j)*NL + t];
    if (t < 128) {
        const int k = h*128 + t;
        wq_s[t] = cwq[k]; bq_s[t] = cbq[k];
        wk_s[t] = cwk[k]; bk_s[t] = cbk[k];
        wv_s[t] = cwv[k]; bv_s[t] = cbv[k];
    }
    __syncthreads();
    {
        const int i = t >> 4, j = t & 15;
        const float4* qi = (const float4*)qh[i];
        const float4* qj = (const float4*)qh[j];
        float gg = 0.f;
        for (int l4 = 0; l4 < NL/4; ++l4) {
            float4 a = qi[l4], c = qj[l4];
            gg = fmaf(a.x,c.x,fmaf(a.y,c.y,fmaf(a.z,c.z,fmaf(a.w,c.w,gg))));
        }
        G_s[i][j] = gg;
    }
    if (t < 16) {
        const float4* qi = (const float4*)qh[t];
        float s = 0.f;
        for (int l4 = 0; l4 < NL/4; ++l4) { float4 a = qi[l4]; s += a.x + a.y + a.z + a.w; }
        S_s[t] = s;
    }
    __syncthreads();
    if (t < 128) {
        const int c2 = t, cg = c2 >> 3;
        const float wqc = wq_s[c2], bqc = bq_s[c2];
        float P[16];
        #pragma unroll
        for (int j = 0; j < 16; ++j) P[j] = wqc*G_s[cg][j] + bqc*S_s[j];
        const float Qc = wqc*S_s[cg] + bqc*256.0f;
        float mx = -3.0e38f;
        #pragma unroll
        for (int dg = 0; dg < 16; ++dg) {
            #pragma unroll
            for (int dj = 0; dj < 8; ++dj) {
                const int d = dg*8 + dj;
                float s = wk_s[d]*P[dg] + bk_s[d]*Qc;
                mx = fmaxf(mx, s);
            }
        }
        float A[16];
        #pragma unroll
        for (int j = 0; j < 16; ++j) A[j] = 0.f;
        float Bv = 0.f, den = 0.f;
        #pragma unroll
        for (int dg = 0; dg < 16; ++dg) {
            #pragma unroll
            for (int dj = 0; dj < 8; ++dj) {
                const int d = dg*8 + dj;
                float s = wk_s[d]*P[dg] + bk_s[d]*Qc;
                float e = __expf((s - mx) * 0.0625f);
                den += e;
                A[dg] = fmaf(e, wv_s[d], A[dg]);
                Bv = fmaf(e, bv_s[d], Bv);
            }
        }
        const float inv = 1.f / den;
        #pragma unroll
        for (int j = 0; j < 16; ++j) A_s[c2][j] = A[j]*inv;
        B_s[c2] = Bv*inv;
    }
    __syncthreads();
    {
        const int cl = t >> 4, j = t & 15;
        const int cp = h*16 + cl;
        float m = 0.f;
        #pragma unroll
        for (int hp = 0; hp < 8; ++hp)
            m = fmaf(cwo[cp*8+hp], A_s[cl*8+hp][j], m);
        M_s[cl][j] = m;
        if (j == 0) {
            float cc = cbo[cp];
            #pragma unroll
            for (int hp = 0; hp < 8; ++hp)
                cc = fmaf(cwo[cp*8+hp], B_s[cl*8+hp], cc);
            c_s[cl] = cc;
        }
    }
    __syncthreads();
    {   // comb (NHWC f32) += 0.5*(out_cha);  out_cha = xc + g*(c + M@qh)
        const float g = gamma[0];
        const int l = t;
        float av[16];
        #pragma unroll
        for (int cl = 0; cl < 16; ++cl) {
            float a = c_s[cl];
            #pragma unroll
            for (int j = 0; j < 16; ++j)
                a = fmaf(M_s[cl][j], qh[j][l], a);
            av[cl] = a;
        }
        float4* cp4 = (float4*)(comb + ((size_t)b*NL + l)*NC + h*16);
        #pragma unroll
        for (int q = 0; q < 4; ++q) {
            float4 c = cp4[q];
            c.x += 0.5f*(qh[4*q+0][l] + g*av[4*q+0]);
            c.y += 0.5f*(qh[4*q+1][l] + g*av[4*q+1]);
            c.z += 0.5f*(qh[4*q+2][l] + g*av[4*q+2]);
            c.w += 0.5f*(qh[4*q+3][l] + g*av[4*q+3]);
            cp4[q] = c;
        }
    }
}

extern "C" void kernel_launch(void* const* d_in, const int* in_sizes, int n_in,
                              void* d_out, int out_size, void* d_ws, size_t ws_size,
                              hipStream_t stream)
{
    const float* qpos = (const float*)d_in[0];
    const float* qcha = (const float*)d_in[1];
    const float* pwq  = (const float*)d_in[2];
    const float* pbq  = (const float*)d_in[3];
    const float* pwk  = (const float*)d_in[4];
    const float* pbk  = (const float*)d_in[5];
    const float* pwv  = (const float*)d_in[6];
    const float* pbv  = (const float*)d_in[7];
    const float* pwo  = (const float*)d_in[8];
    const float* pbo  = (const float*)d_in[9];
    const float* gpos = (const float*)d_in[10];
    const float* cwq  = (const float*)d_in[11];
    const float* cbq  = (const float*)d_in[12];
    const float* cwk  = (const float*)d_in[13];
    const float* cbk  = (const float*)d_in[14];
    const float* cwv  = (const float*)d_in[15];
    const float* cbv  = (const float*)d_in[16];
    const float* cwo  = (const float*)d_in[17];
    const float* cbo  = (const float*)d_in[18];
    const float* gcha = (const float*)d_in[19];
    const float* fw   = (const float*)d_in[20];
    const float* fb   = (const float*)d_in[21];
    float* outp = (float*)d_out;

    char* ws = (char*)d_ws;
    ushort_t* att  = (ushort_t*)ws;                       // 33,554,432 B  (NHWC bf16)
    float*    comb = (float*)(ws + 33554432);             // 16,777,216 B  (NHWC f32)
    short*    wp1  = (short*)(ws + 50331648);             //  1,179,648 B
    short*    wp2  = (short*)(ws + 51511296);             //    294,912 B

    k_wpack<NEV><<<dim3((NEV*1152 + 255)/256), 256, 0, stream>>>(pwo, wp1);
    k_wpack<NC ><<<dim3((NC *1152 + 255)/256), 256, 0, stream>>>(fw,  wp2);

    k_pos_attn<<<dim3(NH, NB), 256, 0, stream>>>(qpos, pwq, pbq, pwk, pbk, pwv, pbv, att);
    k_conv_mfma<NEV, true,  true ><<<dim3(2, NB), 256, 0, stream>>>(
        att, qpos, wp1, pbo, gpos, comb);
    k_cha<<<dim3(NH, NB), 256, 0, stream>>>(qcha, cwq, cbq, cwk, cbk, cwv, cbv,
                                            cwo, cbo, gcha, comb);
    k_conv_mfma<NC, false, false><<<dim3(2, NB), 256, 0, stream>>>(
        comb, nullptr, wp2, fb, nullptr, outp);
}

// Round 3
// 306.344 us; speedup vs baseline: 4.7451x; 2.4771x over previous
//
#include <hip/hip_runtime.h>
#include <cstdint>
#include <cstddef>

typedef unsigned short ushort_t;
typedef unsigned int uint_t;
typedef __attribute__((ext_vector_type(8))) short bf16x8;
typedef __attribute__((ext_vector_type(4))) float f32x4;

#define NB 128
#define NC 128
#define NL 256
#define NH 8
#define HD 16
#define HDV 64
#define NEV 512

__device__ __forceinline__ ushort_t f2bf(float f) {
    uint_t u = __float_as_uint(f);
    u += 0x7fffu + ((u >> 16) & 1u);
    return (ushort_t)(u >> 16);
}
__device__ __forceinline__ float bf2f(ushort_t s) {
    return __uint_as_float(((uint_t)s) << 16);
}
__device__ __forceinline__ uint_t pack2(float lo, float hi) {
    return ((uint_t)f2bf(hi) << 16) | (uint_t)f2bf(lo);
}

// ---------------- K0: pack conv weights into MFMA A-fragment order (bf16)
template<int CIN>
__global__ __launch_bounds__(256) void k_wpack(const float* __restrict__ w,
                                               short* __restrict__ wp) {
    int idx = blockIdx.x * 256 + threadIdx.x;
    if (idx >= CIN * 1152) return;      // CIN*9*128 elements
    int j    = idx & 7;
    int lane = (idx >> 3) & 63;
    int frag = idx >> 9;
    int rt   = frag & 7;
    int tap  = (frag >> 3) % 9;
    int ch   = frag / 72;
    int co   = rt * 16 + (lane & 15);
    int g    = lane >> 4;
    int ci   = ch * 32 + g * 8 + j;
    wp[idx] = (short)f2bf(w[((size_t)co * CIN + ci) * 9 + tap]);
}

// ---------------- K0b: pack projection weights (E x 128) into A-frag order
// wp[((rt*4 + ch)*64 + lane)*8 + j] = W[rt*16 + (lane&15)][ch*32 + (lane>>4)*8 + j]
template<int E>
__global__ __launch_bounds__(256) void k_wpack_qkv(const float* __restrict__ w,
                                                   short* __restrict__ wp) {
    int idx = blockIdx.x * 256 + threadIdx.x;
    if (idx >= E * 128) return;
    int j    = idx & 7;
    int lane = (idx >> 3) & 63;
    int ch   = (idx >> 9) & 3;
    int rt   = idx >> 11;
    int n = lane & 15, g = lane >> 4;
    wp[idx] = (short)f2bf(w[(size_t)(rt*16 + n)*128 + ch*32 + g*8 + j]);
}

// ---------------- K1: full-MFMA position attention. Block = (h, b), 4 waves.
// LDS map (shorts): [0,10240) XT[256][40] (phase A) / PQT_w@w*1024 [64][16] + PB_w@4096+w*640 [16][40] (phase B)
//                   [10240,14336) PKT[256][16]
//                   [14336,31232) PVT[64][264]
__global__ __launch_bounds__(256) void k_pos_mfma(
    const float* __restrict__ x,
    const short* __restrict__ wpq, const short* __restrict__ wpk,
    const short* __restrict__ wpv,
    const float* __restrict__ bq, const float* __restrict__ bk,
    const float* __restrict__ bv,
    ushort_t* __restrict__ att)
{
    const int h = blockIdx.x, b = blockIdx.y;
    const int t = threadIdx.x;
    const int lane = t & 63, w = t >> 6;
    const int n = lane & 15, g = lane >> 4;

    __shared__ __align__(16) short lds[31232];

    const f32x4 z4 = {0.f, 0.f, 0.f, 0.f};
    f32x4 qacc[4], kacc[4], vacc[16];
    #pragma unroll
    for (int ct = 0; ct < 4; ++ct) { qacc[ct] = z4; kacc[ct] = z4; }
    #pragma unroll
    for (int i = 0; i < 16; ++i) vacc[i] = z4;

    const float* xg = x + (size_t)b * NC * NL + t;

    // ---- Phase A: projections, 4 k-chunks of 32 channels
    #pragma unroll 1
    for (int ch = 0; ch < 4; ++ch) {
        __syncthreads();
        #pragma unroll
        for (int k8 = 0; k8 < 4; ++k8) {
            bf16x8 v8;
            #pragma unroll
            for (int jj = 0; jj < 8; ++jj)
                v8[jj] = (short)f2bf(xg[(ch*32 + k8*8 + jj) * NL]);
            *(bf16x8*)&lds[t*40 + k8*8] = v8;
        }
        __syncthreads();
        bf16x8 xb[4];
        #pragma unroll
        for (int ct = 0; ct < 4; ++ct)
            xb[ct] = *(const bf16x8*)&lds[(w*64 + ct*16 + n)*40 + g*8];
        const size_t fo = ((size_t)((h*4 + ch)*64) + lane) * 8;
        {
            bf16x8 aq = *(const bf16x8*)(wpq + fo);
            #pragma unroll
            for (int ct = 0; ct < 4; ++ct)
                qacc[ct] = __builtin_amdgcn_mfma_f32_16x16x32_bf16(aq, xb[ct], qacc[ct], 0, 0, 0);
        }
        {
            bf16x8 ak = *(const bf16x8*)(wpk + fo);
            #pragma unroll
            for (int ct = 0; ct < 4; ++ct)
                kacc[ct] = __builtin_amdgcn_mfma_f32_16x16x32_bf16(ak, xb[ct], kacc[ct], 0, 0, 0);
        }
        #pragma unroll
        for (int vt = 0; vt < 4; ++vt) {
            bf16x8 av = *(const bf16x8*)(wpv + ((size_t)((((h*4 + vt)*4) + ch)*64) + lane) * 8);
            #pragma unroll
            for (int ct = 0; ct < 4; ++ct)
                vacc[vt*4+ct] = __builtin_amdgcn_mfma_f32_16x16x32_bf16(av, xb[ct], vacc[vt*4+ct], 0, 0, 0);
        }
    }
    __syncthreads();   // all XT reads done; XT region reusable

    // ---- biases (loaded late to keep phase-A VGPR down), then LDS writes
    {
        float bqv[4], bkv[4];
        #pragma unroll
        for (int r = 0; r < 4; ++r) {
            bqv[r] = bq[h*16 + g*4 + r];
            bkv[r] = bk[h*16 + g*4 + r];
        }
        #pragma unroll
        for (int ct = 0; ct < 4; ++ct) {
            uint2 qp, kp;
            qp.x = pack2(qacc[ct][0] + bqv[0], qacc[ct][1] + bqv[1]);
            qp.y = pack2(qacc[ct][2] + bqv[2], qacc[ct][3] + bqv[3]);
            *(uint2*)&lds[w*1024 + (ct*16 + n)*16 + g*4] = qp;
            kp.x = pack2(kacc[ct][0] + bkv[0], kacc[ct][1] + bkv[1]);
            kp.y = pack2(kacc[ct][2] + bkv[2], kacc[ct][3] + bkv[3]);
            *(uint2*)&lds[10240 + (w*64 + ct*16 + n)*16 + g*4] = kp;
        }
        #pragma unroll
        for (int vt = 0; vt < 4; ++vt) {
            float bv0 = bv[h*64 + vt*16 + g*4 + 0];
            float bv1 = bv[h*64 + vt*16 + g*4 + 1];
            float bv2 = bv[h*64 + vt*16 + g*4 + 2];
            float bv3 = bv[h*64 + vt*16 + g*4 + 3];
            #pragma unroll
            for (int ct = 0; ct < 4; ++ct) {
                const int col = w*64 + ct*16 + n;
                lds[14336 + (vt*16 + g*4 + 0)*264 + col] = (short)f2bf(vacc[vt*4+ct][0] + bv0);
                lds[14336 + (vt*16 + g*4 + 1)*264 + col] = (short)f2bf(vacc[vt*4+ct][1] + bv1);
                lds[14336 + (vt*16 + g*4 + 2)*264 + col] = (short)f2bf(vacc[vt*4+ct][2] + bv2);
                lds[14336 + (vt*16 + g*4 + 3)*264 + col] = (short)f2bf(vacc[vt*4+ct][3] + bv3);
            }
        }
    }
    __syncthreads();

    // ---- Phase B: per wave, 4 q-tiles of 16 q (wave owns q in [w*64, w*64+64))
    #pragma unroll 1
    for (int qt = 0; qt < 4; ++qt) {
        bf16x8 qf = (bf16x8){0,0,0,0,0,0,0,0};
        if (g < 2) qf = *(const bf16x8*)&lds[w*1024 + (qt*16 + n)*16 + g*8];
        f32x4 s[16];
        #pragma unroll
        for (int kt = 0; kt < 16; ++kt) {
            bf16x8 kf = (bf16x8){0,0,0,0,0,0,0,0};
            if (g < 2) kf = *(const bf16x8*)&lds[10240 + (kt*16 + n)*16 + g*8];
            s[kt] = __builtin_amdgcn_mfma_f32_16x16x32_bf16(kf, qf, z4, 0, 0, 0);
        }
        // softmax over k: 64 in-lane + lanes {n, n+16, n+32, n+48}
        float m = -3.0e38f;
        #pragma unroll
        for (int kt = 0; kt < 16; ++kt)
            #pragma unroll
            for (int r = 0; r < 4; ++r)
                m = fmaxf(m, s[kt][r]);
        m = fmaxf(m, __shfl_xor(m, 16));
        m = fmaxf(m, __shfl_xor(m, 32));
        float den = 0.f;
        #pragma unroll
        for (int kt = 0; kt < 16; ++kt)
            #pragma unroll
            for (int r = 0; r < 4; ++r) {
                float e = __expf((s[kt][r] - m) * 0.25f);
                s[kt][r] = e;
                den += e;
            }
        den += __shfl_xor(den, 16);
        den += __shfl_xor(den, 32);
        const float inv = 1.f / den;

        f32x4 oacc[4] = {z4, z4, z4, z4};
        #pragma unroll
        for (int c2 = 0; c2 < 8; ++c2) {
            #pragma unroll
            for (int u = 0; u < 2; ++u) {
                const int kt = 2*c2 + u;
                uint2 pp;
                pp.x = pack2(s[kt][0], s[kt][1]);
                pp.y = pack2(s[kt][2], s[kt][3]);
                *(uint2*)&lds[4096 + w*640 + n*40 + u*16 + g*4] = pp;
            }
            bf16x8 pf = *(const bf16x8*)&lds[4096 + w*640 + n*40 + g*8];
            #pragma unroll
            for (int vt = 0; vt < 4; ++vt) {
                bf16x8 av = *(const bf16x8*)&lds[14336 + (vt*16 + n)*264 + c2*32 + g*8];
                oacc[vt] = __builtin_amdgcn_mfma_f32_16x16x32_bf16(av, pf, oacc[vt], 0, 0, 0);
            }
        }
        // epilogue: O[q][dv] bf16, NHWC att[b][q][h*64+dv]
        ushort_t* ap = att + (((size_t)b*NL + (w*64 + qt*16 + n))*NEV + h*HDV + g*4);
        #pragma unroll
        for (int vt = 0; vt < 4; ++vt) {
            uint2 op;
            op.x = pack2(oacc[vt][0]*inv, oacc[vt][1]*inv);
            op.y = pack2(oacc[vt][2]*inv, oacc[vt][3]*inv);
            *(uint2*)(ap + vt*16) = op;
        }
    }
}

// ---------------- K2/K4: 3x3 conv via MFMA implicit GEMM
template<int CIN, bool INBF16, bool RES>
__global__ __launch_bounds__(256) void k_conv_mfma(
    const void* __restrict__ in_, const float* __restrict__ resid,
    const short* __restrict__ wp, const float* __restrict__ bias,
    const float* __restrict__ gamma,
    float* __restrict__ outF)
{
    constexpr int CHUNKS = CIN / 32;
    __shared__ __align__(16) short ims[10*4*18*8];   // 11.52 KB

    const int lhalf = blockIdx.x;
    const int b     = blockIdx.y;
    const int t     = threadIdx.x;
    const int lane  = t & 63;
    const int w     = t >> 6;
    const int wr    = w >> 1;
    const int wc    = w & 1;
    const int n     = lane & 15;
    const int g     = lane >> 4;
    const int y0    = lhalf * 8;

    {
        bf16x8 z = {0,0,0,0,0,0,0,0};
        for (int i = t; i < 80; i += 256) {
            int side = i & 1, gg = (i >> 1) & 3, yp = i >> 3;
            *(bf16x8*)&ims[((yp*4 + gg)*18 + side*17) * 8] = z;
        }
    }

    f32x4 acc[4][4];
    #pragma unroll
    for (int i = 0; i < 4; ++i)
        #pragma unroll
        for (int j = 0; j < 4; ++j) acc[i][j] = (f32x4){0.f,0.f,0.f,0.f};

    const short* wpl = wp + (size_t)lane * 8;
    const int laneoff = g * 18 + n;

    for (int ch = 0; ch < CHUNKS; ++ch) {
        const int ci0 = ch * 32;
        __syncthreads();
        for (int task = t; task < 640; task += 256) {
            int gg = task & 3;
            int xx = (task >> 2) & 15;
            int yp = task >> 6;
            int y  = y0 - 1 + yp;
            bf16x8 v = {0,0,0,0,0,0,0,0};
            if (y >= 0 && y < 16) {
                int l = y * 16 + xx;
                if constexpr (INBF16) {
                    v = *(const bf16x8*)((const ushort_t*)in_ +
                        ((size_t)(b*NL + l))*CIN + ci0 + gg*8);
                } else {
                    const float4* sp = (const float4*)((const float*)in_ +
                        ((size_t)(b*NL + l))*CIN + ci0 + gg*8);
                    float4 a = sp[0], c2 = sp[1];
                    v[0] = (short)f2bf(a.x);  v[1] = (short)f2bf(a.y);
                    v[2] = (short)f2bf(a.z);  v[3] = (short)f2bf(a.w);
                    v[4] = (short)f2bf(c2.x); v[5] = (short)f2bf(c2.y);
                    v[6] = (short)f2bf(c2.z); v[7] = (short)f2bf(c2.w);
                }
            }
            *(bf16x8*)&ims[((yp*4 + gg)*18 + xx + 1) * 8] = v;
        }
        __syncthreads();
        #pragma unroll
        for (int tap = 0; tap < 9; ++tap) {
            const int dy = tap / 3, dx = tap % 3;
            bf16x8 Bf[4];
            #pragma unroll
            for (int ct = 0; ct < 4; ++ct) {
                int yrow = wc*4 + ct + dy;
                Bf[ct] = *(const bf16x8*)&ims[(yrow*72 + laneoff + dx) * 8];
            }
            bf16x8 Af[4];
            #pragma unroll
            for (int rt = 0; rt < 4; ++rt) {
                int frag = (ch*9 + tap)*8 + wr*4 + rt;
                Af[rt] = *(const bf16x8*)(wpl + (size_t)frag * 512);
            }
            #pragma unroll
            for (int rt = 0; rt < 4; ++rt)
                #pragma unroll
                for (int ct = 0; ct < 4; ++ct)
                    acc[rt][ct] = __builtin_amdgcn_mfma_f32_16x16x32_bf16(
                        Af[rt], Bf[ct], acc[rt][ct], 0, 0, 0);
        }
    }

    if constexpr (RES) {
        const float g0 = gamma[0];
        #pragma unroll
        for (int rt = 0; rt < 4; ++rt) {
            const int co0 = wr*64 + rt*16 + g*4;
            const float b0 = bias[co0+0], b1 = bias[co0+1],
                        b2 = bias[co0+2], b3 = bias[co0+3];
            #pragma unroll
            for (int ct = 0; ct < 4; ++ct) {
                const int l = lhalf*128 + wc*64 + ct*16 + n;
                f32x4 a = acc[rt][ct];
                float4 r;
                r.x = 0.5f*(resid[((size_t)b*NC + co0+0)*NL + l] + g0*(b0 + a[0]));
                r.y = 0.5f*(resid[((size_t)b*NC + co0+1)*NL + l] + g0*(b1 + a[1]));
                r.z = 0.5f*(resid[((size_t)b*NC + co0+2)*NL + l] + g0*(b2 + a[2]));
                r.w = 0.5f*(resid[((size_t)b*NC + co0+3)*NL + l] + g0*(b3 + a[3]));
                *(float4*)(outF + ((size_t)b*NL + l)*NC + co0) = r;
            }
        }
    } else {
        #pragma unroll
        for (int rt = 0; rt < 4; ++rt) {
            const int co0 = wr*64 + rt*16 + g*4;
            const float b0 = bias[co0+0], b1 = bias[co0+1],
                        b2 = bias[co0+2], b3 = bias[co0+3];
            #pragma unroll
            for (int ct = 0; ct < 4; ++ct) {
                const int l = lhalf*128 + wc*64 + ct*16 + n;
                f32x4 a = acc[rt][ct];
                outF[((size_t)b*NC + co0+0)*NL + l] = b0 + a[0];
                outF[((size_t)b*NC + co0+1)*NL + l] = b1 + a[1];
                outF[((size_t)b*NC + co0+2)*NL + l] = b2 + a[2];
                outF[((size_t)b*NC + co0+3)*NL + l] = b3 + a[3];
            }
        }
    }
}

// ---------------- K3: channel attention (block-diagonal, gram-collapsed) + fusion
#define NLP 260
__global__ __launch_bounds__(256) void k_cha(
    const float* __restrict__ xc,
    const float* __restrict__ cwq, const float* __restrict__ cbq,
    const float* __restrict__ cwk, const float* __restrict__ cbk,
    const float* __restrict__ cwv, const float* __restrict__ cbv,
    const float* __restrict__ cwo, const float* __restrict__ cbo,
    const float* __restrict__ gamma,
    float* __restrict__ comb)
{
    const int h = blockIdx.x, b = blockIdx.y, t = threadIdx.x;
    __shared__ float qh[16][NLP];
    __shared__ float G_s[16][17];
    __shared__ float S_s[16];
    __shared__ float wq_s[128], bq_s[128], wk_s[128], bk_s[128], wv_s[128], bv_s[128];
    __shared__ float A_s[128][17];
    __shared__ float B_s[128];
    __shared__ float M_s[16][17];
    __shared__ float c_s[16];

    #pragma unroll
    for (int j = 0; j < 16; ++j)
        qh[j][t] = xc[((size_t)b*NC + h*16 + j)*NL + t];
    if (t < 128) {
        const int k = h*128 + t;
        wq_s[t] = cwq[k]; bq_s[t] = cbq[k];
        wk_s[t] = cwk[k]; bk_s[t] = cbk[k];
        wv_s[t] = cwv[k]; bv_s[t] = cbv[k];
    }
    __syncthreads();
    {
        const int i = t >> 4, j = t & 15;
        const float4* qi = (const float4*)qh[i];
        const float4* qj = (const float4*)qh[j];
        float gg = 0.f;
        for (int l4 = 0; l4 < NL/4; ++l4) {
            float4 a = qi[l4], c = qj[l4];
            gg = fmaf(a.x,c.x,fmaf(a.y,c.y,fmaf(a.z,c.z,fmaf(a.w,c.w,gg))));
        }
        G_s[i][j] = gg;
    }
    if (t < 16) {
        const float4* qi = (const float4*)qh[t];
        float s = 0.f;
        for (int l4 = 0; l4 < NL/4; ++l4) { float4 a = qi[l4]; s += a.x + a.y + a.z + a.w; }
        S_s[t] = s;
    }
    __syncthreads();
    if (t < 128) {
        const int c2 = t, cg = c2 >> 3;
        const float wqc = wq_s[c2], bqc = bq_s[c2];
        float P[16];
        #pragma unroll
        for (int j = 0; j < 16; ++j) P[j] = wqc*G_s[cg][j] + bqc*S_s[j];
        const float Qc = wqc*S_s[cg] + bqc*256.0f;
        float mx = -3.0e38f;
        #pragma unroll
        for (int dg = 0; dg < 16; ++dg) {
            #pragma unroll
            for (int dj = 0; dj < 8; ++dj) {
                const int d = dg*8 + dj;
                float s = wk_s[d]*P[dg] + bk_s[d]*Qc;
                mx = fmaxf(mx, s);
            }
        }
        float A[16];
        #pragma unroll
        for (int j = 0; j < 16; ++j) A[j] = 0.f;
        float Bv = 0.f, den = 0.f;
        #pragma unroll
        for (int dg = 0; dg < 16; ++dg) {
            #pragma unroll
            for (int dj = 0; dj < 8; ++dj) {
                const int d = dg*8 + dj;
                float s = wk_s[d]*P[dg] + bk_s[d]*Qc;
                float e = __expf((s - mx) * 0.0625f);
                den += e;
                A[dg] = fmaf(e, wv_s[d], A[dg]);
                Bv = fmaf(e, bv_s[d], Bv);
            }
        }
        const float inv = 1.f / den;
        #pragma unroll
        for (int j = 0; j < 16; ++j) A_s[c2][j] = A[j]*inv;
        B_s[c2] = Bv*inv;
    }
    __syncthreads();
    {
        const int cl = t >> 4, j = t & 15;
        const int cp = h*16 + cl;
        float m = 0.f;
        #pragma unroll
        for (int hp = 0; hp < 8; ++hp)
            m = fmaf(cwo[cp*8+hp], A_s[cl*8+hp][j], m);
        M_s[cl][j] = m;
        if (j == 0) {
            float cc = cbo[cp];
            #pragma unroll
            for (int hp = 0; hp < 8; ++hp)
                cc = fmaf(cwo[cp*8+hp], B_s[cl*8+hp], cc);
            c_s[cl] = cc;
        }
    }
    __syncthreads();
    {
        const float g = gamma[0];
        const int l = t;
        float av[16];
        #pragma unroll
        for (int cl = 0; cl < 16; ++cl) {
            float a = c_s[cl];
            #pragma unroll
            for (int j = 0; j < 16; ++j)
                a = fmaf(M_s[cl][j], qh[j][l], a);
            av[cl] = a;
        }
        float4* cp4 = (float4*)(comb + ((size_t)b*NL + l)*NC + h*16);
        #pragma unroll
        for (int q = 0; q < 4; ++q) {
            float4 c = cp4[q];
            c.x += 0.5f*(qh[4*q+0][l] + g*av[4*q+0]);
            c.y += 0.5f*(qh[4*q+1][l] + g*av[4*q+1]);
            c.z += 0.5f*(qh[4*q+2][l] + g*av[4*q+2]);
            c.w += 0.5f*(qh[4*q+3][l] + g*av[4*q+3]);
            cp4[q] = c;
        }
    }
}

extern "C" void kernel_launch(void* const* d_in, const int* in_sizes, int n_in,
                              void* d_out, int out_size, void* d_ws, size_t ws_size,
                              hipStream_t stream)
{
    const float* qpos = (const float*)d_in[0];
    const float* qcha = (const float*)d_in[1];
    const float* pwq  = (const float*)d_in[2];
    const float* pbq  = (const float*)d_in[3];
    const float* pwk  = (const float*)d_in[4];
    const float* pbk  = (const float*)d_in[5];
    const float* pwv  = (const float*)d_in[6];
    const float* pbv  = (const float*)d_in[7];
    const float* pwo  = (const float*)d_in[8];
    const float* pbo  = (const float*)d_in[9];
    const float* gpos = (const float*)d_in[10];
    const float* cwq  = (const float*)d_in[11];
    const float* cbq  = (const float*)d_in[12];
    const float* cwk  = (const float*)d_in[13];
    const float* cbk  = (const float*)d_in[14];
    const float* cwv  = (const float*)d_in[15];
    const float* cbv  = (const float*)d_in[16];
    const float* cwo  = (const float*)d_in[17];
    const float* cbo  = (const float*)d_in[18];
    const float* gcha = (const float*)d_in[19];
    const float* fw   = (const float*)d_in[20];
    const float* fb   = (const float*)d_in[21];
    float* outp = (float*)d_out;

    char* ws = (char*)d_ws;
    ushort_t* att  = (ushort_t*)ws;                       // 33,554,432 B  (NHWC bf16)
    float*    comb = (float*)(ws + 33554432);             // 16,777,216 B  (NHWC f32)
    short*    wp1  = (short*)(ws + 50331648);             //  1,179,648 B
    short*    wp2  = (short*)(ws + 51511296);             //    294,912 B
    short*    wpq  = (short*)(ws + 51806208);             //     32,768 B
    short*    wpk  = (short*)(ws + 51838976);             //     32,768 B
    short*    wpv  = (short*)(ws + 51871744);             //    131,072 B

    k_wpack<NEV><<<dim3((NEV*1152 + 255)/256), 256, 0, stream>>>(pwo, wp1);
    k_wpack<NC ><<<dim3((NC *1152 + 255)/256), 256, 0, stream>>>(fw,  wp2);
    k_wpack_qkv<128><<<dim3(64),  256, 0, stream>>>(pwq, wpq);
    k_wpack_qkv<128><<<dim3(64),  256, 0, stream>>>(pwk, wpk);
    k_wpack_qkv<512><<<dim3(256), 256, 0, stream>>>(pwv, wpv);

    k_pos_mfma<<<dim3(NH, NB), 256, 0, stream>>>(qpos, wpq, wpk, wpv,
                                                 pbq, pbk, pbv, att);
    k_conv_mfma<NEV, true,  true ><<<dim3(2, NB), 256, 0, stream>>>(
        att, qpos, wp1, pbo, gpos, comb);
    k_cha<<<dim3(NH, NB), 256, 0, stream>>>(qcha, cwq, cbq, cwk, cbk, cwv, cbv,
                                            cwo, cbo, gcha, comb);
    k_conv_mfma<NC, false, false><<<dim3(2, NB), 256, 0, stream>>>(
        comb, nullptr, wp2, fb, nullptr, outp);
}

// Round 4
// 238.738 us; speedup vs baseline: 6.0888x; 1.2832x over previous
//
#include <hip/hip_runtime.h>
#include <cstdint>
#include <cstddef>

typedef unsigned short ushort_t;
typedef unsigned int uint_t;
typedef __attribute__((ext_vector_type(8))) short bf16x8;
typedef __attribute__((ext_vector_type(4))) float f32x4;

#define NB 128
#define NC 128
#define NL 256
#define NH 8
#define HD 16
#define HDV 64
#define NEV 512

__device__ __forceinline__ ushort_t f2bf(float f) {
    uint_t u = __float_as_uint(f);
    u += 0x7fffu + ((u >> 16) & 1u);
    return (ushort_t)(u >> 16);
}
__device__ __forceinline__ float bf2f(ushort_t s) {
    return __uint_as_float(((uint_t)s) << 16);
}
__device__ __forceinline__ uint_t pack2(float lo, float hi) {
    return ((uint_t)f2bf(hi) << 16) | (uint_t)f2bf(lo);
}

// ---------------- K0: pack conv weights into MFMA A-fragment order (bf16)
template<int CIN>
__global__ __launch_bounds__(256) void k_wpack(const float* __restrict__ w,
                                               short* __restrict__ wp) {
    int idx = blockIdx.x * 256 + threadIdx.x;
    if (idx >= CIN * 1152) return;      // CIN*9*128 elements
    int j    = idx & 7;
    int lane = (idx >> 3) & 63;
    int frag = idx >> 9;
    int rt   = frag & 7;
    int tap  = (frag >> 3) % 9;
    int ch   = frag / 72;
    int co   = rt * 16 + (lane & 15);
    int g    = lane >> 4;
    int ci   = ch * 32 + g * 8 + j;
    wp[idx] = (short)f2bf(w[((size_t)co * CIN + ci) * 9 + tap]);
}

// ---------------- K0b: pack projection weights (E x 128) into A-frag order
template<int E>
__global__ __launch_bounds__(256) void k_wpack_qkv(const float* __restrict__ w,
                                                   short* __restrict__ wp) {
    int idx = blockIdx.x * 256 + threadIdx.x;
    if (idx >= E * 128) return;
    int j    = idx & 7;
    int lane = (idx >> 3) & 63;
    int ch   = (idx >> 9) & 3;
    int rt   = idx >> 11;
    int n = lane & 15, g = lane >> 4;
    wp[idx] = (short)f2bf(w[(size_t)(rt*16 + n)*128 + ch*32 + g*8 + j]);
}

// ---------------- K1: full-MFMA position attention. Block = (h, b), 4 waves.
__global__ __launch_bounds__(256) void k_pos_mfma(
    const float* __restrict__ x,
    const short* __restrict__ wpq, const short* __restrict__ wpk,
    const short* __restrict__ wpv,
    const float* __restrict__ bq, const float* __restrict__ bk,
    const float* __restrict__ bv,
    ushort_t* __restrict__ att)
{
    const int h = blockIdx.x, b = blockIdx.y;
    const int t = threadIdx.x;
    const int lane = t & 63, w = t >> 6;
    const int n = lane & 15, g = lane >> 4;

    __shared__ __align__(16) short lds[31232];

    const f32x4 z4 = {0.f, 0.f, 0.f, 0.f};
    f32x4 qacc[4], kacc[4], vacc[16];
    #pragma unroll
    for (int ct = 0; ct < 4; ++ct) { qacc[ct] = z4; kacc[ct] = z4; }
    #pragma unroll
    for (int i = 0; i < 16; ++i) vacc[i] = z4;

    const float* xg = x + (size_t)b * NC * NL + t;

    #pragma unroll 1
    for (int ch = 0; ch < 4; ++ch) {
        __syncthreads();
        #pragma unroll
        for (int k8 = 0; k8 < 4; ++k8) {
            bf16x8 v8;
            #pragma unroll
            for (int jj = 0; jj < 8; ++jj)
                v8[jj] = (short)f2bf(xg[(ch*32 + k8*8 + jj) * NL]);
            *(bf16x8*)&lds[t*40 + k8*8] = v8;
        }
        __syncthreads();
        bf16x8 xb[4];
        #pragma unroll
        for (int ct = 0; ct < 4; ++ct)
            xb[ct] = *(const bf16x8*)&lds[(w*64 + ct*16 + n)*40 + g*8];
        const size_t fo = ((size_t)((h*4 + ch)*64) + lane) * 8;
        {
            bf16x8 aq = *(const bf16x8*)(wpq + fo);
            #pragma unroll
            for (int ct = 0; ct < 4; ++ct)
                qacc[ct] = __builtin_amdgcn_mfma_f32_16x16x32_bf16(aq, xb[ct], qacc[ct], 0, 0, 0);
        }
        {
            bf16x8 ak = *(const bf16x8*)(wpk + fo);
            #pragma unroll
            for (int ct = 0; ct < 4; ++ct)
                kacc[ct] = __builtin_amdgcn_mfma_f32_16x16x32_bf16(ak, xb[ct], kacc[ct], 0, 0, 0);
        }
        #pragma unroll
        for (int vt = 0; vt < 4; ++vt) {
            bf16x8 av = *(const bf16x8*)(wpv + ((size_t)((((h*4 + vt)*4) + ch)*64) + lane) * 8);
            #pragma unroll
            for (int ct = 0; ct < 4; ++ct)
                vacc[vt*4+ct] = __builtin_amdgcn_mfma_f32_16x16x32_bf16(av, xb[ct], vacc[vt*4+ct], 0, 0, 0);
        }
    }
    __syncthreads();

    {
        float bqv[4], bkv[4];
        #pragma unroll
        for (int r = 0; r < 4; ++r) {
            bqv[r] = bq[h*16 + g*4 + r];
            bkv[r] = bk[h*16 + g*4 + r];
        }
        #pragma unroll
        for (int ct = 0; ct < 4; ++ct) {
            uint2 qp, kp;
            qp.x = pack2(qacc[ct][0] + bqv[0], qacc[ct][1] + bqv[1]);
            qp.y = pack2(qacc[ct][2] + bqv[2], qacc[ct][3] + bqv[3]);
            *(uint2*)&lds[w*1024 + (ct*16 + n)*16 + g*4] = qp;
            kp.x = pack2(kacc[ct][0] + bkv[0], kacc[ct][1] + bkv[1]);
            kp.y = pack2(kacc[ct][2] + bkv[2], kacc[ct][3] + bkv[3]);
            *(uint2*)&lds[10240 + (w*64 + ct*16 + n)*16 + g*4] = kp;
        }
        #pragma unroll
        for (int vt = 0; vt < 4; ++vt) {
            float bv0 = bv[h*64 + vt*16 + g*4 + 0];
            float bv1 = bv[h*64 + vt*16 + g*4 + 1];
            float bv2 = bv[h*64 + vt*16 + g*4 + 2];
            float bv3 = bv[h*64 + vt*16 + g*4 + 3];
            #pragma unroll
            for (int ct = 0; ct < 4; ++ct) {
                const int col = w*64 + ct*16 + n;
                lds[14336 + (vt*16 + g*4 + 0)*264 + col] = (short)f2bf(vacc[vt*4+ct][0] + bv0);
                lds[14336 + (vt*16 + g*4 + 1)*264 + col] = (short)f2bf(vacc[vt*4+ct][1] + bv1);
                lds[14336 + (vt*16 + g*4 + 2)*264 + col] = (short)f2bf(vacc[vt*4+ct][2] + bv2);
                lds[14336 + (vt*16 + g*4 + 3)*264 + col] = (short)f2bf(vacc[vt*4+ct][3] + bv3);
            }
        }
    }
    __syncthreads();

    #pragma unroll 1
    for (int qt = 0; qt < 4; ++qt) {
        bf16x8 qf = (bf16x8){0,0,0,0,0,0,0,0};
        if (g < 2) qf = *(const bf16x8*)&lds[w*1024 + (qt*16 + n)*16 + g*8];
        f32x4 s[16];
        #pragma unroll
        for (int kt = 0; kt < 16; ++kt) {
            bf16x8 kf = (bf16x8){0,0,0,0,0,0,0,0};
            if (g < 2) kf = *(const bf16x8*)&lds[10240 + (kt*16 + n)*16 + g*8];
            s[kt] = __builtin_amdgcn_mfma_f32_16x16x32_bf16(kf, qf, z4, 0, 0, 0);
        }
        float m = -3.0e38f;
        #pragma unroll
        for (int kt = 0; kt < 16; ++kt)
            #pragma unroll
            for (int r = 0; r < 4; ++r)
                m = fmaxf(m, s[kt][r]);
        m = fmaxf(m, __shfl_xor(m, 16));
        m = fmaxf(m, __shfl_xor(m, 32));
        float den = 0.f;
        #pragma unroll
        for (int kt = 0; kt < 16; ++kt)
            #pragma unroll
            for (int r = 0; r < 4; ++r) {
                float e = __expf((s[kt][r] - m) * 0.25f);
                s[kt][r] = e;
                den += e;
            }
        den += __shfl_xor(den, 16);
        den += __shfl_xor(den, 32);
        const float inv = 1.f / den;

        f32x4 oacc[4] = {z4, z4, z4, z4};
        #pragma unroll
        for (int c2 = 0; c2 < 8; ++c2) {
            #pragma unroll
            for (int u = 0; u < 2; ++u) {
                const int kt = 2*c2 + u;
                uint2 pp;
                pp.x = pack2(s[kt][0], s[kt][1]);
                pp.y = pack2(s[kt][2], s[kt][3]);
                *(uint2*)&lds[4096 + w*640 + n*40 + u*16 + g*4] = pp;
            }
            bf16x8 pf = *(const bf16x8*)&lds[4096 + w*640 + n*40 + g*8];
            #pragma unroll
            for (int vt = 0; vt < 4; ++vt) {
                bf16x8 av = *(const bf16x8*)&lds[14336 + (vt*16 + n)*264 + c2*32 + g*8];
                oacc[vt] = __builtin_amdgcn_mfma_f32_16x16x32_bf16(av, pf, oacc[vt], 0, 0, 0);
            }
        }
        ushort_t* ap = att + (((size_t)b*NL + (w*64 + qt*16 + n))*NEV + h*HDV + g*4);
        #pragma unroll
        for (int vt = 0; vt < 4; ++vt) {
            uint2 op;
            op.x = pack2(oacc[vt][0]*inv, oacc[vt][1]*inv);
            op.y = pack2(oacc[vt][2]*inv, oacc[vt][3]*inv);
            *(uint2*)(ap + vt*16) = op;
        }
    }
}

// ---------------- K2/K4: 3x3 conv via MFMA implicit GEMM.
// 512 threads = 8 waves (2 co-halves x 4 l-quarters); wave tile 64co x 32l.
// T14 async staging: prefetch chunk ch+1 to regs during chunk ch compute.
template<int CIN, bool INBF16, bool RES>
__global__ __launch_bounds__(512, 2) void k_conv_mfma(
    const void* __restrict__ in_, const float* __restrict__ resid,
    const short* __restrict__ wp, const float* __restrict__ bias,
    const float* __restrict__ gamma,
    float* __restrict__ outF)
{
    constexpr int CHUNKS = CIN / 32;
    __shared__ __align__(16) short ims[10*4*18*8];   // 11.52 KB

    const int lhalf = blockIdx.x;
    const int b     = blockIdx.y;
    const int t     = threadIdx.x;
    const int lane  = t & 63;
    const int w     = t >> 6;
    const int wr    = w >> 2;          // co half (0/1)
    const int wc    = w & 3;           // l quarter (32 l each)
    const int n     = lane & 15;
    const int g     = lane >> 4;
    const int y0    = lhalf * 8;

    {   // zero x halo (x_p = 0, 17); never rewritten
        bf16x8 z = {0,0,0,0,0,0,0,0};
        for (int i = t; i < 80; i += 512) {
            int side = i & 1, gg = (i >> 1) & 3, yp = i >> 3;
            *(bf16x8*)&ims[((yp*4 + gg)*18 + side*17) * 8] = z;
        }
    }

    f32x4 acc[4][2];
    #pragma unroll
    for (int i = 0; i < 4; ++i) {
        acc[i][0] = (f32x4){0.f,0.f,0.f,0.f};
        acc[i][1] = (f32x4){0.f,0.f,0.f,0.f};
    }

    const short* wpl = wp + (size_t)lane * 8;

    // staging task split: task1 = t (yp = w), task2 = t+512 (yp = 8+w, only t<128)
    const int gg1 = t & 3, xx1 = (t >> 2) & 15, yp1 = t >> 6;
    const bool has2 = (t < 128);
    const int yp2 = 8 + (t >> 6);
    const int y1 = y0 - 1 + yp1;
    const int y2 = y0 - 1 + yp2;
    const bool ok1 = (y1 >= 0) && (y1 < 16);
    const bool ok2 = has2 && (y2 >= 0) && (y2 < 16);

    bf16x8 v1 = {0,0,0,0,0,0,0,0}, v2 = {0,0,0,0,0,0,0,0};
    float4 f1a, f1b, f2a, f2b;
    f1a = f1b = f2a = f2b = (float4){0.f,0.f,0.f,0.f};

    auto prefetch = [&](int ci0) {
        if constexpr (INBF16) {
            if (ok1) v1 = *(const bf16x8*)((const ushort_t*)in_ +
                          ((size_t)(b*NL + y1*16 + xx1))*CIN + ci0 + gg1*8);
            if (ok2) v2 = *(const bf16x8*)((const ushort_t*)in_ +
                          ((size_t)(b*NL + y2*16 + xx1))*CIN + ci0 + gg1*8);
        } else {
            if (ok1) {
                const float4* sp = (const float4*)((const float*)in_ +
                    ((size_t)(b*NL + y1*16 + xx1))*CIN + ci0 + gg1*8);
                f1a = sp[0]; f1b = sp[1];
            }
            if (ok2) {
                const float4* sp = (const float4*)((const float*)in_ +
                    ((size_t)(b*NL + y2*16 + xx1))*CIN + ci0 + gg1*8);
                f2a = sp[0]; f2b = sp[1];
            }
        }
    };
    auto store_stage = [&]() {
        bf16x8 s1, s2;
        if constexpr (INBF16) { s1 = v1; s2 = v2; }
        else {
            s1[0]=(short)f2bf(f1a.x); s1[1]=(short)f2bf(f1a.y);
            s1[2]=(short)f2bf(f1a.z); s1[3]=(short)f2bf(f1a.w);
            s1[4]=(short)f2bf(f1b.x); s1[5]=(short)f2bf(f1b.y);
            s1[6]=(short)f2bf(f1b.z); s1[7]=(short)f2bf(f1b.w);
            s2[0]=(short)f2bf(f2a.x); s2[1]=(short)f2bf(f2a.y);
            s2[2]=(short)f2bf(f2a.z); s2[3]=(short)f2bf(f2a.w);
            s2[4]=(short)f2bf(f2b.x); s2[5]=(short)f2bf(f2b.y);
            s2[6]=(short)f2bf(f2b.z); s2[7]=(short)f2bf(f2b.w);
        }
        *(bf16x8*)&ims[((yp1*4 + gg1)*18 + xx1 + 1) * 8] = s1;
        if (has2) *(bf16x8*)&ims[((yp2*4 + gg1)*18 + xx1 + 1) * 8] = s2;
        // reset zeros for oob rows (cheap; keeps next prefetch's skip correct)
        if constexpr (INBF16) {
            if (!ok1) v1 = (bf16x8){0,0,0,0,0,0,0,0};
            if (!ok2) v2 = (bf16x8){0,0,0,0,0,0,0,0};
        }
    };

    prefetch(0);
    #pragma unroll 1
    for (int ch = 0; ch < CHUNKS; ++ch) {
        __syncthreads();                 // previous compute / halo init done
        store_stage();
        if (ch + 1 < CHUNKS) prefetch((ch + 1) * 32);
        __syncthreads();                 // LDS image ready
        #pragma unroll
        for (int tap = 0; tap < 9; ++tap) {
            const int dy = tap / 3, dx = tap % 3;
            bf16x8 Bf[2];
            #pragma unroll
            for (int ct = 0; ct < 2; ++ct) {
                int yrow = wc*2 + ct + dy;          // 0..9
                Bf[ct] = *(const bf16x8*)&ims[(yrow*72 + g*18 + n + dx) * 8];
            }
            bf16x8 Af[4];
            #pragma unroll
            for (int rt = 0; rt < 4; ++rt) {
                int frag = (ch*9 + tap)*8 + wr*4 + rt;
                Af[rt] = *(const bf16x8*)(wpl + (size_t)frag * 512);
            }
            #pragma unroll
            for (int rt = 0; rt < 4; ++rt)
                #pragma unroll
                for (int ct = 0; ct < 2; ++ct)
                    acc[rt][ct] = __builtin_amdgcn_mfma_f32_16x16x32_bf16(
                        Af[rt], Bf[ct], acc[rt][ct], 0, 0, 0);
        }
    }

    if constexpr (RES) {
        const float g0 = gamma[0];
        #pragma unroll
        for (int rt = 0; rt < 4; ++rt) {
            const int co0 = wr*64 + rt*16 + g*4;
            const float b0 = bias[co0+0], b1 = bias[co0+1],
                        b2 = bias[co0+2], b3 = bias[co0+3];
            #pragma unroll
            for (int ct = 0; ct < 2; ++ct) {
                const int l = lhalf*128 + wc*32 + ct*16 + n;
                f32x4 a = acc[rt][ct];
                float4 r;
                r.x = 0.5f*(resid[((size_t)b*NC + co0+0)*NL + l] + g0*(b0 + a[0]));
                r.y = 0.5f*(resid[((size_t)b*NC + co0+1)*NL + l] + g0*(b1 + a[1]));
                r.z = 0.5f*(resid[((size_t)b*NC + co0+2)*NL + l] + g0*(b2 + a[2]));
                r.w = 0.5f*(resid[((size_t)b*NC + co0+3)*NL + l] + g0*(b3 + a[3]));
                *(float4*)(outF + ((size_t)b*NL + l)*NC + co0) = r;   // NHWC comb
            }
        }
    } else {
        #pragma unroll
        for (int rt = 0; rt < 4; ++rt) {
            const int co0 = wr*64 + rt*16 + g*4;
            const float b0 = bias[co0+0], b1 = bias[co0+1],
                        b2 = bias[co0+2], b3 = bias[co0+3];
            #pragma unroll
            for (int ct = 0; ct < 2; ++ct) {
                const int l = lhalf*128 + wc*32 + ct*16 + n;
                f32x4 a = acc[rt][ct];
                outF[((size_t)b*NC + co0+0)*NL + l] = b0 + a[0];      // NCHW out
                outF[((size_t)b*NC + co0+1)*NL + l] = b1 + a[1];
                outF[((size_t)b*NC + co0+2)*NL + l] = b2 + a[2];
                outF[((size_t)b*NC + co0+3)*NL + l] = b3 + a[3];
            }
        }
    }
}

// ---------------- K3: channel attention (block-diagonal, gram-collapsed) + fusion
#define NLP 260
__global__ __launch_bounds__(256) void k_cha(
    const float* __restrict__ xc,
    const float* __restrict__ cwq, const float* __restrict__ cbq,
    const float* __restrict__ cwk, const float* __restrict__ cbk,
    const float* __restrict__ cwv, const float* __restrict__ cbv,
    const float* __restrict__ cwo, const float* __restrict__ cbo,
    const float* __restrict__ gamma,
    float* __restrict__ comb)
{
    const int h = blockIdx.x, b = blockIdx.y, t = threadIdx.x;
    __shared__ float qh[16][NLP];
    __shared__ float G_s[16][17];
    __shared__ float S_s[16];
    __shared__ float wq_s[128], bq_s[128], wk_s[128], bk_s[128], wv_s[128], bv_s[128];
    __shared__ float A_s[128][17];
    __shared__ float B_s[128];
    __shared__ float M_s[16][17];
    __shared__ float c_s[16];

    #pragma unroll
    for (int j = 0; j < 16; ++j)
        qh[j][t] = xc[((size_t)b*NC + h*16 + j)*NL + t];
    if (t < 128) {
        const int k = h*128 + t;
        wq_s[t] = cwq[k]; bq_s[t] = cbq[k];
        wk_s[t] = cwk[k]; bk_s[t] = cbk[k];
        wv_s[t] = cwv[k]; bv_s[t] = cbv[k];
    }
    __syncthreads();
    {
        const int i = t >> 4, j = t & 15;
        const float4* qi = (const float4*)qh[i];
        const float4* qj = (const float4*)qh[j];
        float gg = 0.f;
        for (int l4 = 0; l4 < NL/4; ++l4) {
            float4 a = qi[l4], c = qj[l4];
            gg = fmaf(a.x,c.x,fmaf(a.y,c.y,fmaf(a.z,c.z,fmaf(a.w,c.w,gg))));
        }
        G_s[i][j] = gg;
    }
    if (t < 16) {
        const float4* qi = (const float4*)qh[t];
        float s = 0.f;
        for (int l4 = 0; l4 < NL/4; ++l4) { float4 a = qi[l4]; s += a.x + a.y + a.z + a.w; }
        S_s[t] = s;
    }
    __syncthreads();
    if (t < 128) {
        const int c2 = t, cg = c2 >> 3;
        const float wqc = wq_s[c2], bqc = bq_s[c2];
        float P[16];
        #pragma unroll
        for (int j = 0; j < 16; ++j) P[j] = wqc*G_s[cg][j] + bqc*S_s[j];
        const float Qc = wqc*S_s[cg] + bqc*256.0f;
        float mx = -3.0e38f;
        #pragma unroll
        for (int dg = 0; dg < 16; ++dg) {
            #pragma unroll
            for (int dj = 0; dj < 8; ++dj) {
                const int d = dg*8 + dj;
                float s = wk_s[d]*P[dg] + bk_s[d]*Qc;
                mx = fmaxf(mx, s);
            }
        }
        float A[16];
        #pragma unroll
        for (int j = 0; j < 16; ++j) A[j] = 0.f;
        float Bv = 0.f, den = 0.f;
        #pragma unroll
        for (int dg = 0; dg < 16; ++dg) {
            #pragma unroll
            for (int dj = 0; dj < 8; ++dj) {
                const int d = dg*8 + dj;
                float s = wk_s[d]*P[dg] + bk_s[d]*Qc;
                float e = __expf((s - mx) * 0.0625f);
                den += e;
                A[dg] = fmaf(e, wv_s[d], A[dg]);
                Bv = fmaf(e, bv_s[d], Bv);
            }
        }
        const float inv = 1.f / den;
        #pragma unroll
        for (int j = 0; j < 16; ++j) A_s[c2][j] = A[j]*inv;
        B_s[c2] = Bv*inv;
    }
    __syncthreads();
    {
        const int cl = t >> 4, j = t & 15;
        const int cp = h*16 + cl;
        float m = 0.f;
        #pragma unroll
        for (int hp = 0; hp < 8; ++hp)
            m = fmaf(cwo[cp*8+hp], A_s[cl*8+hp][j], m);
        M_s[cl][j] = m;
        if (j == 0) {
            float cc = cbo[cp];
            #pragma unroll
            for (int hp = 0; hp < 8; ++hp)
                cc = fmaf(cwo[cp*8+hp], B_s[cl*8+hp], cc);
            c_s[cl] = cc;
        }
    }
    __syncthreads();
    {
        const float g = gamma[0];
        const int l = t;
        float av[16];
        #pragma unroll
        for (int cl = 0; cl < 16; ++cl) {
            float a = c_s[cl];
            #pragma unroll
            for (int j = 0; j < 16; ++j)
                a = fmaf(M_s[cl][j], qh[j][l], a);
            av[cl] = a;
        }
        float4* cp4 = (float4*)(comb + ((size_t)b*NL + l)*NC + h*16);
        #pragma unroll
        for (int q = 0; q < 4; ++q) {
            float4 c = cp4[q];
            c.x += 0.5f*(qh[4*q+0][l] + g*av[4*q+0]);
            c.y += 0.5f*(qh[4*q+1][l] + g*av[4*q+1]);
            c.z += 0.5f*(qh[4*q+2][l] + g*av[4*q+2]);
            c.w += 0.5f*(qh[4*q+3][l] + g*av[4*q+3]);
            cp4[q] = c;
        }
    }
}

extern "C" void kernel_launch(void* const* d_in, const int* in_sizes, int n_in,
                              void* d_out, int out_size, void* d_ws, size_t ws_size,
                              hipStream_t stream)
{
    const float* qpos = (const float*)d_in[0];
    const float* qcha = (const float*)d_in[1];
    const float* pwq  = (const float*)d_in[2];
    const float* pbq  = (const float*)d_in[3];
    const float* pwk  = (const float*)d_in[4];
    const float* pbk  = (const float*)d_in[5];
    const float* pwv  = (const float*)d_in[6];
    const float* pbv  = (const float*)d_in[7];
    const float* pwo  = (const float*)d_in[8];
    const float* pbo  = (const float*)d_in[9];
    const float* gpos = (const float*)d_in[10];
    const float* cwq  = (const float*)d_in[11];
    const float* cbq  = (const float*)d_in[12];
    const float* cwk  = (const float*)d_in[13];
    const float* cbk  = (const float*)d_in[14];
    const float* cwv  = (const float*)d_in[15];
    const float* cbv  = (const float*)d_in[16];
    const float* cwo  = (const float*)d_in[17];
    const float* cbo  = (const float*)d_in[18];
    const float* gcha = (const float*)d_in[19];
    const float* fw   = (const float*)d_in[20];
    const float* fb   = (const float*)d_in[21];
    float* outp = (float*)d_out;

    char* ws = (char*)d_ws;
    ushort_t* att  = (ushort_t*)ws;                       // 33,554,432 B  (NHWC bf16)
    float*    comb = (float*)(ws + 33554432);             // 16,777,216 B  (NHWC f32)
    short*    wp1  = (short*)(ws + 50331648);             //  1,179,648 B
    short*    wp2  = (short*)(ws + 51511296);             //    294,912 B
    short*    wpq  = (short*)(ws + 51806208);             //     32,768 B
    short*    wpk  = (short*)(ws + 51838976);             //     32,768 B
    short*    wpv  = (short*)(ws + 51871744);             //    131,072 B

    k_wpack<NEV><<<dim3((NEV*1152 + 255)/256), 256, 0, stream>>>(pwo, wp1);
    k_wpack<NC ><<<dim3((NC *1152 + 255)/256), 256, 0, stream>>>(fw,  wp2);
    k_wpack_qkv<128><<<dim3(64),  256, 0, stream>>>(pwq, wpq);
    k_wpack_qkv<128><<<dim3(64),  256, 0, stream>>>(pwk, wpk);
    k_wpack_qkv<512><<<dim3(256), 256, 0, stream>>>(pwv, wpv);

    k_pos_mfma<<<dim3(NH, NB), 256, 0, stream>>>(qpos, wpq, wpk, wpv,
                                                 pbq, pbk, pbv, att);
    k_conv_mfma<NEV, true,  true ><<<dim3(2, NB), 512, 0, stream>>>(
        att, qpos, wp1, pbo, gpos, comb);
    k_cha<<<dim3(NH, NB), 256, 0, stream>>>(qcha, cwq, cbq, cwk, cbk, cwv, cbv,
                                            cwo, cbo, gcha, comb);
    k_conv_mfma<NC, false, false><<<dim3(2, NB), 512, 0, stream>>>(
        comb, nullptr, wp2, fb, nullptr, outp);
}

// Round 5
// 185.911 us; speedup vs baseline: 7.8189x; 1.2842x over previous
//
#include <hip/hip_runtime.h>
#include <cstdint>
#include <cstddef>

typedef unsigned short ushort_t;
typedef unsigned int uint_t;
typedef __attribute__((ext_vector_type(8))) short bf16x8;
typedef __attribute__((ext_vector_type(4))) float f32x4;

#define NB 128
#define NC 128
#define NL 256
#define NH 8
#define HD 16
#define HDV 64
#define NEV 512
#define PHALF 4194304   // elements per conv1 partial half (128*256*128)

__device__ __forceinline__ ushort_t f2bf(float f) {
    uint_t u = __float_as_uint(f);
    u += 0x7fffu + ((u >> 16) & 1u);
    return (ushort_t)(u >> 16);
}
__device__ __forceinline__ float bf2f(ushort_t s) {
    return __uint_as_float(((uint_t)s) << 16);
}
__device__ __forceinline__ uint_t pack2(float lo, float hi) {
    return ((uint_t)f2bf(hi) << 16) | (uint_t)f2bf(lo);
}

// ---------------- K0: pack conv weights into MFMA A-fragment order (bf16)
// wp[frag][lane][8], frag = (chunk*9 + tap)*8 + rt   (chunk of 32 ci, rt = co tile of 16)
template<int CIN>
__global__ __launch_bounds__(256) void k_wpack(const float* __restrict__ w,
                                               short* __restrict__ wp) {
    int idx = blockIdx.x * 256 + threadIdx.x;
    if (idx >= CIN * 1152) return;      // CIN*9*128 elements
    int j    = idx & 7;
    int lane = (idx >> 3) & 63;
    int frag = idx >> 9;
    int rt   = frag & 7;
    int tap  = (frag >> 3) % 9;
    int ch   = frag / 72;
    int co   = rt * 16 + (lane & 15);
    int g    = lane >> 4;
    int ci   = ch * 32 + g * 8 + j;
    wp[idx] = (short)f2bf(w[((size_t)co * CIN + ci) * 9 + tap]);
}

// ---------------- K0b: pack projection weights (E x 128) into A-frag order
template<int E>
__global__ __launch_bounds__(256) void k_wpack_qkv(const float* __restrict__ w,
                                                   short* __restrict__ wp) {
    int idx = blockIdx.x * 256 + threadIdx.x;
    if (idx >= E * 128) return;
    int j    = idx & 7;
    int lane = (idx >> 3) & 63;
    int ch   = (idx >> 9) & 3;
    int rt   = idx >> 11;
    int n = lane & 15, g = lane >> 4;
    wp[idx] = (short)f2bf(w[(size_t)(rt*16 + n)*128 + ch*32 + g*8 + j]);
}

// ---------------- K1: full-MFMA position attention. Block = (h, b), 4 waves.
__global__ __launch_bounds__(256) void k_pos_mfma(
    const float* __restrict__ x,
    const short* __restrict__ wpq, const short* __restrict__ wpk,
    const short* __restrict__ wpv,
    const float* __restrict__ bq, const float* __restrict__ bk,
    const float* __restrict__ bv,
    ushort_t* __restrict__ att)
{
    const int h = blockIdx.x, b = blockIdx.y;
    const int t = threadIdx.x;
    const int lane = t & 63, w = t >> 6;
    const int n = lane & 15, g = lane >> 4;

    __shared__ __align__(16) short lds[31232];

    const f32x4 z4 = {0.f, 0.f, 0.f, 0.f};
    f32x4 qacc[4], kacc[4], vacc[16];
    #pragma unroll
    for (int ct = 0; ct < 4; ++ct) { qacc[ct] = z4; kacc[ct] = z4; }
    #pragma unroll
    for (int i = 0; i < 16; ++i) vacc[i] = z4;

    const float* xg = x + (size_t)b * NC * NL + t;

    #pragma unroll 1
    for (int ch = 0; ch < 4; ++ch) {
        __syncthreads();
        #pragma unroll
        for (int k8 = 0; k8 < 4; ++k8) {
            bf16x8 v8;
            #pragma unroll
            for (int jj = 0; jj < 8; ++jj)
                v8[jj] = (short)f2bf(xg[(ch*32 + k8*8 + jj) * NL]);
            *(bf16x8*)&lds[t*40 + k8*8] = v8;
        }
        __syncthreads();
        bf16x8 xb[4];
        #pragma unroll
        for (int ct = 0; ct < 4; ++ct)
            xb[ct] = *(const bf16x8*)&lds[(w*64 + ct*16 + n)*40 + g*8];
        const size_t fo = ((size_t)((h*4 + ch)*64) + lane) * 8;
        {
            bf16x8 aq = *(const bf16x8*)(wpq + fo);
            #pragma unroll
            for (int ct = 0; ct < 4; ++ct)
                qacc[ct] = __builtin_amdgcn_mfma_f32_16x16x32_bf16(aq, xb[ct], qacc[ct], 0, 0, 0);
        }
        {
            bf16x8 ak = *(const bf16x8*)(wpk + fo);
            #pragma unroll
            for (int ct = 0; ct < 4; ++ct)
                kacc[ct] = __builtin_amdgcn_mfma_f32_16x16x32_bf16(ak, xb[ct], kacc[ct], 0, 0, 0);
        }
        #pragma unroll
        for (int vt = 0; vt < 4; ++vt) {
            bf16x8 av = *(const bf16x8*)(wpv + ((size_t)((((h*4 + vt)*4) + ch)*64) + lane) * 8);
            #pragma unroll
            for (int ct = 0; ct < 4; ++ct)
                vacc[vt*4+ct] = __builtin_amdgcn_mfma_f32_16x16x32_bf16(av, xb[ct], vacc[vt*4+ct], 0, 0, 0);
        }
    }
    __syncthreads();

    {
        float bqv[4], bkv[4];
        #pragma unroll
        for (int r = 0; r < 4; ++r) {
            bqv[r] = bq[h*16 + g*4 + r];
            bkv[r] = bk[h*16 + g*4 + r];
        }
        #pragma unroll
        for (int ct = 0; ct < 4; ++ct) {
            uint2 qp, kp;
            qp.x = pack2(qacc[ct][0] + bqv[0], qacc[ct][1] + bqv[1]);
            qp.y = pack2(qacc[ct][2] + bqv[2], qacc[ct][3] + bqv[3]);
            *(uint2*)&lds[w*1024 + (ct*16 + n)*16 + g*4] = qp;
            kp.x = pack2(kacc[ct][0] + bkv[0], kacc[ct][1] + bkv[1]);
            kp.y = pack2(kacc[ct][2] + bkv[2], kacc[ct][3] + bkv[3]);
            *(uint2*)&lds[10240 + (w*64 + ct*16 + n)*16 + g*4] = kp;
        }
        #pragma unroll
        for (int vt = 0; vt < 4; ++vt) {
            float bv0 = bv[h*64 + vt*16 + g*4 + 0];
            float bv1 = bv[h*64 + vt*16 + g*4 + 1];
            float bv2 = bv[h*64 + vt*16 + g*4 + 2];
            float bv3 = bv[h*64 + vt*16 + g*4 + 3];
            #pragma unroll
            for (int ct = 0; ct < 4; ++ct) {
                const int col = w*64 + ct*16 + n;
                lds[14336 + (vt*16 + g*4 + 0)*264 + col] = (short)f2bf(vacc[vt*4+ct][0] + bv0);
                lds[14336 + (vt*16 + g*4 + 1)*264 + col] = (short)f2bf(vacc[vt*4+ct][1] + bv1);
                lds[14336 + (vt*16 + g*4 + 2)*264 + col] = (short)f2bf(vacc[vt*4+ct][2] + bv2);
                lds[14336 + (vt*16 + g*4 + 3)*264 + col] = (short)f2bf(vacc[vt*4+ct][3] + bv3);
            }
        }
    }
    __syncthreads();

    #pragma unroll 1
    for (int qt = 0; qt < 4; ++qt) {
        bf16x8 qf = (bf16x8){0,0,0,0,0,0,0,0};
        if (g < 2) qf = *(const bf16x8*)&lds[w*1024 + (qt*16 + n)*16 + g*8];
        f32x4 s[16];
        #pragma unroll
        for (int kt = 0; kt < 16; ++kt) {
            bf16x8 kf = (bf16x8){0,0,0,0,0,0,0,0};
            if (g < 2) kf = *(const bf16x8*)&lds[10240 + (kt*16 + n)*16 + g*8];
            s[kt] = __builtin_amdgcn_mfma_f32_16x16x32_bf16(kf, qf, z4, 0, 0, 0);
        }
        float m = -3.0e38f;
        #pragma unroll
        for (int kt = 0; kt < 16; ++kt)
            #pragma unroll
            for (int r = 0; r < 4; ++r)
                m = fmaxf(m, s[kt][r]);
        m = fmaxf(m, __shfl_xor(m, 16));
        m = fmaxf(m, __shfl_xor(m, 32));
        float den = 0.f;
        #pragma unroll
        for (int kt = 0; kt < 16; ++kt)
            #pragma unroll
            for (int r = 0; r < 4; ++r) {
                float e = __expf((s[kt][r] - m) * 0.25f);
                s[kt][r] = e;
                den += e;
            }
        den += __shfl_xor(den, 16);
        den += __shfl_xor(den, 32);
        const float inv = 1.f / den;

        f32x4 oacc[4] = {z4, z4, z4, z4};
        #pragma unroll
        for (int c2 = 0; c2 < 8; ++c2) {
            #pragma unroll
            for (int u = 0; u < 2; ++u) {
                const int kt = 2*c2 + u;
                uint2 pp;
                pp.x = pack2(s[kt][0], s[kt][1]);
                pp.y = pack2(s[kt][2], s[kt][3]);
                *(uint2*)&lds[4096 + w*640 + n*40 + u*16 + g*4] = pp;
            }
            bf16x8 pf = *(const bf16x8*)&lds[4096 + w*640 + n*40 + g*8];
            #pragma unroll
            for (int vt = 0; vt < 4; ++vt) {
                bf16x8 av = *(const bf16x8*)&lds[14336 + (vt*16 + n)*264 + c2*32 + g*8];
                oacc[vt] = __builtin_amdgcn_mfma_f32_16x16x32_bf16(av, pf, oacc[vt], 0, 0, 0);
            }
        }
        ushort_t* ap = att + (((size_t)b*NL + (w*64 + qt*16 + n))*NEV + h*HDV + g*4);
        #pragma unroll
        for (int vt = 0; vt < 4; ++vt) {
            uint2 op;
            op.x = pack2(oacc[vt][0]*inv, oacc[vt][1]*inv);
            op.y = pack2(oacc[vt][2]*inv, oacc[vt][3]*inv);
            *(uint2*)(ap + vt*16) = op;
        }
    }
}

// ---------------- K2: conv1 (3x3, 512->128) ci-split implicit GEMM.
// grid (2, NB): kc = ci half. Block = 128co x 256l (full image), 8 chunks of 32 ci.
// 8 waves (2 co-halves x 4 l-quarters), wave tile 64co x 64l, acc 4x4.
// LDS: full padded image [18 yp][4 g][18 xp][8ci] bf16, double-buffered, 1 barrier/chunk.
// Output: raw bf16 partial, NHWC P[kc][b][l][co].
__global__ __launch_bounds__(512, 2) void k_conv_ci(
    const ushort_t* __restrict__ att, const short* __restrict__ wp,
    ushort_t* __restrict__ P)
{
    const int kc = blockIdx.x, b = blockIdx.y;
    const int t = threadIdx.x;
    const int lane = t & 63, w = t >> 6;
    const int wr = w >> 2, wc = w & 3;
    const int n = lane & 15, gl = lane >> 4;

    __shared__ __align__(16) short ims[2][10368];   // 2 x 20.25 KB

    {   // zero both buffers once (halo rows/cols stay zero forever)
        bf16x8 z = {0,0,0,0,0,0,0,0};
        bf16x8* p = (bf16x8*)&ims[0][0];
        for (int i = t; i < 2592; i += 512) p[i] = z;
    }

    f32x4 acc[4][4];
    #pragma unroll
    for (int i = 0; i < 4; ++i)
        #pragma unroll
        for (int j = 0; j < 4; ++j) acc[i][j] = (f32x4){0.f,0.f,0.f,0.f};

    // staging: 1024 tasks/chunk = (16y x 16x x 4g); thread does (y1,x1,g1) and (y1+8,x1,g1)
    const int g1 = t & 3, x1 = (t >> 2) & 15, y1 = t >> 6;
    const ushort_t* src1 = att + ((size_t)(b*NL + y1*16 + x1))*NEV + kc*256 + g1*8;
    const ushort_t* src2 = att + ((size_t)(b*NL + (y1+8)*16 + x1))*NEV + kc*256 + g1*8;
    const int slot1 = (((y1+1)*4 + g1)*18 + x1 + 1) * 8;
    const int slot2 = (((y1+9)*4 + g1)*18 + x1 + 1) * 8;

    bf16x8 v1 = *(const bf16x8*)src1;       // prefetch chunk 0
    bf16x8 v2 = *(const bf16x8*)src2;
    __syncthreads();                        // zeroing complete

    #pragma unroll 1
    for (int ch = 0; ch < 8; ++ch) {
        short* buf = &ims[ch & 1][0];
        *(bf16x8*)&buf[slot1] = v1;
        *(bf16x8*)&buf[slot2] = v2;
        if (ch < 7) {                       // prefetch next chunk (rides under compute)
            v1 = *(const bf16x8*)(src1 + (ch + 1) * 32);
            v2 = *(const bf16x8*)(src2 + (ch + 1) * 32);
        }
        __syncthreads();                    // image ready (single barrier per chunk)
        #pragma unroll
        for (int tap = 0; tap < 9; ++tap) {
            const int dy = tap / 3, dx = tap % 3;
            bf16x8 Bf[4];
            #pragma unroll
            for (int ct = 0; ct < 4; ++ct)
                Bf[ct] = *(const bf16x8*)&buf[((((wc*4 + ct + dy)*4) + gl)*18 + n + dx) * 8];
            bf16x8 Af[4];
            #pragma unroll
            for (int rt = 0; rt < 4; ++rt)
                Af[rt] = *(const bf16x8*)(wp +
                    ((size_t)(((kc*8 + ch)*9 + tap)*8 + wr*4 + rt)) * 512 + lane*8);
            #pragma unroll
            for (int rt = 0; rt < 4; ++rt)
                #pragma unroll
                for (int ct = 0; ct < 4; ++ct)
                    acc[rt][ct] = __builtin_amdgcn_mfma_f32_16x16x32_bf16(
                        Af[rt], Bf[ct], acc[rt][ct], 0, 0, 0);
        }
    }

    // epilogue: raw bf16 partial, NHWC
    ushort_t* Pb = P + (size_t)kc * PHALF + (size_t)b * NL * NC;
    #pragma unroll
    for (int rt = 0; rt < 4; ++rt) {
        const int co0 = wr*64 + rt*16 + gl*4;
        #pragma unroll
        for (int ct = 0; ct < 4; ++ct) {
            const int l = wc*64 + ct*16 + n;
            uint2 u;
            u.x = pack2(acc[rt][ct][0], acc[rt][ct][1]);
            u.y = pack2(acc[rt][ct][2], acc[rt][ct][3]);
            *(uint2*)(Pb + (size_t)l*NC + co0) = u;
        }
    }
}

// ---------------- K4: conv2 (3x3, 128->128) co-split implicit GEMM.
// grid (2, NB): kc = co half (64 co). Block = 64co x 256l x 128ci, 4 chunks.
// 8 waves (2 co-quarters x 4 l-quarters), wave tile 32co x 64l, acc 2x4.
__global__ __launch_bounds__(512, 2) void k_conv_co(
    const float* __restrict__ comb, const short* __restrict__ wp,
    const float* __restrict__ bias, float* __restrict__ out)
{
    const int kc = blockIdx.x, b = blockIdx.y;
    const int t = threadIdx.x;
    const int lane = t & 63, w = t >> 6;
    const int wr = w & 1, wc = w >> 1;
    const int n = lane & 15, gl = lane >> 4;

    __shared__ __align__(16) short ims[2][10368];

    {
        bf16x8 z = {0,0,0,0,0,0,0,0};
        bf16x8* p = (bf16x8*)&ims[0][0];
        for (int i = t; i < 2592; i += 512) p[i] = z;
    }

    f32x4 acc[2][4];
    #pragma unroll
    for (int i = 0; i < 2; ++i)
        #pragma unroll
        for (int j = 0; j < 4; ++j) acc[i][j] = (f32x4){0.f,0.f,0.f,0.f};

    const int g1 = t & 3, x1 = (t >> 2) & 15, y1 = t >> 6;
    const float* s1 = comb + ((size_t)(b*NL + y1*16 + x1))*NC + g1*8;
    const float* s2 = comb + ((size_t)(b*NL + (y1+8)*16 + x1))*NC + g1*8;
    const int slot1 = (((y1+1)*4 + g1)*18 + x1 + 1) * 8;
    const int slot2 = (((y1+9)*4 + g1)*18 + x1 + 1) * 8;

    float4 a1 = *(const float4*)s1,       b1_ = *(const float4*)(s1 + 4);
    float4 a2 = *(const float4*)s2,       b2_ = *(const float4*)(s2 + 4);
    __syncthreads();

    #pragma unroll 1
    for (int ch = 0; ch < 4; ++ch) {
        short* buf = &ims[ch & 1][0];
        bf16x8 w1, w2;
        w1[0]=(short)f2bf(a1.x);  w1[1]=(short)f2bf(a1.y);
        w1[2]=(short)f2bf(a1.z);  w1[3]=(short)f2bf(a1.w);
        w1[4]=(short)f2bf(b1_.x); w1[5]=(short)f2bf(b1_.y);
        w1[6]=(short)f2bf(b1_.z); w1[7]=(short)f2bf(b1_.w);
        w2[0]=(short)f2bf(a2.x);  w2[1]=(short)f2bf(a2.y);
        w2[2]=(short)f2bf(a2.z);  w2[3]=(short)f2bf(a2.w);
        w2[4]=(short)f2bf(b2_.x); w2[5]=(short)f2bf(b2_.y);
        w2[6]=(short)f2bf(b2_.z); w2[7]=(short)f2bf(b2_.w);
        *(bf16x8*)&buf[slot1] = w1;
        *(bf16x8*)&buf[slot2] = w2;
        if (ch < 3) {
            a1  = *(const float4*)(s1 + (ch+1)*32);
            b1_ = *(const float4*)(s1 + (ch+1)*32 + 4);
            a2  = *(const float4*)(s2 + (ch+1)*32);
            b2_ = *(const float4*)(s2 + (ch+1)*32 + 4);
        }
        __syncthreads();
        #pragma unroll
        for (int tap = 0; tap < 9; ++tap) {
            const int dy = tap / 3, dx = tap % 3;
            bf16x8 Bf[4];
            #pragma unroll
            for (int ct = 0; ct < 4; ++ct)
                Bf[ct] = *(const bf16x8*)&buf[((((wc*4 + ct + dy)*4) + gl)*18 + n + dx) * 8];
            bf16x8 Af[2];
            #pragma unroll
            for (int rt = 0; rt < 2; ++rt)
                Af[rt] = *(const bf16x8*)(wp +
                    ((size_t)((ch*9 + tap)*8 + kc*4 + wr*2 + rt)) * 512 + lane*8);
            #pragma unroll
            for (int rt = 0; rt < 2; ++rt)
                #pragma unroll
                for (int ct = 0; ct < 4; ++ct)
                    acc[rt][ct] = __builtin_amdgcn_mfma_f32_16x16x32_bf16(
                        Af[rt], Bf[ct], acc[rt][ct], 0, 0, 0);
        }
    }

    #pragma unroll
    for (int rt = 0; rt < 2; ++rt) {
        const int co0 = kc*64 + wr*32 + rt*16 + gl*4;
        const float c0 = bias[co0+0], c1 = bias[co0+1],
                    c2 = bias[co0+2], c3 = bias[co0+3];
        #pragma unroll
        for (int ct = 0; ct < 4; ++ct) {
            const int l = wc*64 + ct*16 + n;
            f32x4 a = acc[rt][ct];
            out[((size_t)b*NC + co0+0)*NL + l] = c0 + a[0];
            out[((size_t)b*NC + co0+1)*NL + l] = c1 + a[1];
            out[((size_t)b*NC + co0+2)*NL + l] = c2 + a[2];
            out[((size_t)b*NC + co0+3)*NL + l] = c3 + a[3];
        }
    }
}

// ---------------- K3: channel attention + fold conv1 partials + pos residual + fusion
#define NLP 260
__global__ __launch_bounds__(256) void k_cha(
    const float* __restrict__ xc,
    const float* __restrict__ cwq, const float* __restrict__ cbq,
    const float* __restrict__ cwk, const float* __restrict__ cbk,
    const float* __restrict__ cwv, const float* __restrict__ cbv,
    const float* __restrict__ cwo, const float* __restrict__ cbo,
    const float* __restrict__ gamma,
    const ushort_t* __restrict__ P, const float* __restrict__ qpos,
    const float* __restrict__ pbo, const float* __restrict__ gpos,
    float* __restrict__ comb)
{
    const int h = blockIdx.x, b = blockIdx.y, t = threadIdx.x;
    __shared__ float qh[16][NLP];
    __shared__ float G_s[16][17];
    __shared__ float S_s[16];
    __shared__ float wq_s[128], bq_s[128], wk_s[128], bk_s[128], wv_s[128], bv_s[128];
    __shared__ float A_s[128][17];
    __shared__ float B_s[128];
    __shared__ float M_s[16][17];
    __shared__ float c_s[16];

    #pragma unroll
    for (int j = 0; j < 16; ++j)
        qh[j][t] = xc[((size_t)b*NC + h*16 + j)*NL + t];
    if (t < 128) {
        const int k = h*128 + t;
        wq_s[t] = cwq[k]; bq_s[t] = cbq[k];
        wk_s[t] = cwk[k]; bk_s[t] = cbk[k];
        wv_s[t] = cwv[k]; bv_s[t] = cbv[k];
    }
    __syncthreads();
    {
        const int i = t >> 4, j = t & 15;
        const float4* qi = (const float4*)qh[i];
        const float4* qj = (const float4*)qh[j];
        float gg = 0.f;
        for (int l4 = 0; l4 < NL/4; ++l4) {
            float4 a = qi[l4], c = qj[l4];
            gg = fmaf(a.x,c.x,fmaf(a.y,c.y,fmaf(a.z,c.z,fmaf(a.w,c.w,gg))));
        }
        G_s[i][j] = gg;
    }
    if (t < 16) {
        const float4* qi = (const float4*)qh[t];
        float s = 0.f;
        for (int l4 = 0; l4 < NL/4; ++l4) { float4 a = qi[l4]; s += a.x + a.y + a.z + a.w; }
        S_s[t] = s;
    }
    __syncthreads();
    if (t < 128) {
        const int c2 = t, cg = c2 >> 3;
        const float wqc = wq_s[c2], bqc = bq_s[c2];
        float Pv[16];
        #pragma unroll
        for (int j = 0; j < 16; ++j) Pv[j] = wqc*G_s[cg][j] + bqc*S_s[j];
        const float Qc = wqc*S_s[cg] + bqc*256.0f;
        float mx = -3.0e38f;
        #pragma unroll
        for (int dg = 0; dg < 16; ++dg) {
            #pragma unroll
            for (int dj = 0; dj < 8; ++dj) {
                const int d = dg*8 + dj;
                float s = wk_s[d]*Pv[dg] + bk_s[d]*Qc;
                mx = fmaxf(mx, s);
            }
        }
        float A[16];
        #pragma unroll
        for (int j = 0; j < 16; ++j) A[j] = 0.f;
        float Bv = 0.f, den = 0.f;
        #pragma unroll
        for (int dg = 0; dg < 16; ++dg) {
            #pragma unroll
            for (int dj = 0; dj < 8; ++dj) {
                const int d = dg*8 + dj;
                float s = wk_s[d]*Pv[dg] + bk_s[d]*Qc;
                float e = __expf((s - mx) * 0.0625f);
                den += e;
                A[dg] = fmaf(e, wv_s[d], A[dg]);
                Bv = fmaf(e, bv_s[d], Bv);
            }
        }
        const float inv = 1.f / den;
        #pragma unroll
        for (int j = 0; j < 16; ++j) A_s[c2][j] = A[j]*inv;
        B_s[c2] = Bv*inv;
    }
    __syncthreads();
    {
        const int cl = t >> 4, j = t & 15;
        const int cp = h*16 + cl;
        float m = 0.f;
        #pragma unroll
        for (int hp = 0; hp < 8; ++hp)
            m = fmaf(cwo[cp*8+hp], A_s[cl*8+hp][j], m);
        M_s[cl][j] = m;
        if (j == 0) {
            float cc = cbo[cp];
            #pragma unroll
            for (int hp = 0; hp < 8; ++hp)
                cc = fmaf(cwo[cp*8+hp], B_s[cl*8+hp], cc);
            c_s[cl] = cc;
        }
    }
    __syncthreads();
    {
        const float g  = gamma[0];
        const float gp = gpos[0];
        const int l = t;
        float av[16];
        #pragma unroll
        for (int cl = 0; cl < 16; ++cl) {
            float a = c_s[cl];
            #pragma unroll
            for (int j = 0; j < 16; ++j)
                a = fmaf(M_s[cl][j], qh[j][l], a);
            av[cl] = a;
        }
        const ushort_t* p0 = P + ((size_t)b*NL + l)*NC + h*16;
        const ushort_t* p1 = p0 + PHALF;
        const float* qp = qpos + ((size_t)b*NC + h*16)*NL + l;
        float4* cp4 = (float4*)(comb + ((size_t)b*NL + l)*NC + h*16);
        #pragma unroll
        for (int q = 0; q < 4; ++q) {
            uint2 u0 = *(const uint2*)(p0 + 4*q);
            uint2 u1 = *(const uint2*)(p1 + 4*q);
            float s0 = bf2f((ushort_t)(u0.x & 0xffffu)) + bf2f((ushort_t)(u1.x & 0xffffu));
            float s1 = bf2f((ushort_t)(u0.x >> 16))     + bf2f((ushort_t)(u1.x >> 16));
            float s2 = bf2f((ushort_t)(u0.y & 0xffffu)) + bf2f((ushort_t)(u1.y & 0xffffu));
            float s3 = bf2f((ushort_t)(u0.y >> 16))     + bf2f((ushort_t)(u1.y >> 16));
            float4 c;
            c.x = 0.5f*(qp[(4*q+0)*NL] + gp*(pbo[h*16+4*q+0] + s0) + qh[4*q+0][l] + g*av[4*q+0]);
            c.y = 0.5f*(qp[(4*q+1)*NL] + gp*(pbo[h*16+4*q+1] + s1) + qh[4*q+1][l] + g*av[4*q+1]);
            c.z = 0.5f*(qp[(4*q+2)*NL] + gp*(pbo[h*16+4*q+2] + s2) + qh[4*q+2][l] + g*av[4*q+2]);
            c.w = 0.5f*(qp[(4*q+3)*NL] + gp*(pbo[h*16+4*q+3] + s3) + qh[4*q+3][l] + g*av[4*q+3]);
            cp4[q] = c;
        }
    }
}

extern "C" void kernel_launch(void* const* d_in, const int* in_sizes, int n_in,
                              void* d_out, int out_size, void* d_ws, size_t ws_size,
                              hipStream_t stream)
{
    const float* qpos = (const float*)d_in[0];
    const float* qcha = (const float*)d_in[1];
    const float* pwq  = (const float*)d_in[2];
    const float* pbq  = (const float*)d_in[3];
    const float* pwk  = (const float*)d_in[4];
    const float* pbk  = (const float*)d_in[5];
    const float* pwv  = (const float*)d_in[6];
    const float* pbv  = (const float*)d_in[7];
    const float* pwo  = (const float*)d_in[8];
    const float* pbo  = (const float*)d_in[9];
    const float* gpos = (const float*)d_in[10];
    const float* cwq  = (const float*)d_in[11];
    const float* cbq  = (const float*)d_in[12];
    const float* cwk  = (const float*)d_in[13];
    const float* cbk  = (const float*)d_in[14];
    const float* cwv  = (const float*)d_in[15];
    const float* cbv  = (const float*)d_in[16];
    const float* cwo  = (const float*)d_in[17];
    const float* cbo  = (const float*)d_in[18];
    const float* gcha = (const float*)d_in[19];
    const float* fw   = (const float*)d_in[20];
    const float* fb   = (const float*)d_in[21];
    float* outp = (float*)d_out;

    char* ws = (char*)d_ws;
    ushort_t* att  = (ushort_t*)ws;                       // 33,554,432 B (NHWC bf16)
    float*    comb = (float*)ws;                          // 16,777,216 B (overlays att; att dead)
    ushort_t* P    = (ushort_t*)(ws + 33554432);          // 16,777,216 B (2 bf16 partial halves)
    short*    wp1  = (short*)(ws + 50331648);             //  1,179,648 B
    short*    wp2  = (short*)(ws + 51511296);             //    294,912 B
    short*    wpq  = (short*)(ws + 51806208);             //     32,768 B
    short*    wpk  = (short*)(ws + 51838976);             //     32,768 B
    short*    wpv  = (short*)(ws + 51871744);             //    131,072 B

    k_wpack<NEV><<<dim3((NEV*1152 + 255)/256), 256, 0, stream>>>(pwo, wp1);
    k_wpack<NC ><<<dim3((NC *1152 + 255)/256), 256, 0, stream>>>(fw,  wp2);
    k_wpack_qkv<128><<<dim3(64),  256, 0, stream>>>(pwq, wpq);
    k_wpack_qkv<128><<<dim3(64),  256, 0, stream>>>(pwk, wpk);
    k_wpack_qkv<512><<<dim3(256), 256, 0, stream>>>(pwv, wpv);

    k_pos_mfma<<<dim3(NH, NB), 256, 0, stream>>>(qpos, wpq, wpk, wpv,
                                                 pbq, pbk, pbv, att);
    k_conv_ci<<<dim3(2, NB), 512, 0, stream>>>(att, wp1, P);
    k_cha<<<dim3(NH, NB), 256, 0, stream>>>(qcha, cwq, cbq, cwk, cbk, cwv, cbv,
                                            cwo, cbo, gcha,
                                            P, qpos, pbo, gpos, comb);
    k_conv_co<<<dim3(2, NB), 512, 0, stream>>>(comb, wp2, fb, outp);
}

// Round 6
// 182.942 us; speedup vs baseline: 7.9458x; 1.0162x over previous
//
#include <hip/hip_runtime.h>
#include <cstdint>
#include <cstddef>

typedef unsigned short ushort_t;
typedef unsigned int uint_t;
typedef __attribute__((ext_vector_type(8))) short bf16x8;
typedef __attribute__((ext_vector_type(4))) float f32x4;

#define NB 128
#define NC 128
#define NL 256
#define NH 8
#define HD 16
#define HDV 64
#define NEV 512
#define PHALF 4194304   // elements per conv1 partial half (128*256*128)

__device__ __forceinline__ ushort_t f2bf(float f) {
    uint_t u = __float_as_uint(f);
    u += 0x7fffu + ((u >> 16) & 1u);
    return (ushort_t)(u >> 16);
}
__device__ __forceinline__ float bf2f(ushort_t s) {
    return __uint_as_float(((uint_t)s) << 16);
}
__device__ __forceinline__ uint_t pack2(float lo, float hi) {
    return ((uint_t)f2bf(hi) << 16) | (uint_t)f2bf(lo);
}

// ---------------- K0: pack conv weights into MFMA A-fragment order (bf16)
template<int CIN>
__global__ __launch_bounds__(256) void k_wpack(const float* __restrict__ w,
                                               short* __restrict__ wp) {
    int idx = blockIdx.x * 256 + threadIdx.x;
    if (idx >= CIN * 1152) return;      // CIN*9*128 elements
    int j    = idx & 7;
    int lane = (idx >> 3) & 63;
    int frag = idx >> 9;
    int rt   = frag & 7;
    int tap  = (frag >> 3) % 9;
    int ch   = frag / 72;
    int co   = rt * 16 + (lane & 15);
    int g    = lane >> 4;
    int ci   = ch * 32 + g * 8 + j;
    wp[idx] = (short)f2bf(w[((size_t)co * CIN + ci) * 9 + tap]);
}

// ---------------- K0b: pack projection weights (E x 128) into A-frag order
template<int E>
__global__ __launch_bounds__(256) void k_wpack_qkv(const float* __restrict__ w,
                                                   short* __restrict__ wp) {
    int idx = blockIdx.x * 256 + threadIdx.x;
    if (idx >= E * 128) return;
    int j    = idx & 7;
    int lane = (idx >> 3) & 63;
    int ch   = (idx >> 9) & 3;
    int rt   = idx >> 11;
    int n = lane & 15, g = lane >> 4;
    wp[idx] = (short)f2bf(w[(size_t)(rt*16 + n)*128 + ch*32 + g*8 + j]);
}

// ---------------- K0c: transpose X (NCHW f32) -> xbf (NHWC bf16), once.
// grid (2, NB): half = 64-channel half. thread t = l.
__global__ __launch_bounds__(256) void k_xpose(const float* __restrict__ x,
                                               ushort_t* __restrict__ xbf) {
    const int half = blockIdx.x, b = blockIdx.y, t = threadIdx.x;
    const float* src = x + (size_t)b*NC*NL + (size_t)half*64*NL + t;
    ushort_t* dst = xbf + ((size_t)b*NL + t)*NC + half*64;
    #pragma unroll
    for (int k8 = 0; k8 < 8; ++k8) {
        bf16x8 v;
        #pragma unroll
        for (int j = 0; j < 8; ++j) v[j] = (short)f2bf(src[(k8*8 + j)*NL]);
        *(bf16x8*)(dst + k8*8) = v;
    }
}

// ---------------- K1: full-MFMA position attention. Block = (h, b), 4 waves.
// Phase A: barrier-free projections, B-frags straight from xbf (global).
// LDS (shorts): PKT @0 [256][16] ; PQT @4096 + w*1024 [64][16] ;
//               PBUF @8192 + w*640 [16][40] ; PVT @10752 [64 dv][264 l]
__global__ __launch_bounds__(256) void k_pos_mfma(
    const ushort_t* __restrict__ xbf,
    const short* __restrict__ wpq, const short* __restrict__ wpk,
    const short* __restrict__ wpv,
    const float* __restrict__ bq, const float* __restrict__ bk,
    const float* __restrict__ bv,
    ushort_t* __restrict__ att)
{
    const int h = blockIdx.x, b = blockIdx.y;
    const int t = threadIdx.x;
    const int lane = t & 63, w = t >> 6;
    const int n = lane & 15, g = lane >> 4;

    __shared__ __align__(16) short lds[27648];   // 55.3 KB

    const f32x4 z4 = {0.f, 0.f, 0.f, 0.f};
    f32x4 qacc[4], kacc[4], vacc[4][4];
    #pragma unroll
    for (int ct = 0; ct < 4; ++ct) { qacc[ct] = z4; kacc[ct] = z4; }
    #pragma unroll
    for (int vt = 0; vt < 4; ++vt)
        #pragma unroll
        for (int ct = 0; ct < 4; ++ct) vacc[vt][ct] = z4;

    // lane's row base in xbf for this wave's l-quarter
    const ushort_t* xr = xbf + ((size_t)(b*NL + w*64 + n))*NC;

    // ---- Phase A: 4 k-chunks of 32 channels; no LDS, no barriers
    #pragma unroll 2
    for (int ch = 0; ch < 4; ++ch) {
        bf16x8 xb[4];
        #pragma unroll
        for (int ct = 0; ct < 4; ++ct)
            xb[ct] = *(const bf16x8*)(xr + ct*16*NC + ch*32 + g*8);
        const size_t fo = ((size_t)((h*4 + ch)*64) + lane) * 8;
        {
            bf16x8 aq = *(const bf16x8*)(wpq + fo);
            #pragma unroll
            for (int ct = 0; ct < 4; ++ct)
                qacc[ct] = __builtin_amdgcn_mfma_f32_16x16x32_bf16(aq, xb[ct], qacc[ct], 0, 0, 0);
        }
        {
            bf16x8 ak = *(const bf16x8*)(wpk + fo);
            #pragma unroll
            for (int ct = 0; ct < 4; ++ct)
                kacc[ct] = __builtin_amdgcn_mfma_f32_16x16x32_bf16(ak, xb[ct], kacc[ct], 0, 0, 0);
        }
        #pragma unroll
        for (int vt = 0; vt < 4; ++vt) {
            bf16x8 av = *(const bf16x8*)(wpv + ((size_t)((((h*4 + vt)*4) + ch)*64) + lane) * 8);
            #pragma unroll
            for (int ct = 0; ct < 4; ++ct)   // SWAPPED: D[l][dv]
                vacc[vt][ct] = __builtin_amdgcn_mfma_f32_16x16x32_bf16(xb[ct], av, vacc[vt][ct], 0, 0, 0);
        }
    }

    // ---- stores: Q [q][dq], K [k][dq] (uint2); V [dv][l] (uint2, swapped layout)
    {
        float bqv[4], bkv[4];
        #pragma unroll
        for (int r = 0; r < 4; ++r) {
            bqv[r] = bq[h*16 + g*4 + r];
            bkv[r] = bk[h*16 + g*4 + r];
        }
        #pragma unroll
        for (int ct = 0; ct < 4; ++ct) {
            uint2 qp, kp;
            qp.x = pack2(qacc[ct][0] + bqv[0], qacc[ct][1] + bqv[1]);
            qp.y = pack2(qacc[ct][2] + bqv[2], qacc[ct][3] + bqv[3]);
            *(uint2*)&lds[4096 + w*1024 + (ct*16 + n)*16 + g*4] = qp;
            kp.x = pack2(kacc[ct][0] + bkv[0], kacc[ct][1] + bkv[1]);
            kp.y = pack2(kacc[ct][2] + bkv[2], kacc[ct][3] + bkv[3]);
            *(uint2*)&lds[(w*64 + ct*16 + n)*16 + g*4] = kp;
        }
        #pragma unroll
        for (int vt = 0; vt < 4; ++vt) {
            const float bvv = bv[h*64 + vt*16 + n];   // dv = vt*16 + n
            #pragma unroll
            for (int ct = 0; ct < 4; ++ct) {
                uint2 vp;
                vp.x = pack2(vacc[vt][ct][0] + bvv, vacc[vt][ct][1] + bvv);
                vp.y = pack2(vacc[vt][ct][2] + bvv, vacc[vt][ct][3] + bvv);
                *(uint2*)&lds[10752 + (vt*16 + n)*264 + w*64 + ct*16 + g*4] = vp;
            }
        }
    }
    __syncthreads();

    // ---- Phase B: per wave, 4 q-tiles of 16 q
    #pragma unroll 1
    for (int qt = 0; qt < 4; ++qt) {
        bf16x8 qf = (bf16x8){0,0,0,0,0,0,0,0};
        if (g < 2) qf = *(const bf16x8*)&lds[4096 + w*1024 + (qt*16 + n)*16 + g*8];
        f32x4 s[16];
        #pragma unroll
        for (int kt = 0; kt < 16; ++kt) {
            bf16x8 kf = (bf16x8){0,0,0,0,0,0,0,0};
            if (g < 2) kf = *(const bf16x8*)&lds[(kt*16 + n)*16 + g*8];
            s[kt] = __builtin_amdgcn_mfma_f32_16x16x32_bf16(kf, qf, z4, 0, 0, 0);
        }
        float m = -3.0e38f;
        #pragma unroll
        for (int kt = 0; kt < 16; ++kt)
            #pragma unroll
            for (int r = 0; r < 4; ++r)
                m = fmaxf(m, s[kt][r]);
        m = fmaxf(m, __shfl_xor(m, 16));
        m = fmaxf(m, __shfl_xor(m, 32));
        float den = 0.f;
        #pragma unroll
        for (int kt = 0; kt < 16; ++kt)
            #pragma unroll
            for (int r = 0; r < 4; ++r) {
                float e = __expf((s[kt][r] - m) * 0.25f);
                s[kt][r] = e;
                den += e;
            }
        den += __shfl_xor(den, 16);
        den += __shfl_xor(den, 32);
        const float inv = 1.f / den;

        f32x4 oacc[4] = {z4, z4, z4, z4};
        #pragma unroll
        for (int c2 = 0; c2 < 8; ++c2) {
            #pragma unroll
            for (int u = 0; u < 2; ++u) {
                const int kt = 2*c2 + u;
                uint2 pp;
                pp.x = pack2(s[kt][0], s[kt][1]);
                pp.y = pack2(s[kt][2], s[kt][3]);
                *(uint2*)&lds[8192 + w*640 + n*40 + u*16 + g*4] = pp;
            }
            bf16x8 pf = *(const bf16x8*)&lds[8192 + w*640 + n*40 + g*8];
            #pragma unroll
            for (int vt = 0; vt < 4; ++vt) {
                bf16x8 av = *(const bf16x8*)&lds[10752 + (vt*16 + n)*264 + c2*32 + g*8];
                oacc[vt] = __builtin_amdgcn_mfma_f32_16x16x32_bf16(av, pf, oacc[vt], 0, 0, 0);
            }
        }
        ushort_t* ap = att + (((size_t)b*NL + (w*64 + qt*16 + n))*NEV + h*HDV + g*4);
        #pragma unroll
        for (int vt = 0; vt < 4; ++vt) {
            uint2 op;
            op.x = pack2(oacc[vt][0]*inv, oacc[vt][1]*inv);
            op.y = pack2(oacc[vt][2]*inv, oacc[vt][3]*inv);
            *(uint2*)(ap + vt*16) = op;
        }
    }
}

// ---------------- K2: conv1 (3x3, 512->128) ci-split implicit GEMM.
__global__ __launch_bounds__(512, 2) void k_conv_ci(
    const ushort_t* __restrict__ att, const short* __restrict__ wp,
    ushort_t* __restrict__ P)
{
    const int kc = blockIdx.x, b = blockIdx.y;
    const int t = threadIdx.x;
    const int lane = t & 63, w = t >> 6;
    const int wr = w >> 2, wc = w & 3;
    const int n = lane & 15, gl = lane >> 4;

    __shared__ __align__(16) short ims[2][10368];   // 2 x 20.25 KB

    {
        bf16x8 z = {0,0,0,0,0,0,0,0};
        bf16x8* p = (bf16x8*)&ims[0][0];
        for (int i = t; i < 2592; i += 512) p[i] = z;
    }

    f32x4 acc[4][4];
    #pragma unroll
    for (int i = 0; i < 4; ++i)
        #pragma unroll
        for (int j = 0; j < 4; ++j) acc[i][j] = (f32x4){0.f,0.f,0.f,0.f};

    const int g1 = t & 3, x1 = (t >> 2) & 15, y1 = t >> 6;
    const ushort_t* src1 = att + ((size_t)(b*NL + y1*16 + x1))*NEV + kc*256 + g1*8;
    const ushort_t* src2 = att + ((size_t)(b*NL + (y1+8)*16 + x1))*NEV + kc*256 + g1*8;
    const int slot1 = (((y1+1)*4 + g1)*18 + x1 + 1) * 8;
    const int slot2 = (((y1+9)*4 + g1)*18 + x1 + 1) * 8;

    bf16x8 v1 = *(const bf16x8*)src1;
    bf16x8 v2 = *(const bf16x8*)src2;
    __syncthreads();

    #pragma unroll 1
    for (int ch = 0; ch < 8; ++ch) {
        short* buf = &ims[ch & 1][0];
        *(bf16x8*)&buf[slot1] = v1;
        *(bf16x8*)&buf[slot2] = v2;
        if (ch < 7) {
            v1 = *(const bf16x8*)(src1 + (ch + 1) * 32);
            v2 = *(const bf16x8*)(src2 + (ch + 1) * 32);
        }
        __syncthreads();
        #pragma unroll
        for (int tap = 0; tap < 9; ++tap) {
            const int dy = tap / 3, dx = tap % 3;
            bf16x8 Bf[4];
            #pragma unroll
            for (int ct = 0; ct < 4; ++ct)
                Bf[ct] = *(const bf16x8*)&buf[((((wc*4 + ct + dy)*4) + gl)*18 + n + dx) * 8];
            bf16x8 Af[4];
            #pragma unroll
            for (int rt = 0; rt < 4; ++rt)
                Af[rt] = *(const bf16x8*)(wp +
                    ((size_t)(((kc*8 + ch)*9 + tap)*8 + wr*4 + rt)) * 512 + lane*8);
            #pragma unroll
            for (int rt = 0; rt < 4; ++rt)
                #pragma unroll
                for (int ct = 0; ct < 4; ++ct)
                    acc[rt][ct] = __builtin_amdgcn_mfma_f32_16x16x32_bf16(
                        Af[rt], Bf[ct], acc[rt][ct], 0, 0, 0);
        }
    }

    ushort_t* Pb = P + (size_t)kc * PHALF + (size_t)b * NL * NC;
    #pragma unroll
    for (int rt = 0; rt < 4; ++rt) {
        const int co0 = wr*64 + rt*16 + gl*4;
        #pragma unroll
        for (int ct = 0; ct < 4; ++ct) {
            const int l = wc*64 + ct*16 + n;
            uint2 u;
            u.x = pack2(acc[rt][ct][0], acc[rt][ct][1]);
            u.y = pack2(acc[rt][ct][2], acc[rt][ct][3]);
            *(uint2*)(Pb + (size_t)l*NC + co0) = u;
        }
    }
}

// ---------------- K4: conv2 (3x3, 128->128) co-split implicit GEMM.
__global__ __launch_bounds__(512, 2) void k_conv_co(
    const float* __restrict__ comb, const short* __restrict__ wp,
    const float* __restrict__ bias, float* __restrict__ out)
{
    const int kc = blockIdx.x, b = blockIdx.y;
    const int t = threadIdx.x;
    const int lane = t & 63, w = t >> 6;
    const int wr = w & 1, wc = w >> 1;
    const int n = lane & 15, gl = lane >> 4;

    __shared__ __align__(16) short ims[2][10368];

    {
        bf16x8 z = {0,0,0,0,0,0,0,0};
        bf16x8* p = (bf16x8*)&ims[0][0];
        for (int i = t; i < 2592; i += 512) p[i] = z;
    }

    f32x4 acc[2][4];
    #pragma unroll
    for (int i = 0; i < 2; ++i)
        #pragma unroll
        for (int j = 0; j < 4; ++j) acc[i][j] = (f32x4){0.f,0.f,0.f,0.f};

    const int g1 = t & 3, x1 = (t >> 2) & 15, y1 = t >> 6;
    const float* s1 = comb + ((size_t)(b*NL + y1*16 + x1))*NC + g1*8;
    const float* s2 = comb + ((size_t)(b*NL + (y1+8)*16 + x1))*NC + g1*8;
    const int slot1 = (((y1+1)*4 + g1)*18 + x1 + 1) * 8;
    const int slot2 = (((y1+9)*4 + g1)*18 + x1 + 1) * 8;

    float4 a1 = *(const float4*)s1,       b1_ = *(const float4*)(s1 + 4);
    float4 a2 = *(const float4*)s2,       b2_ = *(const float4*)(s2 + 4);
    __syncthreads();

    #pragma unroll 1
    for (int ch = 0; ch < 4; ++ch) {
        short* buf = &ims[ch & 1][0];
        bf16x8 w1, w2;
        w1[0]=(short)f2bf(a1.x);  w1[1]=(short)f2bf(a1.y);
        w1[2]=(short)f2bf(a1.z);  w1[3]=(short)f2bf(a1.w);
        w1[4]=(short)f2bf(b1_.x); w1[5]=(short)f2bf(b1_.y);
        w1[6]=(short)f2bf(b1_.z); w1[7]=(short)f2bf(b1_.w);
        w2[0]=(short)f2bf(a2.x);  w2[1]=(short)f2bf(a2.y);
        w2[2]=(short)f2bf(a2.z);  w2[3]=(short)f2bf(a2.w);
        w2[4]=(short)f2bf(b2_.x); w2[5]=(short)f2bf(b2_.y);
        w2[6]=(short)f2bf(b2_.z); w2[7]=(short)f2bf(b2_.w);
        *(bf16x8*)&buf[slot1] = w1;
        *(bf16x8*)&buf[slot2] = w2;
        if (ch < 3) {
            a1  = *(const float4*)(s1 + (ch+1)*32);
            b1_ = *(const float4*)(s1 + (ch+1)*32 + 4);
            a2  = *(const float4*)(s2 + (ch+1)*32);
            b2_ = *(const float4*)(s2 + (ch+1)*32 + 4);
        }
        __syncthreads();
        #pragma unroll
        for (int tap = 0; tap < 9; ++tap) {
            const int dy = tap / 3, dx = tap % 3;
            bf16x8 Bf[4];
            #pragma unroll
            for (int ct = 0; ct < 4; ++ct)
                Bf[ct] = *(const bf16x8*)&buf[((((wc*4 + ct + dy)*4) + gl)*18 + n + dx) * 8];
            bf16x8 Af[2];
            #pragma unroll
            for (int rt = 0; rt < 2; ++rt)
                Af[rt] = *(const bf16x8*)(wp +
                    ((size_t)((ch*9 + tap)*8 + kc*4 + wr*2 + rt)) * 512 + lane*8);
            #pragma unroll
            for (int rt = 0; rt < 2; ++rt)
                #pragma unroll
                for (int ct = 0; ct < 4; ++ct)
                    acc[rt][ct] = __builtin_amdgcn_mfma_f32_16x16x32_bf16(
                        Af[rt], Bf[ct], acc[rt][ct], 0, 0, 0);
        }
    }

    #pragma unroll
    for (int rt = 0; rt < 2; ++rt) {
        const int co0 = kc*64 + wr*32 + rt*16 + gl*4;
        const float c0 = bias[co0+0], c1 = bias[co0+1],
                    c2 = bias[co0+2], c3 = bias[co0+3];
        #pragma unroll
        for (int ct = 0; ct < 4; ++ct) {
            const int l = wc*64 + ct*16 + n;
            f32x4 a = acc[rt][ct];
            out[((size_t)b*NC + co0+0)*NL + l] = c0 + a[0];
            out[((size_t)b*NC + co0+1)*NL + l] = c1 + a[1];
            out[((size_t)b*NC + co0+2)*NL + l] = c2 + a[2];
            out[((size_t)b*NC + co0+3)*NL + l] = c3 + a[3];
        }
    }
}

// ---------------- K3: channel attention + fold conv1 partials + pos residual + fusion
#define NLP 260
__global__ __launch_bounds__(256) void k_cha(
    const float* __restrict__ xc,
    const float* __restrict__ cwq, const float* __restrict__ cbq,
    const float* __restrict__ cwk, const float* __restrict__ cbk,
    const float* __restrict__ cwv, const float* __restrict__ cbv,
    const float* __restrict__ cwo, const float* __restrict__ cbo,
    const float* __restrict__ gamma,
    const ushort_t* __restrict__ P, const float* __restrict__ qpos,
    const float* __restrict__ pbo, const float* __restrict__ gpos,
    float* __restrict__ comb)
{
    const int h = blockIdx.x, b = blockIdx.y, t = threadIdx.x;
    __shared__ float qh[16][NLP];
    __shared__ float G_s[16][17];
    __shared__ float S_s[16];
    __shared__ float wq_s[128], bq_s[128], wk_s[128], bk_s[128], wv_s[128], bv_s[128];
    __shared__ float A_s[128][17];
    __shared__ float B_s[128];
    __shared__ float M_s[16][17];
    __shared__ float c_s[16];

    #pragma unroll
    for (int j = 0; j < 16; ++j)
        qh[j][t] = xc[((size_t)b*NC + h*16 + j)*NL + t];
    if (t < 128) {
        const int k = h*128 + t;
        wq_s[t] = cwq[k]; bq_s[t] = cbq[k];
        wk_s[t] = cwk[k]; bk_s[t] = cbk[k];
        wv_s[t] = cwv[k]; bv_s[t] = cbv[k];
    }
    __syncthreads();
    {
        const int i = t >> 4, j = t & 15;
        const float4* qi = (const float4*)qh[i];
        const float4* qj = (const float4*)qh[j];
        float gg = 0.f;
        for (int l4 = 0; l4 < NL/4; ++l4) {
            float4 a = qi[l4], c = qj[l4];
            gg = fmaf(a.x,c.x,fmaf(a.y,c.y,fmaf(a.z,c.z,fmaf(a.w,c.w,gg))));
        }
        G_s[i][j] = gg;
    }
    if (t < 16) {
        const float4* qi = (const float4*)qh[t];
        float s = 0.f;
        for (int l4 = 0; l4 < NL/4; ++l4) { float4 a = qi[l4]; s += a.x + a.y + a.z + a.w; }
        S_s[t] = s;
    }
    __syncthreads();
    if (t < 128) {
        const int c2 = t, cg = c2 >> 3;
        const float wqc = wq_s[c2], bqc = bq_s[c2];
        float Pv[16];
        #pragma unroll
        for (int j = 0; j < 16; ++j) Pv[j] = wqc*G_s[cg][j] + bqc*S_s[j];
        const float Qc = wqc*S_s[cg] + bqc*256.0f;
        float mx = -3.0e38f;
        #pragma unroll
        for (int dg = 0; dg < 16; ++dg) {
            #pragma unroll
            for (int dj = 0; dj < 8; ++dj) {
                const int d = dg*8 + dj;
                float s = wk_s[d]*Pv[dg] + bk_s[d]*Qc;
                mx = fmaxf(mx, s);
            }
        }
        float A[16];
        #pragma unroll
        for (int j = 0; j < 16; ++j) A[j] = 0.f;
        float Bv = 0.f, den = 0.f;
        #pragma unroll
        for (int dg = 0; dg < 16; ++dg) {
            #pragma unroll
            for (int dj = 0; dj < 8; ++dj) {
                const int d = dg*8 + dj;
                float s = wk_s[d]*Pv[dg] + bk_s[d]*Qc;
                float e = __expf((s - mx) * 0.0625f);
                den += e;
                A[dg] = fmaf(e, wv_s[d], A[dg]);
                Bv = fmaf(e, bv_s[d], Bv);
            }
        }
        const float inv = 1.f / den;
        #pragma unroll
        for (int j = 0; j < 16; ++j) A_s[c2][j] = A[j]*inv;
        B_s[c2] = Bv*inv;
    }
    __syncthreads();
    {
        const int cl = t >> 4, j = t & 15;
        const int cp = h*16 + cl;
        float m = 0.f;
        #pragma unroll
        for (int hp = 0; hp < 8; ++hp)
            m = fmaf(cwo[cp*8+hp], A_s[cl*8+hp][j], m);
        M_s[cl][j] = m;
        if (j == 0) {
            float cc = cbo[cp];
            #pragma unroll
            for (int hp = 0; hp < 8; ++hp)
                cc = fmaf(cwo[cp*8+hp], B_s[cl*8+hp], cc);
            c_s[cl] = cc;
        }
    }
    __syncthreads();
    {
        const float g  = gamma[0];
        const float gp = gpos[0];
        const int l = t;
        float av[16];
        #pragma unroll
        for (int cl = 0; cl < 16; ++cl) {
            float a = c_s[cl];
            #pragma unroll
            for (int j = 0; j < 16; ++j)
                a = fmaf(M_s[cl][j], qh[j][l], a);
            av[cl] = a;
        }
        const ushort_t* p0 = P + ((size_t)b*NL + l)*NC + h*16;
        const ushort_t* p1 = p0 + PHALF;
        const float* qp = qpos + ((size_t)b*NC + h*16)*NL + l;
        float4* cp4 = (float4*)(comb + ((size_t)b*NL + l)*NC + h*16);
        #pragma unroll
        for (int q = 0; q < 4; ++q) {
            uint2 u0 = *(const uint2*)(p0 + 4*q);
            uint2 u1 = *(const uint2*)(p1 + 4*q);
            float s0 = bf2f((ushort_t)(u0.x & 0xffffu)) + bf2f((ushort_t)(u1.x & 0xffffu));
            float s1 = bf2f((ushort_t)(u0.x >> 16))     + bf2f((ushort_t)(u1.x >> 16));
            float s2 = bf2f((ushort_t)(u0.y & 0xffffu)) + bf2f((ushort_t)(u1.y & 0xffffu));
            float s3 = bf2f((ushort_t)(u0.y >> 16))     + bf2f((ushort_t)(u1.y >> 16));
            float4 c;
            c.x = 0.5f*(qp[(4*q+0)*NL] + gp*(pbo[h*16+4*q+0] + s0) + qh[4*q+0][l] + g*av[4*q+0]);
            c.y = 0.5f*(qp[(4*q+1)*NL] + gp*(pbo[h*16+4*q+1] + s1) + qh[4*q+1][l] + g*av[4*q+1]);
            c.z = 0.5f*(qp[(4*q+2)*NL] + gp*(pbo[h*16+4*q+2] + s2) + qh[4*q+2][l] + g*av[4*q+2]);
            c.w = 0.5f*(qp[(4*q+3)*NL] + gp*(pbo[h*16+4*q+3] + s3) + qh[4*q+3][l] + g*av[4*q+3]);
            cp4[q] = c;
        }
    }
}

extern "C" void kernel_launch(void* const* d_in, const int* in_sizes, int n_in,
                              void* d_out, int out_size, void* d_ws, size_t ws_size,
                              hipStream_t stream)
{
    const float* qpos = (const float*)d_in[0];
    const float* qcha = (const float*)d_in[1];
    const float* pwq  = (const float*)d_in[2];
    const float* pbq  = (const float*)d_in[3];
    const float* pwk  = (const float*)d_in[4];
    const float* pbk  = (const float*)d_in[5];
    const float* pwv  = (const float*)d_in[6];
    const float* pbv  = (const float*)d_in[7];
    const float* pwo  = (const float*)d_in[8];
    const float* pbo  = (const float*)d_in[9];
    const float* gpos = (const float*)d_in[10];
    const float* cwq  = (const float*)d_in[11];
    const float* cbq  = (const float*)d_in[12];
    const float* cwk  = (const float*)d_in[13];
    const float* cbk  = (const float*)d_in[14];
    const float* cwv  = (const float*)d_in[15];
    const float* cbv  = (const float*)d_in[16];
    const float* cwo  = (const float*)d_in[17];
    const float* cbo  = (const float*)d_in[18];
    const float* gcha = (const float*)d_in[19];
    const float* fw   = (const float*)d_in[20];
    const float* fb   = (const float*)d_in[21];
    float* outp = (float*)d_out;

    char* ws = (char*)d_ws;
    ushort_t* att  = (ushort_t*)ws;                       // 33,554,432 B (NHWC bf16)
    float*    comb = (float*)ws;                          // 16,777,216 B (overlays att; att dead)
    ushort_t* P    = (ushort_t*)(ws + 33554432);          // 16,777,216 B (2 bf16 partial halves)
    ushort_t* xbf  = (ushort_t*)(ws + 33554432);          //  8,388,608 B (overlays P; dead before conv_ci)
    short*    wp1  = (short*)(ws + 50331648);             //  1,179,648 B
    short*    wp2  = (short*)(ws + 51511296);             //    294,912 B
    short*    wpq  = (short*)(ws + 51806208);             //     32,768 B
    short*    wpk  = (short*)(ws + 51838976);             //     32,768 B
    short*    wpv  = (short*)(ws + 51871744);             //    131,072 B

    k_wpack<NEV><<<dim3((NEV*1152 + 255)/256), 256, 0, stream>>>(pwo, wp1);
    k_wpack<NC ><<<dim3((NC *1152 + 255)/256), 256, 0, stream>>>(fw,  wp2);
    k_wpack_qkv<128><<<dim3(64),  256, 0, stream>>>(pwq, wpq);
    k_wpack_qkv<128><<<dim3(64),  256, 0, stream>>>(pwk, wpk);
    k_wpack_qkv<512><<<dim3(256), 256, 0, stream>>>(pwv, wpv);

    k_xpose<<<dim3(2, NB), 256, 0, stream>>>(qpos, xbf);
    k_pos_mfma<<<dim3(NH, NB), 256, 0, stream>>>(xbf, wpq, wpk, wpv,
                                                 pbq, pbk, pbv, att);
    k_conv_ci<<<dim3(2, NB), 512, 0, stream>>>(att, wp1, P);
    k_cha<<<dim3(NH, NB), 256, 0, stream>>>(qcha, cwq, cbq, cwk, cbk, cwv, cbv,
                                            cwo, cbo, gcha,
                                            P, qpos, pbo, gpos, comb);
    k_conv_co<<<dim3(2, NB), 512, 0, stream>>>(comb, wp2, fb, outp);
}

// Round 7
// 181.833 us; speedup vs baseline: 7.9943x; 1.0061x over previous
//
#include <hip/hip_runtime.h>
#include <cstdint>
#include <cstddef>

typedef unsigned short ushort_t;
typedef unsigned int uint_t;
typedef __attribute__((ext_vector_type(8))) short bf16x8;
typedef __attribute__((ext_vector_type(4))) float f32x4;

#define NB 128
#define NC 128
#define NL 256
#define NH 8
#define HD 16
#define HDV 64
#define NEV 512
#define PHALF 4194304   // elements per conv1 partial half (128*256*128)

__device__ __forceinline__ ushort_t f2bf(float f) {
    uint_t u = __float_as_uint(f);
    u += 0x7fffu + ((u >> 16) & 1u);
    return (ushort_t)(u >> 16);
}
__device__ __forceinline__ float bf2f(ushort_t s) {
    return __uint_as_float(((uint_t)s) << 16);
}
// single-instruction packed f32->bf16 (RNE), lo in low 16 bits
__device__ __forceinline__ uint_t pack2(float lo, float hi) {
    uint_t r;
    asm("v_cvt_pk_bf16_f32 %0, %1, %2" : "=v"(r) : "v"(lo), "v"(hi));
    return r;
}

// ---------------- K0: pack conv weights into MFMA A-fragment order (bf16)
template<int CIN>
__global__ __launch_bounds__(256) void k_wpack(const float* __restrict__ w,
                                               short* __restrict__ wp) {
    int idx = blockIdx.x * 256 + threadIdx.x;
    if (idx >= CIN * 1152) return;      // CIN*9*128 elements
    int j    = idx & 7;
    int lane = (idx >> 3) & 63;
    int frag = idx >> 9;
    int rt   = frag & 7;
    int tap  = (frag >> 3) % 9;
    int ch   = frag / 72;
    int co   = rt * 16 + (lane & 15);
    int g    = lane >> 4;
    int ci   = ch * 32 + g * 8 + j;
    wp[idx] = (short)f2bf(w[((size_t)co * CIN + ci) * 9 + tap]);
}

// ---------------- K0b: pack projection weights (E x 128) into A-frag order
template<int E>
__global__ __launch_bounds__(256) void k_wpack_qkv(const float* __restrict__ w,
                                                   short* __restrict__ wp) {
    int idx = blockIdx.x * 256 + threadIdx.x;
    if (idx >= E * 128) return;
    int j    = idx & 7;
    int lane = (idx >> 3) & 63;
    int ch   = (idx >> 9) & 3;
    int rt   = idx >> 11;
    int n = lane & 15, g = lane >> 4;
    wp[idx] = (short)f2bf(w[(size_t)(rt*16 + n)*128 + ch*32 + g*8 + j]);
}

// ---------------- K0c: transpose X (NCHW f32) -> xbf (NHWC bf16), once.
__global__ __launch_bounds__(256) void k_xpose(const float* __restrict__ x,
                                               ushort_t* __restrict__ xbf) {
    const int half = blockIdx.x, b = blockIdx.y, t = threadIdx.x;
    const float* src = x + (size_t)b*NC*NL + (size_t)half*64*NL + t;
    uint_t* dst = (uint_t*)(xbf + ((size_t)b*NL + t)*NC + half*64);
    #pragma unroll
    for (int k8 = 0; k8 < 8; ++k8) {
        uint4 u;
        u.x = pack2(src[(k8*8+0)*NL], src[(k8*8+1)*NL]);
        u.y = pack2(src[(k8*8+2)*NL], src[(k8*8+3)*NL]);
        u.z = pack2(src[(k8*8+4)*NL], src[(k8*8+5)*NL]);
        u.w = pack2(src[(k8*8+6)*NL], src[(k8*8+7)*NL]);
        *(uint4*)(dst + k8*4) = u;
    }
}

// ---------------- K1: full-MFMA position attention. Block = (h, b), 4 waves.
// LDS map (shorts): PKT @0 [256][24] ; PQT @6144 + w*1536 [64][24] ;
//                   PBUF @12288 + w*640 [16][40] ; PVT @14848 [64 dv][264 l]
__global__ __launch_bounds__(256) void k_pos_mfma(
    const ushort_t* __restrict__ xbf,
    const short* __restrict__ wpq, const short* __restrict__ wpk,
    const short* __restrict__ wpv,
    const float* __restrict__ bq, const float* __restrict__ bk,
    const float* __restrict__ bv,
    ushort_t* __restrict__ att)
{
    const int h = blockIdx.x, b = blockIdx.y;
    const int t = threadIdx.x;
    const int lane = t & 63, w = t >> 6;
    const int n = lane & 15, g = lane >> 4;

    __shared__ __align__(16) short lds[31744];   // 63.5 KB

    const f32x4 z4 = {0.f, 0.f, 0.f, 0.f};
    f32x4 qacc[4], kacc[4], vacc[4][4];
    #pragma unroll
    for (int ct = 0; ct < 4; ++ct) { qacc[ct] = z4; kacc[ct] = z4; }
    #pragma unroll
    for (int vt = 0; vt < 4; ++vt)
        #pragma unroll
        for (int ct = 0; ct < 4; ++ct) vacc[vt][ct] = z4;

    const ushort_t* xr = xbf + ((size_t)(b*NL + w*64 + n))*NC;

    // ---- Phase A: 4 k-chunks of 32 channels; no LDS, no barriers
    #pragma unroll 2
    for (int ch = 0; ch < 4; ++ch) {
        bf16x8 xb[4];
        #pragma unroll
        for (int ct = 0; ct < 4; ++ct)
            xb[ct] = *(const bf16x8*)(xr + ct*16*NC + ch*32 + g*8);
        const size_t fo = ((size_t)((h*4 + ch)*64) + lane) * 8;
        {
            bf16x8 aq = *(const bf16x8*)(wpq + fo);
            #pragma unroll
            for (int ct = 0; ct < 4; ++ct)
                qacc[ct] = __builtin_amdgcn_mfma_f32_16x16x32_bf16(aq, xb[ct], qacc[ct], 0, 0, 0);
        }
        {
            bf16x8 ak = *(const bf16x8*)(wpk + fo);
            #pragma unroll
            for (int ct = 0; ct < 4; ++ct)
                kacc[ct] = __builtin_amdgcn_mfma_f32_16x16x32_bf16(ak, xb[ct], kacc[ct], 0, 0, 0);
        }
        #pragma unroll
        for (int vt = 0; vt < 4; ++vt) {
            bf16x8 av = *(const bf16x8*)(wpv + ((size_t)((((h*4 + vt)*4) + ch)*64) + lane) * 8);
            #pragma unroll
            for (int ct = 0; ct < 4; ++ct)   // SWAPPED: D[l][dv]
                vacc[vt][ct] = __builtin_amdgcn_mfma_f32_16x16x32_bf16(xb[ct], av, vacc[vt][ct], 0, 0, 0);
        }
    }

    // ---- stores: Q [q][24-stride], K [k][24-stride] (uint2); V [dv][264] (uint2)
    {
        float bqv[4], bkv[4];
        #pragma unroll
        for (int r = 0; r < 4; ++r) {
            bqv[r] = bq[h*16 + g*4 + r];
            bkv[r] = bk[h*16 + g*4 + r];
        }
        #pragma unroll
        for (int ct = 0; ct < 4; ++ct) {
            uint2 qp, kp;
            qp.x = pack2(qacc[ct][0] + bqv[0], qacc[ct][1] + bqv[1]);
            qp.y = pack2(qacc[ct][2] + bqv[2], qacc[ct][3] + bqv[3]);
            *(uint2*)&lds[6144 + w*1536 + (ct*16 + n)*24 + g*4] = qp;
            kp.x = pack2(kacc[ct][0] + bkv[0], kacc[ct][1] + bkv[1]);
            kp.y = pack2(kacc[ct][2] + bkv[2], kacc[ct][3] + bkv[3]);
            *(uint2*)&lds[(w*64 + ct*16 + n)*24 + g*4] = kp;
        }
        #pragma unroll
        for (int vt = 0; vt < 4; ++vt) {
            const float bvv = bv[h*64 + vt*16 + n];   // dv = vt*16 + n
            #pragma unroll
            for (int ct = 0; ct < 4; ++ct) {
                uint2 vp;
                vp.x = pack2(vacc[vt][ct][0] + bvv, vacc[vt][ct][1] + bvv);
                vp.y = pack2(vacc[vt][ct][2] + bvv, vacc[vt][ct][3] + bvv);
                *(uint2*)&lds[14848 + (vt*16 + n)*264 + w*64 + ct*16 + g*4] = vp;
            }
        }
    }
    __syncthreads();

    // ---- Phase B: per wave, 4 q-tiles of 16 q
    #pragma unroll 1
    for (int qt = 0; qt < 4; ++qt) {
        bf16x8 qf = (bf16x8){0,0,0,0,0,0,0,0};
        if (g < 2) qf = *(const bf16x8*)&lds[6144 + w*1536 + (qt*16 + n)*24 + g*8];
        f32x4 s[16];
        #pragma unroll
        for (int kt = 0; kt < 16; ++kt) {
            bf16x8 kf = (bf16x8){0,0,0,0,0,0,0,0};
            if (g < 2) kf = *(const bf16x8*)&lds[(kt*16 + n)*24 + g*8];
            s[kt] = __builtin_amdgcn_mfma_f32_16x16x32_bf16(kf, qf, z4, 0, 0, 0);
        }
        // softmax over k (no max subtraction: |s*0.25| < ~2, exp-safe)
        float den = 0.f;
        #pragma unroll
        for (int kt = 0; kt < 16; ++kt)
            #pragma unroll
            for (int r = 0; r < 4; ++r) {
                float e = exp2f(s[kt][r] * 0.36067376022224085f);  // 0.25*log2(e)
                s[kt][r] = e;
                den += e;
            }
        den += __shfl_xor(den, 16);
        den += __shfl_xor(den, 32);
        const float inv = 1.f / den;

        f32x4 oacc[4] = {z4, z4, z4, z4};
        #pragma unroll
        for (int c2 = 0; c2 < 8; ++c2) {
            #pragma unroll
            for (int u = 0; u < 2; ++u) {
                const int kt = 2*c2 + u;
                uint2 pp;
                pp.x = pack2(s[kt][0], s[kt][1]);
                pp.y = pack2(s[kt][2], s[kt][3]);
                *(uint2*)&lds[12288 + w*640 + n*40 + u*16 + g*4] = pp;
            }
            bf16x8 pf = *(const bf16x8*)&lds[12288 + w*640 + n*40 + g*8];
            #pragma unroll
            for (int vt = 0; vt < 4; ++vt) {
                bf16x8 av = *(const bf16x8*)&lds[14848 + (vt*16 + n)*264 + c2*32 + g*8];
                oacc[vt] = __builtin_amdgcn_mfma_f32_16x16x32_bf16(av, pf, oacc[vt], 0, 0, 0);
            }
        }
        ushort_t* ap = att + (((size_t)b*NL + (w*64 + qt*16 + n))*NEV + h*HDV + g*4);
        #pragma unroll
        for (int vt = 0; vt < 4; ++vt) {
            uint2 op;
            op.x = pack2(oacc[vt][0]*inv, oacc[vt][1]*inv);
            op.y = pack2(oacc[vt][2]*inv, oacc[vt][3]*inv);
            *(uint2*)(ap + vt*16) = op;
        }
    }
}

// ---------------- K2: conv1 (3x3, 512->128) ci-split implicit GEMM.
__global__ __launch_bounds__(512, 2) void k_conv_ci(
    const ushort_t* __restrict__ att, const short* __restrict__ wp,
    ushort_t* __restrict__ P)
{
    const int kc = blockIdx.x, b = blockIdx.y;
    const int t = threadIdx.x;
    const int lane = t & 63, w = t >> 6;
    const int wr = w >> 2, wc = w & 3;
    const int n = lane & 15, gl = lane >> 4;

    __shared__ __align__(16) short ims[2][10368];   // 2 x 20.25 KB

    {
        bf16x8 z = {0,0,0,0,0,0,0,0};
        bf16x8* p = (bf16x8*)&ims[0][0];
        for (int i = t; i < 2592; i += 512) p[i] = z;
    }

    f32x4 acc[4][4];
    #pragma unroll
    for (int i = 0; i < 4; ++i)
        #pragma unroll
        for (int j = 0; j < 4; ++j) acc[i][j] = (f32x4){0.f,0.f,0.f,0.f};

    const int g1 = t & 3, x1 = (t >> 2) & 15, y1 = t >> 6;
    const ushort_t* src1 = att + ((size_t)(b*NL + y1*16 + x1))*NEV + kc*256 + g1*8;
    const ushort_t* src2 = att + ((size_t)(b*NL + (y1+8)*16 + x1))*NEV + kc*256 + g1*8;
    const int slot1 = (((y1+1)*4 + g1)*18 + x1 + 1) * 8;
    const int slot2 = (((y1+9)*4 + g1)*18 + x1 + 1) * 8;

    bf16x8 v1 = *(const bf16x8*)src1;
    bf16x8 v2 = *(const bf16x8*)src2;
    __syncthreads();

    #pragma unroll 1
    for (int ch = 0; ch < 8; ++ch) {
        short* buf = &ims[ch & 1][0];
        *(bf16x8*)&buf[slot1] = v1;
        *(bf16x8*)&buf[slot2] = v2;
        if (ch < 7) {
            v1 = *(const bf16x8*)(src1 + (ch + 1) * 32);
            v2 = *(const bf16x8*)(src2 + (ch + 1) * 32);
        }
        __syncthreads();
        #pragma unroll
        for (int tap = 0; tap < 9; ++tap) {
            const int dy = tap / 3, dx = tap % 3;
            bf16x8 Bf[4];
            #pragma unroll
            for (int ct = 0; ct < 4; ++ct)
                Bf[ct] = *(const bf16x8*)&buf[((((wc*4 + ct + dy)*4) + gl)*18 + n + dx) * 8];
            bf16x8 Af[4];
            #pragma unroll
            for (int rt = 0; rt < 4; ++rt)
                Af[rt] = *(const bf16x8*)(wp +
                    ((size_t)(((kc*8 + ch)*9 + tap)*8 + wr*4 + rt)) * 512 + lane*8);
            #pragma unroll
            for (int rt = 0; rt < 4; ++rt)
                #pragma unroll
                for (int ct = 0; ct < 4; ++ct)
                    acc[rt][ct] = __builtin_amdgcn_mfma_f32_16x16x32_bf16(
                        Af[rt], Bf[ct], acc[rt][ct], 0, 0, 0);
        }
    }

    ushort_t* Pb = P + (size_t)kc * PHALF + (size_t)b * NL * NC;
    #pragma unroll
    for (int rt = 0; rt < 4; ++rt) {
        const int co0 = wr*64 + rt*16 + gl*4;
        #pragma unroll
        for (int ct = 0; ct < 4; ++ct) {
            const int l = wc*64 + ct*16 + n;
            uint2 u;
            u.x = pack2(acc[rt][ct][0], acc[rt][ct][1]);
            u.y = pack2(acc[rt][ct][2], acc[rt][ct][3]);
            *(uint2*)(Pb + (size_t)l*NC + co0) = u;
        }
    }
}

// ---------------- K4: conv2 (3x3, 128->128) co-split implicit GEMM.
__global__ __launch_bounds__(512, 2) void k_conv_co(
    const float* __restrict__ comb, const short* __restrict__ wp,
    const float* __restrict__ bias, float* __restrict__ out)
{
    const int kc = blockIdx.x, b = blockIdx.y;
    const int t = threadIdx.x;
    const int lane = t & 63, w = t >> 6;
    const int wr = w & 1, wc = w >> 1;
    const int n = lane & 15, gl = lane >> 4;

    __shared__ __align__(16) short ims[2][10368];

    {
        bf16x8 z = {0,0,0,0,0,0,0,0};
        bf16x8* p = (bf16x8*)&ims[0][0];
        for (int i = t; i < 2592; i += 512) p[i] = z;
    }

    f32x4 acc[2][4];
    #pragma unroll
    for (int i = 0; i < 2; ++i)
        #pragma unroll
        for (int j = 0; j < 4; ++j) acc[i][j] = (f32x4){0.f,0.f,0.f,0.f};

    const int g1 = t & 3, x1 = (t >> 2) & 15, y1 = t >> 6;
    const float* s1 = comb + ((size_t)(b*NL + y1*16 + x1))*NC + g1*8;
    const float* s2 = comb + ((size_t)(b*NL + (y1+8)*16 + x1))*NC + g1*8;
    const int slot1 = (((y1+1)*4 + g1)*18 + x1 + 1) * 8;
    const int slot2 = (((y1+9)*4 + g1)*18 + x1 + 1) * 8;

    float4 a1 = *(const float4*)s1,       b1_ = *(const float4*)(s1 + 4);
    float4 a2 = *(const float4*)s2,       b2_ = *(const float4*)(s2 + 4);
    __syncthreads();

    #pragma unroll 1
    for (int ch = 0; ch < 4; ++ch) {
        short* buf = &ims[ch & 1][0];
        uint4 w1, w2;
        w1.x = pack2(a1.x, a1.y);   w1.y = pack2(a1.z, a1.w);
        w1.z = pack2(b1_.x, b1_.y); w1.w = pack2(b1_.z, b1_.w);
        w2.x = pack2(a2.x, a2.y);   w2.y = pack2(a2.z, a2.w);
        w2.z = pack2(b2_.x, b2_.y); w2.w = pack2(b2_.z, b2_.w);
        *(uint4*)&buf[slot1] = w1;
        *(uint4*)&buf[slot2] = w2;
        if (ch < 3) {
            a1  = *(const float4*)(s1 + (ch+1)*32);
            b1_ = *(const float4*)(s1 + (ch+1)*32 + 4);
            a2  = *(const float4*)(s2 + (ch+1)*32);
            b2_ = *(const float4*)(s2 + (ch+1)*32 + 4);
        }
        __syncthreads();
        #pragma unroll
        for (int tap = 0; tap < 9; ++tap) {
            const int dy = tap / 3, dx = tap % 3;
            bf16x8 Bf[4];
            #pragma unroll
            for (int ct = 0; ct < 4; ++ct)
                Bf[ct] = *(const bf16x8*)&buf[((((wc*4 + ct + dy)*4) + gl)*18 + n + dx) * 8];
            bf16x8 Af[2];
            #pragma unroll
            for (int rt = 0; rt < 2; ++rt)
                Af[rt] = *(const bf16x8*)(wp +
                    ((size_t)((ch*9 + tap)*8 + kc*4 + wr*2 + rt)) * 512 + lane*8);
            #pragma unroll
            for (int rt = 0; rt < 2; ++rt)
                #pragma unroll
                for (int ct = 0; ct < 4; ++ct)
                    acc[rt][ct] = __builtin_amdgcn_mfma_f32_16x16x32_bf16(
                        Af[rt], Bf[ct], acc[rt][ct], 0, 0, 0);
        }
    }

    #pragma unroll
    for (int rt = 0; rt < 2; ++rt) {
        const int co0 = kc*64 + wr*32 + rt*16 + gl*4;
        const float c0 = bias[co0+0], c1 = bias[co0+1],
                    c2 = bias[co0+2], c3 = bias[co0+3];
        #pragma unroll
        for (int ct = 0; ct < 4; ++ct) {
            const int l = wc*64 + ct*16 + n;
            f32x4 a = acc[rt][ct];
            out[((size_t)b*NC + co0+0)*NL + l] = c0 + a[0];
            out[((size_t)b*NC + co0+1)*NL + l] = c1 + a[1];
            out[((size_t)b*NC + co0+2)*NL + l] = c2 + a[2];
            out[((size_t)b*NC + co0+3)*NL + l] = c3 + a[3];
        }
    }
}

// ---------------- K3: channel attention + fold conv1 partials + pos residual + fusion
#define NLP 260
__global__ __launch_bounds__(256) void k_cha(
    const float* __restrict__ xc,
    const float* __restrict__ cwq, const float* __restrict__ cbq,
    const float* __restrict__ cwk, const float* __restrict__ cbk,
    const float* __restrict__ cwv, const float* __restrict__ cbv,
    const float* __restrict__ cwo, const float* __restrict__ cbo,
    const float* __restrict__ gamma,
    const ushort_t* __restrict__ P, const float* __restrict__ qpos,
    const float* __restrict__ pbo, const float* __restrict__ gpos,
    float* __restrict__ comb)
{
    const int h = blockIdx.x, b = blockIdx.y, t = threadIdx.x;
    __shared__ float qh[16][NLP];
    __shared__ float G_s[16][17];
    __shared__ float S_s[16];
    __shared__ float wq_s[128], bq_s[128], wk_s[128], bk_s[128], wv_s[128], bv_s[128];
    __shared__ float A_s[128][17];
    __shared__ float B_s[128];
    __shared__ float M_s[16][17];
    __shared__ float c_s[16];

    #pragma unroll
    for (int j = 0; j < 16; ++j)
        qh[j][t] = xc[((size_t)b*NC + h*16 + j)*NL + t];
    if (t < 128) {
        const int k = h*128 + t;
        wq_s[t] = cwq[k]; bq_s[t] = cbq[k];
        wk_s[t] = cwk[k]; bk_s[t] = cbk[k];
        wv_s[t] = cwv[k]; bv_s[t] = cbv[k];
    }
    __syncthreads();
    {
        const int i = t >> 4, j = t & 15;
        const float4* qi = (const float4*)qh[i];
        const float4* qj = (const float4*)qh[j];
        float gg = 0.f;
        for (int l4 = 0; l4 < NL/4; ++l4) {
            float4 a = qi[l4], c = qj[l4];
            gg = fmaf(a.x,c.x,fmaf(a.y,c.y,fmaf(a.z,c.z,fmaf(a.w,c.w,gg))));
        }
        G_s[i][j] = gg;
    }
    if (t < 16) {
        const float4* qi = (const float4*)qh[t];
        float s = 0.f;
        for (int l4 = 0; l4 < NL/4; ++l4) { float4 a = qi[l4]; s += a.x + a.y + a.z + a.w; }
        S_s[t] = s;
    }
    __syncthreads();
    if (t < 128) {
        const int c2 = t, cg = c2 >> 3;
        const float wqc = wq_s[c2], bqc = bq_s[c2];
        float Pv[16];
        #pragma unroll
        for (int j = 0; j < 16; ++j) Pv[j] = wqc*G_s[cg][j] + bqc*S_s[j];
        const float Qc = wqc*S_s[cg] + bqc*256.0f;
        float mx = -3.0e38f;
        #pragma unroll
        for (int dg = 0; dg < 16; ++dg) {
            #pragma unroll
            for (int dj = 0; dj < 8; ++dj) {
                const int d = dg*8 + dj;
                float s = wk_s[d]*Pv[dg] + bk_s[d]*Qc;
                mx = fmaxf(mx, s);
            }
        }
        float A[16];
        #pragma unroll
        for (int j = 0; j < 16; ++j) A[j] = 0.f;
        float Bv = 0.f, den = 0.f;
        #pragma unroll
        for (int dg = 0; dg < 16; ++dg) {
            #pragma unroll
            for (int dj = 0; dj < 8; ++dj) {
                const int d = dg*8 + dj;
                float s = wk_s[d]*Pv[dg] + bk_s[d]*Qc;
                float e = __expf((s - mx) * 0.0625f);
                den += e;
                A[dg] = fmaf(e, wv_s[d], A[dg]);
                Bv = fmaf(e, bv_s[d], Bv);
            }
        }
        const float inv = 1.f / den;
        #pragma unroll
        for (int j = 0; j < 16; ++j) A_s[c2][j] = A[j]*inv;
        B_s[c2] = Bv*inv;
    }
    __syncthreads();
    {
        const int cl = t >> 4, j = t & 15;
        const int cp = h*16 + cl;
        float m = 0.f;
        #pragma unroll
        for (int hp = 0; hp < 8; ++hp)
            m = fmaf(cwo[cp*8+hp], A_s[cl*8+hp][j], m);
        M_s[cl][j] = m;
        if (j == 0) {
            float cc = cbo[cp];
            #pragma unroll
            for (int hp = 0; hp < 8; ++hp)
                cc = fmaf(cwo[cp*8+hp], B_s[cl*8+hp], cc);
            c_s[cl] = cc;
        }
    }
    __syncthreads();
    {
        const float g  = gamma[0];
        const float gp = gpos[0];
        const int l = t;
        float av[16];
        #pragma unroll
        for (int cl = 0; cl < 16; ++cl) {
            float a = c_s[cl];
            #pragma unroll
            for (int j = 0; j < 16; ++j)
                a = fmaf(M_s[cl][j], qh[j][l], a);
            av[cl] = a;
        }
        const ushort_t* p0 = P + ((size_t)b*NL + l)*NC + h*16;
        const ushort_t* p1 = p0 + PHALF;
        const float* qp = qpos + ((size_t)b*NC + h*16)*NL + l;
        float4* cp4 = (float4*)(comb + ((size_t)b*NL + l)*NC + h*16);
        #pragma unroll
        for (int q = 0; q < 4; ++q) {
            uint2 u0 = *(const uint2*)(p0 + 4*q);
            uint2 u1 = *(const uint2*)(p1 + 4*q);
            float s0 = bf2f((ushort_t)(u0.x & 0xffffu)) + bf2f((ushort_t)(u1.x & 0xffffu));
            float s1 = bf2f((ushort_t)(u0.x >> 16))     + bf2f((ushort_t)(u1.x >> 16));
            float s2 = bf2f((ushort_t)(u0.y & 0xffffu)) + bf2f((ushort_t)(u1.y & 0xffffu));
            float s3 = bf2f((ushort_t)(u0.y >> 16))     + bf2f((ushort_t)(u1.y >> 16));
            float4 c;
            c.x = 0.5f*(qp[(4*q+0)*NL] + gp*(pbo[h*16+4*q+0] + s0) + qh[4*q+0][l] + g*av[4*q+0]);
            c.y = 0.5f*(qp[(4*q+1)*NL] + gp*(pbo[h*16+4*q+1] + s1) + qh[4*q+1][l] + g*av[4*q+1]);
            c.z = 0.5f*(qp[(4*q+2)*NL] + gp*(pbo[h*16+4*q+2] + s2) + qh[4*q+2][l] + g*av[4*q+2]);
            c.w = 0.5f*(qp[(4*q+3)*NL] + gp*(pbo[h*16+4*q+3] + s3) + qh[4*q+3][l] + g*av[4*q+3]);
            cp4[q] = c;
        }
    }
}

extern "C" void kernel_launch(void* const* d_in, const int* in_sizes, int n_in,
                              void* d_out, int out_size, void* d_ws, size_t ws_size,
                              hipStream_t stream)
{
    const float* qpos = (const float*)d_in[0];
    const float* qcha = (const float*)d_in[1];
    const float* pwq  = (const float*)d_in[2];
    const float* pbq  = (const float*)d_in[3];
    const float* pwk  = (const float*)d_in[4];
    const float* pbk  = (const float*)d_in[5];
    const float* pwv  = (const float*)d_in[6];
    const float* pbv  = (const float*)d_in[7];
    const float* pwo  = (const float*)d_in[8];
    const float* pbo  = (const float*)d_in[9];
    const float* gpos = (const float*)d_in[10];
    const float* cwq  = (const float*)d_in[11];
    const float* cbq  = (const float*)d_in[12];
    const float* cwk  = (const float*)d_in[13];
    const float* cbk  = (const float*)d_in[14];
    const float* cwv  = (const float*)d_in[15];
    const float* cbv  = (const float*)d_in[16];
    const float* cwo  = (const float*)d_in[17];
    const float* cbo  = (const float*)d_in[18];
    const float* gcha = (const float*)d_in[19];
    const float* fw   = (const float*)d_in[20];
    const float* fb   = (const float*)d_in[21];
    float* outp = (float*)d_out;

    char* ws = (char*)d_ws;
    ushort_t* att  = (ushort_t*)ws;                       // 33,554,432 B (NHWC bf16)
    float*    comb = (float*)ws;                          // 16,777,216 B (overlays att; att dead)
    ushort_t* P    = (ushort_t*)(ws + 33554432);          // 16,777,216 B (2 bf16 partial halves)
    ushort_t* xbf  = (ushort_t*)(ws + 33554432);          //  8,388,608 B (overlays P; dead before conv_ci)
    short*    wp1  = (short*)(ws + 50331648);             //  1,179,648 B
    short*    wp2  = (short*)(ws + 51511296);             //    294,912 B
    short*    wpq  = (short*)(ws + 51806208);             //     32,768 B
    short*    wpk  = (short*)(ws + 51838976);             //     32,768 B
    short*    wpv  = (short*)(ws + 51871744);             //    131,072 B

    k_wpack<NEV><<<dim3((NEV*1152 + 255)/256), 256, 0, stream>>>(pwo, wp1);
    k_wpack<NC ><<<dim3((NC *1152 + 255)/256), 256, 0, stream>>>(fw,  wp2);
    k_wpack_qkv<128><<<dim3(64),  256, 0, stream>>>(pwq, wpq);
    k_wpack_qkv<128><<<dim3(64),  256, 0, stream>>>(pwk, wpk);
    k_wpack_qkv<512><<<dim3(256), 256, 0, stream>>>(pwv, wpv);

    k_xpose<<<dim3(2, NB), 256, 0, stream>>>(qpos, xbf);
    k_pos_mfma<<<dim3(NH, NB), 256, 0, stream>>>(xbf, wpq, wpk, wpv,
                                                 pbq, pbk, pbv, att);
    k_conv_ci<<<dim3(2, NB), 512, 0, stream>>>(att, wp1, P);
    k_cha<<<dim3(NH, NB), 256, 0, stream>>>(qcha, cwq, cbq, cwk, cbk, cwv, cbv,
                                            cwo, cbo, gcha,
                                            P, qpos, pbo, gpos, comb);
    k_conv_co<<<dim3(2, NB), 512, 0, stream>>>(comb, wp2, fb, outp);
}

// Round 8
// 181.650 us; speedup vs baseline: 8.0023x; 1.0010x over previous
//
#include <hip/hip_runtime.h>
#include <cstdint>
#include <cstddef>

typedef unsigned short ushort_t;
typedef unsigned int uint_t;
typedef __attribute__((ext_vector_type(8))) short bf16x8;
typedef __attribute__((ext_vector_type(4))) float f32x4;

#define NB 128
#define NC 128
#define NL 256
#define NH 8
#define HD 16
#define HDV 64
#define NEV 512
#define PHALF 4194304   // elements per conv1 partial half (128*256*128)

__device__ __forceinline__ ushort_t f2bf(float f) {
    uint_t u = __float_as_uint(f);
    u += 0x7fffu + ((u >> 16) & 1u);
    return (ushort_t)(u >> 16);
}
__device__ __forceinline__ float bf2f(ushort_t s) {
    return __uint_as_float(((uint_t)s) << 16);
}
// single-instruction packed f32->bf16 (RNE), lo in low 16 bits
__device__ __forceinline__ uint_t pack2(float lo, float hi) {
    uint_t r;
    asm("v_cvt_pk_bf16_f32 %0, %1, %2" : "=v"(r) : "v"(lo), "v"(hi));
    return r;
}

// ---------------- K0: pack conv weights into MFMA A-fragment order (bf16)
template<int CIN>
__global__ __launch_bounds__(256) void k_wpack(const float* __restrict__ w,
                                               short* __restrict__ wp) {
    int idx = blockIdx.x * 256 + threadIdx.x;
    if (idx >= CIN * 1152) return;      // CIN*9*128 elements
    int j    = idx & 7;
    int lane = (idx >> 3) & 63;
    int frag = idx >> 9;
    int rt   = frag & 7;
    int tap  = (frag >> 3) % 9;
    int ch   = frag / 72;
    int co   = rt * 16 + (lane & 15);
    int g    = lane >> 4;
    int ci   = ch * 32 + g * 8 + j;
    wp[idx] = (short)f2bf(w[((size_t)co * CIN + ci) * 9 + tap]);
}

// ---------------- K0b: pack projection weights (E x 128) into A-frag order
template<int E>
__global__ __launch_bounds__(256) void k_wpack_qkv(const float* __restrict__ w,
                                                   short* __restrict__ wp) {
    int idx = blockIdx.x * 256 + threadIdx.x;
    if (idx >= E * 128) return;
    int j    = idx & 7;
    int lane = (idx >> 3) & 63;
    int ch   = (idx >> 9) & 3;
    int rt   = idx >> 11;
    int n = lane & 15, g = lane >> 4;
    wp[idx] = (short)f2bf(w[(size_t)(rt*16 + n)*128 + ch*32 + g*8 + j]);
}

// ---------------- K0c: transpose X (NCHW f32) -> xbf (NHWC bf16), once.
__global__ __launch_bounds__(256) void k_xpose(const float* __restrict__ x,
                                               ushort_t* __restrict__ xbf) {
    const int half = blockIdx.x, b = blockIdx.y, t = threadIdx.x;
    const float* src = x + (size_t)b*NC*NL + (size_t)half*64*NL + t;
    uint_t* dst = (uint_t*)(xbf + ((size_t)b*NL + t)*NC + half*64);
    #pragma unroll
    for (int k8 = 0; k8 < 8; ++k8) {
        uint4 u;
        u.x = pack2(src[(k8*8+0)*NL], src[(k8*8+1)*NL]);
        u.y = pack2(src[(k8*8+2)*NL], src[(k8*8+3)*NL]);
        u.z = pack2(src[(k8*8+4)*NL], src[(k8*8+5)*NL]);
        u.w = pack2(src[(k8*8+6)*NL], src[(k8*8+7)*NL]);
        *(uint4*)(dst + k8*4) = u;
    }
}

// ---------------- K1: full-MFMA position attention. Block = (h, b), 4 waves.
// LDS (shorts, 47.1 KB): PKT @0 [256][16] ; PBUF @4096 + w*640 [16][40] ;
//                        PVT @6656 [64 dv][264 l].  Q stays in registers
//                        (in-wave transpose via ds_bpermute).
__global__ __launch_bounds__(256) void k_pos_mfma(
    const ushort_t* __restrict__ xbf,
    const short* __restrict__ wpq, const short* __restrict__ wpk,
    const short* __restrict__ wpv,
    const float* __restrict__ bq, const float* __restrict__ bk,
    const float* __restrict__ bv,
    ushort_t* __restrict__ att)
{
    const int h = blockIdx.x, b = blockIdx.y;
    const int t = threadIdx.x;
    const int lane = t & 63, w = t >> 6;
    const int n = lane & 15, g = lane >> 4;

    __shared__ __align__(16) short lds[23552];   // 47.1 KB

    const f32x4 z4 = {0.f, 0.f, 0.f, 0.f};
    f32x4 qacc[4], kacc[4], vacc[4][4];
    #pragma unroll
    for (int ct = 0; ct < 4; ++ct) { qacc[ct] = z4; kacc[ct] = z4; }
    #pragma unroll
    for (int vt = 0; vt < 4; ++vt)
        #pragma unroll
        for (int ct = 0; ct < 4; ++ct) vacc[vt][ct] = z4;

    const ushort_t* xr = xbf + ((size_t)(b*NL + w*64 + n))*NC;

    // ---- Phase A: 4 k-chunks of 32 channels; no LDS, no barriers
    #pragma unroll 2
    for (int ch = 0; ch < 4; ++ch) {
        bf16x8 xb[4];
        #pragma unroll
        for (int ct = 0; ct < 4; ++ct)
            xb[ct] = *(const bf16x8*)(xr + ct*16*NC + ch*32 + g*8);
        const size_t fo = ((size_t)((h*4 + ch)*64) + lane) * 8;
        {
            bf16x8 aq = *(const bf16x8*)(wpq + fo);
            #pragma unroll
            for (int ct = 0; ct < 4; ++ct)
                qacc[ct] = __builtin_amdgcn_mfma_f32_16x16x32_bf16(aq, xb[ct], qacc[ct], 0, 0, 0);
        }
        {
            bf16x8 ak = *(const bf16x8*)(wpk + fo);
            #pragma unroll
            for (int ct = 0; ct < 4; ++ct)
                kacc[ct] = __builtin_amdgcn_mfma_f32_16x16x32_bf16(ak, xb[ct], kacc[ct], 0, 0, 0);
        }
        #pragma unroll
        for (int vt = 0; vt < 4; ++vt) {
            bf16x8 av = *(const bf16x8*)(wpv + ((size_t)((((h*4 + vt)*4) + ch)*64) + lane) * 8);
            #pragma unroll
            for (int ct = 0; ct < 4; ++ct)   // SWAPPED: D[l][dv]
                vacc[vt][ct] = __builtin_amdgcn_mfma_f32_16x16x32_bf16(xb[ct], av, vacc[vt][ct], 0, 0, 0);
        }
    }

    // ---- K/V -> LDS; Q -> packed registers (stays in-wave)
    uint_t qu01[4], qu23[4];
    {
        float bqv[4], bkv[4];
        #pragma unroll
        for (int r = 0; r < 4; ++r) {
            bqv[r] = bq[h*16 + g*4 + r];
            bkv[r] = bk[h*16 + g*4 + r];
        }
        #pragma unroll
        for (int ct = 0; ct < 4; ++ct) {
            qu01[ct] = pack2(qacc[ct][0] + bqv[0], qacc[ct][1] + bqv[1]);
            qu23[ct] = pack2(qacc[ct][2] + bqv[2], qacc[ct][3] + bqv[3]);
            uint2 kp;
            kp.x = pack2(kacc[ct][0] + bkv[0], kacc[ct][1] + bkv[1]);
            kp.y = pack2(kacc[ct][2] + bkv[2], kacc[ct][3] + bkv[3]);
            *(uint2*)&lds[(w*64 + ct*16 + n)*16 + g*4] = kp;
        }
        #pragma unroll
        for (int vt = 0; vt < 4; ++vt) {
            const float bvv = bv[h*64 + vt*16 + n];   // dv = vt*16 + n
            #pragma unroll
            for (int ct = 0; ct < 4; ++ct) {
                uint2 vp;
                vp.x = pack2(vacc[vt][ct][0] + bvv, vacc[vt][ct][1] + bvv);
                vp.y = pack2(vacc[vt][ct][2] + bvv, vacc[vt][ct][3] + bvv);
                *(uint2*)&lds[6656 + (vt*16 + n)*264 + w*64 + ct*16 + g*4] = vp;
            }
        }
    }
    __syncthreads();

    // ---- Phase B: per wave, 4 q-tiles of 16 q
    const int a0 = (n + 32*(g & 1)) * 4;      // source lane for dq[0..3] of this g
    #pragma unroll 1
    for (int qt = 0; qt < 4; ++qt) {
        // in-wave Q transpose: lane (n,g) gathers Q[qt*16+n][g*8..g*8+7]
        union { uint_t u[4]; bf16x8 v; } qfu;
        qfu.u[0] = (uint_t)__builtin_amdgcn_ds_bpermute(a0,      (int)qu01[qt]);
        qfu.u[1] = (uint_t)__builtin_amdgcn_ds_bpermute(a0,      (int)qu23[qt]);
        qfu.u[2] = (uint_t)__builtin_amdgcn_ds_bpermute(a0 + 64, (int)qu01[qt]);
        qfu.u[3] = (uint_t)__builtin_amdgcn_ds_bpermute(a0 + 64, (int)qu23[qt]);
        if (g >= 2) { qfu.u[0] = 0; qfu.u[1] = 0; qfu.u[2] = 0; qfu.u[3] = 0; }
        bf16x8 qf = qfu.v;

        f32x4 s[16];
        #pragma unroll
        for (int kt = 0; kt < 16; ++kt) {
            bf16x8 kf = (bf16x8){0,0,0,0,0,0,0,0};
            if (g < 2) kf = *(const bf16x8*)&lds[(kt*16 + n)*16 + g*8];
            s[kt] = __builtin_amdgcn_mfma_f32_16x16x32_bf16(kf, qf, z4, 0, 0, 0);
        }
        // softmax over k (no max subtraction: |s*0.25| < ~2, exp-safe)
        float den = 0.f;
        #pragma unroll
        for (int kt = 0; kt < 16; ++kt)
            #pragma unroll
            for (int r = 0; r < 4; ++r) {
                float e = exp2f(s[kt][r] * 0.36067376022224085f);  // 0.25*log2(e)
                s[kt][r] = e;
                den += e;
            }
        den += __shfl_xor(den, 16);
        den += __shfl_xor(den, 32);
        const float inv = 1.f / den;

        f32x4 oacc[4] = {z4, z4, z4, z4};
        #pragma unroll
        for (int c2 = 0; c2 < 8; ++c2) {
            #pragma unroll
            for (int u = 0; u < 2; ++u) {
                const int kt = 2*c2 + u;
                uint2 pp;
                pp.x = pack2(s[kt][0], s[kt][1]);
                pp.y = pack2(s[kt][2], s[kt][3]);
                *(uint2*)&lds[4096 + w*640 + n*40 + u*16 + g*4] = pp;
            }
            bf16x8 pf = *(const bf16x8*)&lds[4096 + w*640 + n*40 + g*8];
            #pragma unroll
            for (int vt = 0; vt < 4; ++vt) {
                bf16x8 av = *(const bf16x8*)&lds[6656 + (vt*16 + n)*264 + c2*32 + g*8];
                oacc[vt] = __builtin_amdgcn_mfma_f32_16x16x32_bf16(av, pf, oacc[vt], 0, 0, 0);
            }
        }
        ushort_t* ap = att + (((size_t)b*NL + (w*64 + qt*16 + n))*NEV + h*HDV + g*4);
        #pragma unroll
        for (int vt = 0; vt < 4; ++vt) {
            uint2 op;
            op.x = pack2(oacc[vt][0]*inv, oacc[vt][1]*inv);
            op.y = pack2(oacc[vt][2]*inv, oacc[vt][3]*inv);
            *(uint2*)(ap + vt*16) = op;
        }
    }
}

// ---------------- K2: conv1 (3x3, 512->128) ci+l-split implicit GEMM.
// grid (4, NB): blockIdx.x = kc*2 + lh. Block = 128co x 128l (l-half) x 256ci,
// 4 waves (2co x 2l), wave tile 64co x 64l. LDS: 10-row haloed image dbuf.
__global__ __launch_bounds__(256, 3) void k_conv_ci(
    const ushort_t* __restrict__ att, const short* __restrict__ wp,
    ushort_t* __restrict__ P)
{
    const int kc = blockIdx.x >> 1, lh = blockIdx.x & 1, b = blockIdx.y;
    const int t = threadIdx.x;
    const int lane = t & 63, w = t >> 6;
    const int wr = w >> 1, wc = w & 1;
    const int n = lane & 15, gl = lane >> 4;
    const int y0 = lh * 8;

    __shared__ __align__(16) short ims[2][5760];   // 2 x 11.25 KB (10yp x 4g x 18xp x 8ci)

    {   // zero both buffers once (halos stay zero; oob rows rewritten as zeros)
        bf16x8 z = {0,0,0,0,0,0,0,0};
        bf16x8* p = (bf16x8*)&ims[0][0];
        for (int i = t; i < 1440; i += 256) p[i] = z;
    }

    f32x4 acc[4][4];
    #pragma unroll
    for (int i = 0; i < 4; ++i)
        #pragma unroll
        for (int j = 0; j < 4; ++j) acc[i][j] = (f32x4){0.f,0.f,0.f,0.f};

    // staging: 640 tasks = 10yp x 16xx x 4gg; thread does t, t+256, (t<128: t+512)
    const int gg1 = t & 3,        xx1 = (t >> 2) & 15,        yp1 = t >> 6;
    const int id2 = t + 256;
    const int gg2 = id2 & 3,      xx2 = (id2 >> 2) & 15,      yp2 = id2 >> 6;
    const int id3 = t + 512;
    const int gg3 = id3 & 3,      xx3 = (id3 >> 2) & 15,      yp3 = id3 >> 6;
    const bool has3 = (t < 128);
    const int y1 = y0 - 1 + yp1, y2 = y0 - 1 + yp2, y3 = y0 - 1 + yp3;
    const bool ok1 = (y1 >= 0) && (y1 < 16);
    const bool ok2 = (y2 >= 0) && (y2 < 16);
    const bool ok3 = has3 && (y3 >= 0) && (y3 < 16);
    const ushort_t* src1 = att + ((size_t)(b*NL + y1*16 + xx1))*NEV + kc*256 + gg1*8;
    const ushort_t* src2 = att + ((size_t)(b*NL + y2*16 + xx2))*NEV + kc*256 + gg2*8;
    const ushort_t* src3 = att + ((size_t)(b*NL + y3*16 + xx3))*NEV + kc*256 + gg3*8;
    const int slot1 = ((yp1*4 + gg1)*18 + xx1 + 1) * 8;
    const int slot2 = ((yp2*4 + gg2)*18 + xx2 + 1) * 8;
    const int slot3 = ((yp3*4 + gg3)*18 + xx3 + 1) * 8;

    bf16x8 v1 = {0,0,0,0,0,0,0,0}, v2 = v1, v3 = v1;
    if (ok1) v1 = *(const bf16x8*)src1;          // prefetch chunk 0
    if (ok2) v2 = *(const bf16x8*)src2;
    if (ok3) v3 = *(const bf16x8*)src3;
    __syncthreads();                              // zero-init done

    #pragma unroll 1
    for (int ch = 0; ch < 8; ++ch) {
        short* buf = &ims[ch & 1][0];
        *(bf16x8*)&buf[slot1] = v1;
        *(bf16x8*)&buf[slot2] = v2;
        if (has3) *(bf16x8*)&buf[slot3] = v3;
        if (ch < 7) {                             // prefetch next chunk
            if (ok1) v1 = *(const bf16x8*)(src1 + (ch + 1) * 32);
            if (ok2) v2 = *(const bf16x8*)(src2 + (ch + 1) * 32);
            if (ok3) v3 = *(const bf16x8*)(src3 + (ch + 1) * 32);
        }
        __syncthreads();                          // image ready
        #pragma unroll
        for (int tap = 0; tap < 9; ++tap) {
            const int dy = tap / 3, dx = tap % 3;
            bf16x8 Bf[4];
            #pragma unroll
            for (int ct = 0; ct < 4; ++ct)
                Bf[ct] = *(const bf16x8*)&buf[(((wc*4 + ct + dy)*4 + gl)*18 + n + dx) * 8];
            bf16x8 Af[4];
            #pragma unroll
            for (int rt = 0; rt < 4; ++rt)
                Af[rt] = *(const bf16x8*)(wp +
                    ((size_t)(((kc*8 + ch)*9 + tap)*8 + wr*4 + rt)) * 512 + lane*8);
            #pragma unroll
            for (int rt = 0; rt < 4; ++rt)
                #pragma unroll
                for (int ct = 0; ct < 4; ++ct)
                    acc[rt][ct] = __builtin_amdgcn_mfma_f32_16x16x32_bf16(
                        Af[rt], Bf[ct], acc[rt][ct], 0, 0, 0);
        }
    }

    ushort_t* Pb = P + (size_t)kc * PHALF + (size_t)b * NL * NC;
    #pragma unroll
    for (int rt = 0; rt < 4; ++rt) {
        const int co0 = wr*64 + rt*16 + gl*4;
        #pragma unroll
        for (int ct = 0; ct < 4; ++ct) {
            const int l = lh*128 + wc*64 + ct*16 + n;
            uint2 u;
            u.x = pack2(acc[rt][ct][0], acc[rt][ct][1]);
            u.y = pack2(acc[rt][ct][2], acc[rt][ct][3]);
            *(uint2*)(Pb + (size_t)l*NC + co0) = u;
        }
    }
}

// ---------------- K4: conv2 (3x3, 128->128) co-split implicit GEMM.
__global__ __launch_bounds__(512, 2) void k_conv_co(
    const float* __restrict__ comb, const short* __restrict__ wp,
    const float* __restrict__ bias, float* __restrict__ out)
{
    const int kc = blockIdx.x, b = blockIdx.y;
    const int t = threadIdx.x;
    const int lane = t & 63, w = t >> 6;
    const int wr = w & 1, wc = w >> 1;
    const int n = lane & 15, gl = lane >> 4;

    __shared__ __align__(16) short ims[2][10368];

    {
        bf16x8 z = {0,0,0,0,0,0,0,0};
        bf16x8* p = (bf16x8*)&ims[0][0];
        for (int i = t; i < 2592; i += 512) p[i] = z;
    }

    f32x4 acc[2][4];
    #pragma unroll
    for (int i = 0; i < 2; ++i)
        #pragma unroll
        for (int j = 0; j < 4; ++j) acc[i][j] = (f32x4){0.f,0.f,0.f,0.f};

    const int g1 = t & 3, x1 = (t >> 2) & 15, y1 = t >> 6;
    const float* s1 = comb + ((size_t)(b*NL + y1*16 + x1))*NC + g1*8;
    const float* s2 = comb + ((size_t)(b*NL + (y1+8)*16 + x1))*NC + g1*8;
    const int slot1 = (((y1+1)*4 + g1)*18 + x1 + 1) * 8;
    const int slot2 = (((y1+9)*4 + g1)*18 + x1 + 1) * 8;

    float4 a1 = *(const float4*)s1,       b1_ = *(const float4*)(s1 + 4);
    float4 a2 = *(const float4*)s2,       b2_ = *(const float4*)(s2 + 4);
    __syncthreads();

    #pragma unroll 1
    for (int ch = 0; ch < 4; ++ch) {
        short* buf = &ims[ch & 1][0];
        uint4 w1, w2;
        w1.x = pack2(a1.x, a1.y);   w1.y = pack2(a1.z, a1.w);
        w1.z = pack2(b1_.x, b1_.y); w1.w = pack2(b1_.z, b1_.w);
        w2.x = pack2(a2.x, a2.y);   w2.y = pack2(a2.z, a2.w);
        w2.z = pack2(b2_.x, b2_.y); w2.w = pack2(b2_.z, b2_.w);
        *(uint4*)&buf[slot1] = w1;
        *(uint4*)&buf[slot2] = w2;
        if (ch < 3) {
            a1  = *(const float4*)(s1 + (ch+1)*32);
            b1_ = *(const float4*)(s1 + (ch+1)*32 + 4);
            a2  = *(const float4*)(s2 + (ch+1)*32);
            b2_ = *(const float4*)(s2 + (ch+1)*32 + 4);
        }
        __syncthreads();
        #pragma unroll
        for (int tap = 0; tap < 9; ++tap) {
            const int dy = tap / 3, dx = tap % 3;
            bf16x8 Bf[4];
            #pragma unroll
            for (int ct = 0; ct < 4; ++ct)
                Bf[ct] = *(const bf16x8*)&buf[((((wc*4 + ct + dy)*4) + gl)*18 + n + dx) * 8];
            bf16x8 Af[2];
            #pragma unroll
            for (int rt = 0; rt < 2; ++rt)
                Af[rt] = *(const bf16x8*)(wp +
                    ((size_t)((ch*9 + tap)*8 + kc*4 + wr*2 + rt)) * 512 + lane*8);
            #pragma unroll
            for (int rt = 0; rt < 2; ++rt)
                #pragma unroll
                for (int ct = 0; ct < 4; ++ct)
                    acc[rt][ct] = __builtin_amdgcn_mfma_f32_16x16x32_bf16(
                        Af[rt], Bf[ct], acc[rt][ct], 0, 0, 0);
        }
    }

    #pragma unroll
    for (int rt = 0; rt < 2; ++rt) {
        const int co0 = kc*64 + wr*32 + rt*16 + gl*4;
        const float c0 = bias[co0+0], c1 = bias[co0+1],
                    c2 = bias[co0+2], c3 = bias[co0+3];
        #pragma unroll
        for (int ct = 0; ct < 4; ++ct) {
            const int l = wc*64 + ct*16 + n;
            f32x4 a = acc[rt][ct];
            out[((size_t)b*NC + co0+0)*NL + l] = c0 + a[0];
            out[((size_t)b*NC + co0+1)*NL + l] = c1 + a[1];
            out[((size_t)b*NC + co0+2)*NL + l] = c2 + a[2];
            out[((size_t)b*NC + co0+3)*NL + l] = c3 + a[3];
        }
    }
}

// ---------------- K3: channel attention + fold conv1 partials + pos residual + fusion
#define NLP 260
__global__ __launch_bounds__(256) void k_cha(
    const float* __restrict__ xc,
    const float* __restrict__ cwq, const float* __restrict__ cbq,
    const float* __restrict__ cwk, const float* __restrict__ cbk,
    const float* __restrict__ cwv, const float* __restrict__ cbv,
    const float* __restrict__ cwo, const float* __restrict__ cbo,
    const float* __restrict__ gamma,
    const ushort_t* __restrict__ P, const float* __restrict__ qpos,
    const float* __restrict__ pbo, const float* __restrict__ gpos,
    float* __restrict__ comb)
{
    const int h = blockIdx.x, b = blockIdx.y, t = threadIdx.x;
    __shared__ float qh[16][NLP];
    __shared__ float G_s[16][17];
    __shared__ float S_s[16];
    __shared__ float wq_s[128], bq_s[128], wk_s[128], bk_s[128], wv_s[128], bv_s[128];
    __shared__ float A_s[128][17];
    __shared__ float B_s[128];
    __shared__ float M_s[16][17];
    __shared__ float c_s[16];

    #pragma unroll
    for (int j = 0; j < 16; ++j)
        qh[j][t] = xc[((size_t)b*NC + h*16 + j)*NL + t];
    if (t < 128) {
        const int k = h*128 + t;
        wq_s[t] = cwq[k]; bq_s[t] = cbq[k];
        wk_s[t] = cwk[k]; bk_s[t] = cbk[k];
        wv_s[t] = cwv[k]; bv_s[t] = cbv[k];
    }
    __syncthreads();
    {
        const int i = t >> 4, j = t & 15;
        const float4* qi = (const float4*)qh[i];
        const float4* qj = (const float4*)qh[j];
        float gg = 0.f;
        for (int l4 = 0; l4 < NL/4; ++l4) {
            float4 a = qi[l4], c = qj[l4];
            gg = fmaf(a.x,c.x,fmaf(a.y,c.y,fmaf(a.z,c.z,fmaf(a.w,c.w,gg))));
        }
        G_s[i][j] = gg;
    }
    if (t < 16) {
        const float4* qi = (const float4*)qh[t];
        float s = 0.f;
        for (int l4 = 0; l4 < NL/4; ++l4) { float4 a = qi[l4]; s += a.x + a.y + a.z + a.w; }
        S_s[t] = s;
    }
    __syncthreads();
    if (t < 128) {
        const int c2 = t, cg = c2 >> 3;
        const float wqc = wq_s[c2], bqc = bq_s[c2];
        float Pv[16];
        #pragma unroll
        for (int j = 0; j < 16; ++j) Pv[j] = wqc*G_s[cg][j] + bqc*S_s[j];
        const float Qc = wqc*S_s[cg] + bqc*256.0f;
        float mx = -3.0e38f;
        #pragma unroll
        for (int dg = 0; dg < 16; ++dg) {
            #pragma unroll
            for (int dj = 0; dj < 8; ++dj) {
                const int d = dg*8 + dj;
                float s = wk_s[d]*Pv[dg] + bk_s[d]*Qc;
                mx = fmaxf(mx, s);
            }
        }
        float A[16];
        #pragma unroll
        for (int j = 0; j < 16; ++j) A[j] = 0.f;
        float Bv = 0.f, den = 0.f;
        #pragma unroll
        for (int dg = 0; dg < 16; ++dg) {
            #pragma unroll
            for (int dj = 0; dj < 8; ++dj) {
                const int d = dg*8 + dj;
                float s = wk_s[d]*Pv[dg] + bk_s[d]*Qc;
                float e = __expf((s - mx) * 0.0625f);
                den += e;
                A[dg] = fmaf(e, wv_s[d], A[dg]);
                Bv = fmaf(e, bv_s[d], Bv);
            }
        }
        const float inv = 1.f / den;
        #pragma unroll
        for (int j = 0; j < 16; ++j) A_s[c2][j] = A[j]*inv;
        B_s[c2] = Bv*inv;
    }
    __syncthreads();
    {
        const int cl = t >> 4, j = t & 15;
        const int cp = h*16 + cl;
        float m = 0.f;
        #pragma unroll
        for (int hp = 0; hp < 8; ++hp)
            m = fmaf(cwo[cp*8+hp], A_s[cl*8+hp][j], m);
        M_s[cl][j] = m;
        if (j == 0) {
            float cc = cbo[cp];
            #pragma unroll
            for (int hp = 0; hp < 8; ++hp)
                cc = fmaf(cwo[cp*8+hp], B_s[cl*8+hp], cc);
            c_s[cl] = cc;
        }
    }
    __syncthreads();
    {
        const float g  = gamma[0];
        const float gp = gpos[0];
        const int l = t;
        float av[16];
        #pragma unroll
        for (int cl = 0; cl < 16; ++cl) {
            float a = c_s[cl];
            #pragma unroll
            for (int j = 0; j < 16; ++j)
                a = fmaf(M_s[cl][j], qh[j][l], a);
            av[cl] = a;
        }
        const ushort_t* p0 = P + ((size_t)b*NL + l)*NC + h*16;
        const ushort_t* p1 = p0 + PHALF;
        const float* qp = qpos + ((size_t)b*NC + h*16)*NL + l;
        float4* cp4 = (float4*)(comb + ((size_t)b*NL + l)*NC + h*16);
        #pragma unroll
        for (int q = 0; q < 4; ++q) {
            uint2 u0 = *(const uint2*)(p0 + 4*q);
            uint2 u1 = *(const uint2*)(p1 + 4*q);
            float s0 = bf2f((ushort_t)(u0.x & 0xffffu)) + bf2f((ushort_t)(u1.x & 0xffffu));
            float s1 = bf2f((ushort_t)(u0.x >> 16))     + bf2f((ushort_t)(u1.x >> 16));
            float s2 = bf2f((ushort_t)(u0.y & 0xffffu)) + bf2f((ushort_t)(u1.y & 0xffffu));
            float s3 = bf2f((ushort_t)(u0.y >> 16))     + bf2f((ushort_t)(u1.y >> 16));
            float4 c;
            c.x = 0.5f*(qp[(4*q+0)*NL] + gp*(pbo[h*16+4*q+0] + s0) + qh[4*q+0][l] + g*av[4*q+0]);
            c.y = 0.5f*(qp[(4*q+1)*NL] + gp*(pbo[h*16+4*q+1] + s1) + qh[4*q+1][l] + g*av[4*q+1]);
            c.z = 0.5f*(qp[(4*q+2)*NL] + gp*(pbo[h*16+4*q+2] + s2) + qh[4*q+2][l] + g*av[4*q+2]);
            c.w = 0.5f*(qp[(4*q+3)*NL] + gp*(pbo[h*16+4*q+3] + s3) + qh[4*q+3][l] + g*av[4*q+3]);
            cp4[q] = c;
        }
    }
}

extern "C" void kernel_launch(void* const* d_in, const int* in_sizes, int n_in,
                              void* d_out, int out_size, void* d_ws, size_t ws_size,
                              hipStream_t stream)
{
    const float* qpos = (const float*)d_in[0];
    const float* qcha = (const float*)d_in[1];
    const float* pwq  = (const float*)d_in[2];
    const float* pbq  = (const float*)d_in[3];
    const float* pwk  = (const float*)d_in[4];
    const float* pbk  = (const float*)d_in[5];
    const float* pwv  = (const float*)d_in[6];
    const float* pbv  = (const float*)d_in[7];
    const float* pwo  = (const float*)d_in[8];
    const float* pbo  = (const float*)d_in[9];
    const float* gpos = (const float*)d_in[10];
    const float* cwq  = (const float*)d_in[11];
    const float* cbq  = (const float*)d_in[12];
    const float* cwk  = (const float*)d_in[13];
    const float* cbk  = (const float*)d_in[14];
    const float* cwv  = (const float*)d_in[15];
    const float* cbv  = (const float*)d_in[16];
    const float* cwo  = (const float*)d_in[17];
    const float* cbo  = (const float*)d_in[18];
    const float* gcha = (const float*)d_in[19];
    const float* fw   = (const float*)d_in[20];
    const float* fb   = (const float*)d_in[21];
    float* outp = (float*)d_out;

    char* ws = (char*)d_ws;
    ushort_t* att  = (ushort_t*)ws;                       // 33,554,432 B (NHWC bf16)
    float*    comb = (float*)ws;                          // 16,777,216 B (overlays att; att dead)
    ushort_t* P    = (ushort_t*)(ws + 33554432);          // 16,777,216 B (2 bf16 partial halves)
    ushort_t* xbf  = (ushort_t*)(ws + 33554432);          //  8,388,608 B (overlays P; dead before conv_ci)
    short*    wp1  = (short*)(ws + 50331648);             //  1,179,648 B
    short*    wp2  = (short*)(ws + 51511296);             //    294,912 B
    short*    wpq  = (short*)(ws + 51806208);             //     32,768 B
    short*    wpk  = (short*)(ws + 51838976);             //     32,768 B
    short*    wpv  = (short*)(ws + 51871744);             //    131,072 B

    k_wpack<NEV><<<dim3((NEV*1152 + 255)/256), 256, 0, stream>>>(pwo, wp1);
    k_wpack<NC ><<<dim3((NC *1152 + 255)/256), 256, 0, stream>>>(fw,  wp2);
    k_wpack_qkv<128><<<dim3(64),  256, 0, stream>>>(pwq, wpq);
    k_wpack_qkv<128><<<dim3(64),  256, 0, stream>>>(pwk, wpk);
    k_wpack_qkv<512><<<dim3(256), 256, 0, stream>>>(pwv, wpv);

    k_xpose<<<dim3(2, NB), 256, 0, stream>>>(qpos, xbf);
    k_pos_mfma<<<dim3(NH, NB), 256, 0, stream>>>(xbf, wpq, wpk, wpv,
                                                 pbq, pbk, pbv, att);
    k_conv_ci<<<dim3(4, NB), 256, 0, stream>>>(att, wp1, P);
    k_cha<<<dim3(NH, NB), 256, 0, stream>>>(qcha, cwq, cbq, cwk, cbk, cwv, cbv,
                                            cwo, cbo, gcha,
                                            P, qpos, pbo, gpos, comb);
    k_conv_co<<<dim3(2, NB), 512, 0, stream>>>(comb, wp2, fb, outp);
}

// Round 9
// 175.198 us; speedup vs baseline: 8.2970x; 1.0368x over previous
//
#include <hip/hip_runtime.h>
#include <cstdint>
#include <cstddef>

typedef unsigned short ushort_t;
typedef unsigned int uint_t;
typedef __attribute__((ext_vector_type(8))) short bf16x8;
typedef __attribute__((ext_vector_type(4))) float f32x4;

#define NB 128
#define NC 128
#define NL 256
#define NH 8
#define HD 16
#define HDV 64
#define NEV 512
#define PHALF 4194304   // elements per conv1 partial half (128*256*128)

__device__ __forceinline__ ushort_t f2bf(float f) {
    uint_t u = __float_as_uint(f);
    u += 0x7fffu + ((u >> 16) & 1u);
    return (ushort_t)(u >> 16);
}
__device__ __forceinline__ float bf2f(ushort_t s) {
    return __uint_as_float(((uint_t)s) << 16);
}
// single-instruction packed f32->bf16 (RNE), lo in low 16 bits
__device__ __forceinline__ uint_t pack2(float lo, float hi) {
    uint_t r;
    asm("v_cvt_pk_bf16_f32 %0, %1, %2" : "=v"(r) : "v"(lo), "v"(hi));
    return r;
}

// ---------------- K0: pack conv weights into MFMA A-fragment order (bf16)
template<int CIN>
__global__ __launch_bounds__(256) void k_wpack(const float* __restrict__ w,
                                               short* __restrict__ wp) {
    int idx = blockIdx.x * 256 + threadIdx.x;
    if (idx >= CIN * 1152) return;      // CIN*9*128 elements
    int j    = idx & 7;
    int lane = (idx >> 3) & 63;
    int frag = idx >> 9;
    int rt   = frag & 7;
    int tap  = (frag >> 3) % 9;
    int ch   = frag / 72;
    int co   = rt * 16 + (lane & 15);
    int g    = lane >> 4;
    int ci   = ch * 32 + g * 8 + j;
    wp[idx] = (short)f2bf(w[((size_t)co * CIN + ci) * 9 + tap]);
}

// ---------------- K0b: pack projection weights (E x 128) into A-frag order
template<int E>
__global__ __launch_bounds__(256) void k_wpack_qkv(const float* __restrict__ w,
                                                   short* __restrict__ wp) {
    int idx = blockIdx.x * 256 + threadIdx.x;
    if (idx >= E * 128) return;
    int j    = idx & 7;
    int lane = (idx >> 3) & 63;
    int ch   = (idx >> 9) & 3;
    int rt   = idx >> 11;
    int n = lane & 15, g = lane >> 4;
    wp[idx] = (short)f2bf(w[(size_t)(rt*16 + n)*128 + ch*32 + g*8 + j]);
}

// ---------------- K0c: transpose X (NCHW f32) -> xbf (NHWC bf16), once.
__global__ __launch_bounds__(256) void k_xpose(const float* __restrict__ x,
                                               ushort_t* __restrict__ xbf) {
    const int half = blockIdx.x, b = blockIdx.y, t = threadIdx.x;
    const float* src = x + (size_t)b*NC*NL + (size_t)half*64*NL + t;
    uint_t* dst = (uint_t*)(xbf + ((size_t)b*NL + t)*NC + half*64);
    #pragma unroll
    for (int k8 = 0; k8 < 8; ++k8) {
        uint4 u;
        u.x = pack2(src[(k8*8+0)*NL], src[(k8*8+1)*NL]);
        u.y = pack2(src[(k8*8+2)*NL], src[(k8*8+3)*NL]);
        u.z = pack2(src[(k8*8+4)*NL], src[(k8*8+5)*NL]);
        u.w = pack2(src[(k8*8+6)*NL], src[(k8*8+7)*NL]);
        *(uint4*)(dst + k8*4) = u;
    }
}

// ---------------- K1: full-MFMA position attention. Block = (h, b), 8 waves x 32 q.
// LDS (shorts, 52.2 KB): PKT @0 [256][16] ; PBUF @4096 + w*640 [16][40] ;
//                        PVT @9216 [64 dv][264 l].  Q in registers (ds_bpermute).
__global__ __launch_bounds__(512, 4) void k_pos_mfma(
    const ushort_t* __restrict__ xbf,
    const short* __restrict__ wpq, const short* __restrict__ wpk,
    const short* __restrict__ wpv,
    const float* __restrict__ bq, const float* __restrict__ bk,
    const float* __restrict__ bv,
    ushort_t* __restrict__ att)
{
    const int h = blockIdx.x, b = blockIdx.y;
    const int t = threadIdx.x;
    const int lane = t & 63, w = t >> 6;       // w in [0,8): owns l/q range w*32..+32
    const int n = lane & 15, g = lane >> 4;

    __shared__ __align__(16) short lds[26112];   // 52,224 B

    const f32x4 z4 = {0.f, 0.f, 0.f, 0.f};
    f32x4 qacc[2], kacc[2], vacc[4][2];
    #pragma unroll
    for (int ct = 0; ct < 2; ++ct) { qacc[ct] = z4; kacc[ct] = z4; }
    #pragma unroll
    for (int vt = 0; vt < 4; ++vt)
        #pragma unroll
        for (int ct = 0; ct < 2; ++ct) vacc[vt][ct] = z4;

    const ushort_t* xr = xbf + ((size_t)(b*NL + w*32 + n))*NC;

    // ---- Phase A: projections over 4 k-chunks of 32 channels; no LDS, no barriers
    #pragma unroll 2
    for (int ch = 0; ch < 4; ++ch) {
        bf16x8 xb[2];
        #pragma unroll
        for (int ct = 0; ct < 2; ++ct)
            xb[ct] = *(const bf16x8*)(xr + ct*16*NC + ch*32 + g*8);
        const size_t fo = ((size_t)((h*4 + ch)*64) + lane) * 8;
        {
            bf16x8 aq = *(const bf16x8*)(wpq + fo);
            #pragma unroll
            for (int ct = 0; ct < 2; ++ct)
                qacc[ct] = __builtin_amdgcn_mfma_f32_16x16x32_bf16(aq, xb[ct], qacc[ct], 0, 0, 0);
        }
        {
            bf16x8 ak = *(const bf16x8*)(wpk + fo);
            #pragma unroll
            for (int ct = 0; ct < 2; ++ct)
                kacc[ct] = __builtin_amdgcn_mfma_f32_16x16x32_bf16(ak, xb[ct], kacc[ct], 0, 0, 0);
        }
        #pragma unroll
        for (int vt = 0; vt < 4; ++vt) {
            bf16x8 av = *(const bf16x8*)(wpv + ((size_t)((((h*4 + vt)*4) + ch)*64) + lane) * 8);
            #pragma unroll
            for (int ct = 0; ct < 2; ++ct)   // SWAPPED: D[l][dv]
                vacc[vt][ct] = __builtin_amdgcn_mfma_f32_16x16x32_bf16(xb[ct], av, vacc[vt][ct], 0, 0, 0);
        }
    }

    // ---- K/V -> LDS; Q -> packed registers (stays in-wave)
    uint_t qu01[2], qu23[2];
    {
        float bqv[4], bkv[4];
        #pragma unroll
        for (int r = 0; r < 4; ++r) {
            bqv[r] = bq[h*16 + g*4 + r];
            bkv[r] = bk[h*16 + g*4 + r];
        }
        #pragma unroll
        for (int ct = 0; ct < 2; ++ct) {
            qu01[ct] = pack2(qacc[ct][0] + bqv[0], qacc[ct][1] + bqv[1]);
            qu23[ct] = pack2(qacc[ct][2] + bqv[2], qacc[ct][3] + bqv[3]);
            uint2 kp;
            kp.x = pack2(kacc[ct][0] + bkv[0], kacc[ct][1] + bkv[1]);
            kp.y = pack2(kacc[ct][2] + bkv[2], kacc[ct][3] + bkv[3]);
            *(uint2*)&lds[(w*32 + ct*16 + n)*16 + g*4] = kp;
        }
        #pragma unroll
        for (int vt = 0; vt < 4; ++vt) {
            const float bvv = bv[h*64 + vt*16 + n];   // dv = vt*16 + n
            #pragma unroll
            for (int ct = 0; ct < 2; ++ct) {
                uint2 vp;
                vp.x = pack2(vacc[vt][ct][0] + bvv, vacc[vt][ct][1] + bvv);
                vp.y = pack2(vacc[vt][ct][2] + bvv, vacc[vt][ct][3] + bvv);
                *(uint2*)&lds[9216 + (vt*16 + n)*264 + w*32 + ct*16 + g*4] = vp;
            }
        }
    }
    __syncthreads();

    // ---- Phase B: per wave, 2 q-tiles of 16 q
    const int a0 = (n + 32*(g & 1)) * 4;      // source lane*4 for dq gather
    #pragma unroll 1
    for (int qt = 0; qt < 2; ++qt) {
        // in-wave Q transpose: lane (n,g) gathers Q[w*32+qt*16+n][g*8..g*8+7]
        union { uint_t u[4]; bf16x8 v; } qfu;
        qfu.u[0] = (uint_t)__builtin_amdgcn_ds_bpermute(a0,      (int)qu01[qt]);
        qfu.u[1] = (uint_t)__builtin_amdgcn_ds_bpermute(a0,      (int)qu23[qt]);
        qfu.u[2] = (uint_t)__builtin_amdgcn_ds_bpermute(a0 + 64, (int)qu01[qt]);
        qfu.u[3] = (uint_t)__builtin_amdgcn_ds_bpermute(a0 + 64, (int)qu23[qt]);
        if (g >= 2) { qfu.u[0] = 0; qfu.u[1] = 0; qfu.u[2] = 0; qfu.u[3] = 0; }
        bf16x8 qf = qfu.v;

        f32x4 s[16];
        #pragma unroll
        for (int kt = 0; kt < 16; ++kt) {
            bf16x8 kf = (bf16x8){0,0,0,0,0,0,0,0};
            if (g < 2) kf = *(const bf16x8*)&lds[(kt*16 + n)*16 + g*8];
            s[kt] = __builtin_amdgcn_mfma_f32_16x16x32_bf16(kf, qf, z4, 0, 0, 0);
        }
        // softmax over k (no max subtraction: |s*0.25| < ~2, exp-safe)
        float den = 0.f;
        #pragma unroll
        for (int kt = 0; kt < 16; ++kt)
            #pragma unroll
            for (int r = 0; r < 4; ++r) {
                float e = exp2f(s[kt][r] * 0.36067376022224085f);  // 0.25*log2(e)
                s[kt][r] = e;
                den += e;
            }
        den += __shfl_xor(den, 16);
        den += __shfl_xor(den, 32);
        const float inv = 1.f / den;

        f32x4 oacc[4] = {z4, z4, z4, z4};
        #pragma unroll
        for (int c2 = 0; c2 < 8; ++c2) {
            #pragma unroll
            for (int u = 0; u < 2; ++u) {
                const int kt = 2*c2 + u;
                uint2 pp;
                pp.x = pack2(s[kt][0], s[kt][1]);
                pp.y = pack2(s[kt][2], s[kt][3]);
                *(uint2*)&lds[4096 + w*640 + n*40 + u*16 + g*4] = pp;
            }
            bf16x8 pf = *(const bf16x8*)&lds[4096 + w*640 + n*40 + g*8];
            #pragma unroll
            for (int vt = 0; vt < 4; ++vt) {
                bf16x8 av = *(const bf16x8*)&lds[9216 + (vt*16 + n)*264 + c2*32 + g*8];
                oacc[vt] = __builtin_amdgcn_mfma_f32_16x16x32_bf16(av, pf, oacc[vt], 0, 0, 0);
            }
        }
        ushort_t* ap = att + (((size_t)b*NL + (w*32 + qt*16 + n))*NEV + h*HDV + g*4);
        #pragma unroll
        for (int vt = 0; vt < 4; ++vt) {
            uint2 op;
            op.x = pack2(oacc[vt][0]*inv, oacc[vt][1]*inv);
            op.y = pack2(oacc[vt][2]*inv, oacc[vt][3]*inv);
            *(uint2*)(ap + vt*16) = op;
        }
    }
}

// ---------------- K2: conv1 (3x3, 512->128) ci+l-split implicit GEMM.
// grid (4, NB): blockIdx.x = kc*2 + lh. Block = 128co x 128l x 256ci,
// 4 waves (2co x 2l), wave tile 64co x 64l. LDS: 10-row haloed image dbuf.
__global__ __launch_bounds__(256, 3) void k_conv_ci(
    const ushort_t* __restrict__ att, const short* __restrict__ wp,
    ushort_t* __restrict__ P)
{
    const int kc = blockIdx.x >> 1, lh = blockIdx.x & 1, b = blockIdx.y;
    const int t = threadIdx.x;
    const int lane = t & 63, w = t >> 6;
    const int wr = w >> 1, wc = w & 1;
    const int n = lane & 15, gl = lane >> 4;
    const int y0 = lh * 8;

    __shared__ __align__(16) short ims[2][5760];   // 2 x 11.25 KB

    {   // zero both buffers once
        bf16x8 z = {0,0,0,0,0,0,0,0};
        bf16x8* p = (bf16x8*)&ims[0][0];
        for (int i = t; i < 1440; i += 256) p[i] = z;
    }

    f32x4 acc[4][4];
    #pragma unroll
    for (int i = 0; i < 4; ++i)
        #pragma unroll
        for (int j = 0; j < 4; ++j) acc[i][j] = (f32x4){0.f,0.f,0.f,0.f};

    const int gg1 = t & 3,        xx1 = (t >> 2) & 15,        yp1 = t >> 6;
    const int id2 = t + 256;
    const int gg2 = id2 & 3,      xx2 = (id2 >> 2) & 15,      yp2 = id2 >> 6;
    const int id3 = t + 512;
    const int gg3 = id3 & 3,      xx3 = (id3 >> 2) & 15,      yp3 = id3 >> 6;
    const bool has3 = (t < 128);
    const int y1 = y0 - 1 + yp1, y2 = y0 - 1 + yp2, y3 = y0 - 1 + yp3;
    const bool ok1 = (y1 >= 0) && (y1 < 16);
    const bool ok2 = (y2 >= 0) && (y2 < 16);
    const bool ok3 = has3 && (y3 >= 0) && (y3 < 16);
    const ushort_t* src1 = att + ((size_t)(b*NL + y1*16 + xx1))*NEV + kc*256 + gg1*8;
    const ushort_t* src2 = att + ((size_t)(b*NL + y2*16 + xx2))*NEV + kc*256 + gg2*8;
    const ushort_t* src3 = att + ((size_t)(b*NL + y3*16 + xx3))*NEV + kc*256 + gg3*8;
    const int slot1 = ((yp1*4 + gg1)*18 + xx1 + 1) * 8;
    const int slot2 = ((yp2*4 + gg2)*18 + xx2 + 1) * 8;
    const int slot3 = ((yp3*4 + gg3)*18 + xx3 + 1) * 8;

    bf16x8 v1 = {0,0,0,0,0,0,0,0}, v2 = v1, v3 = v1;
    if (ok1) v1 = *(const bf16x8*)src1;
    if (ok2) v2 = *(const bf16x8*)src2;
    if (ok3) v3 = *(const bf16x8*)src3;
    __syncthreads();

    #pragma unroll 1
    for (int ch = 0; ch < 8; ++ch) {
        short* buf = &ims[ch & 1][0];
        *(bf16x8*)&buf[slot1] = v1;
        *(bf16x8*)&buf[slot2] = v2;
        if (has3) *(bf16x8*)&buf[slot3] = v3;
        if (ch < 7) {
            if (ok1) v1 = *(const bf16x8*)(src1 + (ch + 1) * 32);
            if (ok2) v2 = *(const bf16x8*)(src2 + (ch + 1) * 32);
            if (ok3) v3 = *(const bf16x8*)(src3 + (ch + 1) * 32);
        }
        __syncthreads();
        #pragma unroll
        for (int tap = 0; tap < 9; ++tap) {
            const int dy = tap / 3, dx = tap % 3;
            bf16x8 Bf[4];
            #pragma unroll
            for (int ct = 0; ct < 4; ++ct)
                Bf[ct] = *(const bf16x8*)&buf[(((wc*4 + ct + dy)*4 + gl)*18 + n + dx) * 8];
            bf16x8 Af[4];
            #pragma unroll
            for (int rt = 0; rt < 4; ++rt)
                Af[rt] = *(const bf16x8*)(wp +
                    ((size_t)(((kc*8 + ch)*9 + tap)*8 + wr*4 + rt)) * 512 + lane*8);
            #pragma unroll
            for (int rt = 0; rt < 4; ++rt)
                #pragma unroll
                for (int ct = 0; ct < 4; ++ct)
                    acc[rt][ct] = __builtin_amdgcn_mfma_f32_16x16x32_bf16(
                        Af[rt], Bf[ct], acc[rt][ct], 0, 0, 0);
        }
    }

    ushort_t* Pb = P + (size_t)kc * PHALF + (size_t)b * NL * NC;
    #pragma unroll
    for (int rt = 0; rt < 4; ++rt) {
        const int co0 = wr*64 + rt*16 + gl*4;
        #pragma unroll
        for (int ct = 0; ct < 4; ++ct) {
            const int l = lh*128 + wc*64 + ct*16 + n;
            uint2 u;
            u.x = pack2(acc[rt][ct][0], acc[rt][ct][1]);
            u.y = pack2(acc[rt][ct][2], acc[rt][ct][3]);
            *(uint2*)(Pb + (size_t)l*NC + co0) = u;
        }
    }
}

// ---------------- K4: conv2 (3x3, 128->128) co+l-split implicit GEMM.
// grid (4, NB): blockIdx.x = kc*2 + lh (kc = 64-co half, lh = 128-l half).
// 4 waves (2co x 2l), wave tile 32co x 64l. 10-row haloed image dbuf.
__global__ __launch_bounds__(256, 3) void k_conv_co(
    const float* __restrict__ comb, const short* __restrict__ wp,
    const float* __restrict__ bias, float* __restrict__ out)
{
    const int kc = blockIdx.x >> 1, lh = blockIdx.x & 1, b = blockIdx.y;
    const int t = threadIdx.x;
    const int lane = t & 63, w = t >> 6;
    const int wr = w >> 1, wc = w & 1;
    const int n = lane & 15, gl = lane >> 4;
    const int y0 = lh * 8;

    __shared__ __align__(16) short ims[2][5760];

    {
        bf16x8 z = {0,0,0,0,0,0,0,0};
        bf16x8* p = (bf16x8*)&ims[0][0];
        for (int i = t; i < 1440; i += 256) p[i] = z;
    }

    f32x4 acc[2][4];
    #pragma unroll
    for (int i = 0; i < 2; ++i)
        #pragma unroll
        for (int j = 0; j < 4; ++j) acc[i][j] = (f32x4){0.f,0.f,0.f,0.f};

    const int gg1 = t & 3,        xx1 = (t >> 2) & 15,        yp1 = t >> 6;
    const int id2 = t + 256;
    const int gg2 = id2 & 3,      xx2 = (id2 >> 2) & 15,      yp2 = id2 >> 6;
    const int id3 = t + 512;
    const int gg3 = id3 & 3,      xx3 = (id3 >> 2) & 15,      yp3 = id3 >> 6;
    const bool has3 = (t < 128);
    const int y1 = y0 - 1 + yp1, y2 = y0 - 1 + yp2, y3 = y0 - 1 + yp3;
    const bool ok1 = (y1 >= 0) && (y1 < 16);
    const bool ok2 = (y2 >= 0) && (y2 < 16);
    const bool ok3 = has3 && (y3 >= 0) && (y3 < 16);
    const float* s1 = comb + ((size_t)(b*NL + y1*16 + xx1))*NC + gg1*8;
    const float* s2 = comb + ((size_t)(b*NL + y2*16 + xx2))*NC + gg2*8;
    const float* s3 = comb + ((size_t)(b*NL + y3*16 + xx3))*NC + gg3*8;
    const int slot1 = ((yp1*4 + gg1)*18 + xx1 + 1) * 8;
    const int slot2 = ((yp2*4 + gg2)*18 + xx2 + 1) * 8;
    const int slot3 = ((yp3*4 + gg3)*18 + xx3 + 1) * 8;

    float4 f1a, f1b, f2a, f2b, f3a, f3b;
    f1a = f1b = f2a = f2b = f3a = f3b = (float4){0.f,0.f,0.f,0.f};
    if (ok1) { f1a = *(const float4*)s1; f1b = *(const float4*)(s1 + 4); }
    if (ok2) { f2a = *(const float4*)s2; f2b = *(const float4*)(s2 + 4); }
    if (ok3) { f3a = *(const float4*)s3; f3b = *(const float4*)(s3 + 4); }
    __syncthreads();

    #pragma unroll 1
    for (int ch = 0; ch < 4; ++ch) {
        short* buf = &ims[ch & 1][0];
        uint4 w1, w2, w3;
        w1.x = pack2(f1a.x, f1a.y);  w1.y = pack2(f1a.z, f1a.w);
        w1.z = pack2(f1b.x, f1b.y);  w1.w = pack2(f1b.z, f1b.w);
        w2.x = pack2(f2a.x, f2a.y);  w2.y = pack2(f2a.z, f2a.w);
        w2.z = pack2(f2b.x, f2b.y);  w2.w = pack2(f2b.z, f2b.w);
        w3.x = pack2(f3a.x, f3a.y);  w3.y = pack2(f3a.z, f3a.w);
        w3.z = pack2(f3b.x, f3b.y);  w3.w = pack2(f3b.z, f3b.w);
        *(uint4*)&buf[slot1] = w1;
        *(uint4*)&buf[slot2] = w2;
        if (has3) *(uint4*)&buf[slot3] = w3;
        if (ch < 3) {
            if (ok1) { f1a = *(const float4*)(s1 + (ch+1)*32); f1b = *(const float4*)(s1 + (ch+1)*32 + 4); }
            if (ok2) { f2a = *(const float4*)(s2 + (ch+1)*32); f2b = *(const float4*)(s2 + (ch+1)*32 + 4); }
            if (ok3) { f3a = *(const float4*)(s3 + (ch+1)*32); f3b = *(const float4*)(s3 + (ch+1)*32 + 4); }
        }
        __syncthreads();
        #pragma unroll
        for (int tap = 0; tap < 9; ++tap) {
            const int dy = tap / 3, dx = tap % 3;
            bf16x8 Bf[4];
            #pragma unroll
            for (int ct = 0; ct < 4; ++ct)
                Bf[ct] = *(const bf16x8*)&buf[(((wc*4 + ct + dy)*4 + gl)*18 + n + dx) * 8];
            bf16x8 Af[2];
            #pragma unroll
            for (int rt = 0; rt < 2; ++rt)
                Af[rt] = *(const bf16x8*)(wp +
                    ((size_t)((ch*9 + tap)*8 + kc*4 + wr*2 + rt)) * 512 + lane*8);
            #pragma unroll
            for (int rt = 0; rt < 2; ++rt)
                #pragma unroll
                for (int ct = 0; ct < 4; ++ct)
                    acc[rt][ct] = __builtin_amdgcn_mfma_f32_16x16x32_bf16(
                        Af[rt], Bf[ct], acc[rt][ct], 0, 0, 0);
        }
    }

    #pragma unroll
    for (int rt = 0; rt < 2; ++rt) {
        const int co0 = kc*64 + wr*32 + rt*16 + gl*4;
        const float c0 = bias[co0+0], c1 = bias[co0+1],
                    c2 = bias[co0+2], c3 = bias[co0+3];
        #pragma unroll
        for (int ct = 0; ct < 4; ++ct) {
            const int l = lh*128 + wc*64 + ct*16 + n;
            f32x4 a = acc[rt][ct];
            out[((size_t)b*NC + co0+0)*NL + l] = c0 + a[0];
            out[((size_t)b*NC + co0+1)*NL + l] = c1 + a[1];
            out[((size_t)b*NC + co0+2)*NL + l] = c2 + a[2];
            out[((size_t)b*NC + co0+3)*NL + l] = c3 + a[3];
        }
    }
}

// ---------------- K3: channel attention + fold conv1 partials + pos residual + fusion
#define NLP 260
__global__ __launch_bounds__(256) void k_cha(
    const float* __restrict__ xc,
    const float* __restrict__ cwq, const float* __restrict__ cbq,
    const float* __restrict__ cwk, const float* __restrict__ cbk,
    const float* __restrict__ cwv, const float* __restrict__ cbv,
    const float* __restrict__ cwo, const float* __restrict__ cbo,
    const float* __restrict__ gamma,
    const ushort_t* __restrict__ P, const float* __restrict__ qpos,
    const float* __restrict__ pbo, const float* __restrict__ gpos,
    float* __restrict__ comb)
{
    const int h = blockIdx.x, b = blockIdx.y, t = threadIdx.x;
    __shared__ float qh[16][NLP];
    __shared__ float G_s[16][17];
    __shared__ float S_s[16];
    __shared__ float wq_s[128], bq_s[128], wk_s[128], bk_s[128], wv_s[128], bv_s[128];
    __shared__ float A_s[128][17];
    __shared__ float B_s[128];
    __shared__ float M_s[16][17];
    __shared__ float c_s[16];

    #pragma unroll
    for (int j = 0; j < 16; ++j)
        qh[j][t] = xc[((size_t)b*NC + h*16 + j)*NL + t];
    if (t < 128) {
        const int k = h*128 + t;
        wq_s[t] = cwq[k]; bq_s[t] = cbq[k];
        wk_s[t] = cwk[k]; bk_s[t] = cbk[k];
        wv_s[t] = cwv[k]; bv_s[t] = cbv[k];
    }
    __syncthreads();
    {
        const int i = t >> 4, j = t & 15;
        const float4* qi = (const float4*)qh[i];
        const float4* qj = (const float4*)qh[j];
        float gg = 0.f;
        for (int l4 = 0; l4 < NL/4; ++l4) {
            float4 a = qi[l4], c = qj[l4];
            gg = fmaf(a.x,c.x,fmaf(a.y,c.y,fmaf(a.z,c.z,fmaf(a.w,c.w,gg))));
        }
        G_s[i][j] = gg;
    }
    if (t < 16) {
        const float4* qi = (const float4*)qh[t];
        float s = 0.f;
        for (int l4 = 0; l4 < NL/4; ++l4) { float4 a = qi[l4]; s += a.x + a.y + a.z + a.w; }
        S_s[t] = s;
    }
    __syncthreads();
    if (t < 128) {
        const int c2 = t, cg = c2 >> 3;
        const float wqc = wq_s[c2], bqc = bq_s[c2];
        float Pv[16];
        #pragma unroll
        for (int j = 0; j < 16; ++j) Pv[j] = wqc*G_s[cg][j] + bqc*S_s[j];
        const float Qc = wqc*S_s[cg] + bqc*256.0f;
        float mx = -3.0e38f;
        #pragma unroll
        for (int dg = 0; dg < 16; ++dg) {
            #pragma unroll
            for (int dj = 0; dj < 8; ++dj) {
                const int d = dg*8 + dj;
                float s = wk_s[d]*Pv[dg] + bk_s[d]*Qc;
                mx = fmaxf(mx, s);
            }
        }
        float A[16];
        #pragma unroll
        for (int j = 0; j < 16; ++j) A[j] = 0.f;
        float Bv = 0.f, den = 0.f;
        #pragma unroll
        for (int dg = 0; dg < 16; ++dg) {
            #pragma unroll
            for (int dj = 0; dj < 8; ++dj) {
                const int d = dg*8 + dj;
                float s = wk_s[d]*Pv[dg] + bk_s[d]*Qc;
                float e = __expf((s - mx) * 0.0625f);
                den += e;
                A[dg] = fmaf(e, wv_s[d], A[dg]);
                Bv = fmaf(e, bv_s[d], Bv);
            }
        }
        const float inv = 1.f / den;
        #pragma unroll
        for (int j = 0; j < 16; ++j) A_s[c2][j] = A[j]*inv;
        B_s[c2] = Bv*inv;
    }
    __syncthreads();
    {
        const int cl = t >> 4, j = t & 15;
        const int cp = h*16 + cl;
        float m = 0.f;
        #pragma unroll
        for (int hp = 0; hp < 8; ++hp)
            m = fmaf(cwo[cp*8+hp], A_s[cl*8+hp][j], m);
        M_s[cl][j] = m;
        if (j == 0) {
            float cc = cbo[cp];
            #pragma unroll
            for (int hp = 0; hp < 8; ++hp)
                cc = fmaf(cwo[cp*8+hp], B_s[cl*8+hp], cc);
            c_s[cl] = cc;
        }
    }
    __syncthreads();
    {
        const float g  = gamma[0];
        const float gp = gpos[0];
        const int l = t;
        float av[16];
        #pragma unroll
        for (int cl = 0; cl < 16; ++cl) {
            float a = c_s[cl];
            #pragma unroll
            for (int j = 0; j < 16; ++j)
                a = fmaf(M_s[cl][j], qh[j][l], a);
            av[cl] = a;
        }
        const ushort_t* p0 = P + ((size_t)b*NL + l)*NC + h*16;
        const ushort_t* p1 = p0 + PHALF;
        const float* qp = qpos + ((size_t)b*NC + h*16)*NL + l;
        float4* cp4 = (float4*)(comb + ((size_t)b*NL + l)*NC + h*16);
        #pragma unroll
        for (int q = 0; q < 4; ++q) {
            uint2 u0 = *(const uint2*)(p0 + 4*q);
            uint2 u1 = *(const uint2*)(p1 + 4*q);
            float s0 = bf2f((ushort_t)(u0.x & 0xffffu)) + bf2f((ushort_t)(u1.x & 0xffffu));
            float s1 = bf2f((ushort_t)(u0.x >> 16))     + bf2f((ushort_t)(u1.x >> 16));
            float s2 = bf2f((ushort_t)(u0.y & 0xffffu)) + bf2f((ushort_t)(u1.y & 0xffffu));
            float s3 = bf2f((ushort_t)(u0.y >> 16))     + bf2f((ushort_t)(u1.y >> 16));
            float4 c;
            c.x = 0.5f*(qp[(4*q+0)*NL] + gp*(pbo[h*16+4*q+0] + s0) + qh[4*q+0][l] + g*av[4*q+0]);
            c.y = 0.5f*(qp[(4*q+1)*NL] + gp*(pbo[h*16+4*q+1] + s1) + qh[4*q+1][l] + g*av[4*q+1]);
            c.z = 0.5f*(qp[(4*q+2)*NL] + gp*(pbo[h*16+4*q+2] + s2) + qh[4*q+2][l] + g*av[4*q+2]);
            c.w = 0.5f*(qp[(4*q+3)*NL] + gp*(pbo[h*16+4*q+3] + s3) + qh[4*q+3][l] + g*av[4*q+3]);
            cp4[q] = c;
        }
    }
}

extern "C" void kernel_launch(void* const* d_in, const int* in_sizes, int n_in,
                              void* d_out, int out_size, void* d_ws, size_t ws_size,
                              hipStream_t stream)
{
    const float* qpos = (const float*)d_in[0];
    const float* qcha = (const float*)d_in[1];
    const float* pwq  = (const float*)d_in[2];
    const float* pbq  = (const float*)d_in[3];
    const float* pwk  = (const float*)d_in[4];
    const float* pbk  = (const float*)d_in[5];
    const float* pwv  = (const float*)d_in[6];
    const float* pbv  = (const float*)d_in[7];
    const float* pwo  = (const float*)d_in[8];
    const float* pbo  = (const float*)d_in[9];
    const float* gpos = (const float*)d_in[10];
    const float* cwq  = (const float*)d_in[11];
    const float* cbq  = (const float*)d_in[12];
    const float* cwk  = (const float*)d_in[13];
    const float* cbk  = (const float*)d_in[14];
    const float* cwv  = (const float*)d_in[15];
    const float* cbv  = (const float*)d_in[16];
    const float* cwo  = (const float*)d_in[17];
    const float* cbo  = (const float*)d_in[18];
    const float* gcha = (const float*)d_in[19];
    const float* fw   = (const float*)d_in[20];
    const float* fb   = (const float*)d_in[21];
    float* outp = (float*)d_out;

    char* ws = (char*)d_ws;
    ushort_t* att  = (ushort_t*)ws;                       // 33,554,432 B (NHWC bf16)
    float*    comb = (float*)ws;                          // 16,777,216 B (overlays att; att dead)
    ushort_t* P    = (ushort_t*)(ws + 33554432);          // 16,777,216 B (2 bf16 partial halves)
    ushort_t* xbf  = (ushort_t*)(ws + 33554432);          //  8,388,608 B (overlays P; dead before conv_ci)
    short*    wp1  = (short*)(ws + 50331648);             //  1,179,648 B
    short*    wp2  = (short*)(ws + 51511296);             //    294,912 B
    short*    wpq  = (short*)(ws + 51806208);             //     32,768 B
    short*    wpk  = (short*)(ws + 51838976);             //     32,768 B
    short*    wpv  = (short*)(ws + 51871744);             //    131,072 B

    k_wpack<NEV><<<dim3((NEV*1152 + 255)/256), 256, 0, stream>>>(pwo, wp1);
    k_wpack<NC ><<<dim3((NC *1152 + 255)/256), 256, 0, stream>>>(fw,  wp2);
    k_wpack_qkv<128><<<dim3(64),  256, 0, stream>>>(pwq, wpq);
    k_wpack_qkv<128><<<dim3(64),  256, 0, stream>>>(pwk, wpk);
    k_wpack_qkv<512><<<dim3(256), 256, 0, stream>>>(pwv, wpv);

    k_xpose<<<dim3(2, NB), 256, 0, stream>>>(qpos, xbf);
    k_pos_mfma<<<dim3(NH, NB), 512, 0, stream>>>(xbf, wpq, wpk, wpv,
                                                 pbq, pbk, pbv, att);
    k_conv_ci<<<dim3(4, NB), 256, 0, stream>>>(att, wp1, P);
    k_cha<<<dim3(NH, NB), 256, 0, stream>>>(qcha, cwq, cbq, cwk, cbk, cwv, cbv,
                                            cwo, cbo, gcha,
                                            P, qpos, pbo, gpos, comb);
    k_conv_co<<<dim3(4, NB), 256, 0, stream>>>(comb, wp2, fb, outp);
}